// Round 8
// baseline (3168.299 us; speedup 1.0000x reference)
//
#include <hip/hip_runtime.h>
#include <hip/hip_bf16.h>
#include <cstdint>

typedef __attribute__((ext_vector_type(8))) short short8;
typedef __attribute__((ext_vector_type(4))) float f32x4;
typedef __attribute__((ext_vector_type(4))) unsigned short ushort4v;

#define DEV static __device__ __forceinline__

DEV float bf2f(unsigned short u) {
    union { unsigned int i; float f; } v; v.i = ((unsigned int)u) << 16; return v.f;
}
DEV unsigned short f2bf(float f) {
    union { float f; unsigned int i; } v; v.f = f;
    unsigned int x = v.i;
    unsigned int r = x + 0x7fffu + ((x >> 16) & 1u);
    return (unsigned short)(r >> 16);
}

// ---------------------------------------------------------------------------
// GEMM: C[M,N] = A[M,K](bf16, row-stride lda) @ Wt[N,K]^T + bias -> bf16 (ldc)
// 128x128 tile, 4 waves, 16x16x32 MFMA, BK=64, single-buffer LDS, XCD-aware
// 1D-grid swizzle (r7-measured best).
// EPI 0: elu+1 applied iff col<512 | EPI 2: relu
// ---------------------------------------------------------------------------
template<int EPI>
__global__ __launch_bounds__(256) void gemm_kernel(
    const unsigned short* __restrict__ A, int lda,
    const unsigned short* __restrict__ Bt,
    const float* __restrict__ bias,
    unsigned short* __restrict__ outp, int ldc,
    int nshift, int K)
{
    __shared__ unsigned short lds[128 * 136];
    const int t  = threadIdx.x;
    const int w  = t >> 6, l = t & 63;
    const int wr = w >> 1, wc = w & 1;
    const int lr = l & 15, lg = l >> 4;
    const int bid = blockIdx.x;
    const int j8  = bid & 7, s = bid >> 3;
    const int bx  = j8 * 32 + (s >> nshift);
    const int by  = s & ((1 << nshift) - 1);
    const long tM = (long)bx * 128;
    const long tN = (long)by * 128;

    f32x4 acc[4][4];
#pragma unroll
    for (int i = 0; i < 4; i++)
#pragma unroll
        for (int j = 0; j < 4; j++) acc[i][j] = f32x4{0.f, 0.f, 0.f, 0.f};

    const unsigned short* Ab = A  + tM * lda;
    const unsigned short* Bb = Bt + tN * K;

    for (int kt = 0; kt < K; kt += 64) {
#pragma unroll
        for (int j = 0; j < 4; j++) {
            int c = (w * 4 + j) * 64 + l;
            int row = c >> 3, sc = (c & 7) ^ (row & 7);
            __builtin_amdgcn_global_load_lds(
                (const __attribute__((address_space(1))) void*)(Ab + (long)row * lda + kt + sc * 8),
                (__attribute__((address_space(3))) void*)(lds + (w * 4 + j) * 512),
                16, 0, 0);
        }
#pragma unroll
        for (int j = 0; j < 4; j++) {
            int c = (w * 4 + j) * 64 + l;
            int row = c >> 3, sc = (c & 7) ^ (row & 7);
            __builtin_amdgcn_global_load_lds(
                (const __attribute__((address_space(1))) void*)(Bb + (long)row * K + kt + sc * 8),
                (__attribute__((address_space(3))) void*)(lds + 8192 + (w * 4 + j) * 512),
                16, 0, 0);
        }
        __syncthreads();
#pragma unroll
        for (int kk = 0; kk < 2; kk++) {
            short8 af[4], bfv[4];
#pragma unroll
            for (int mi = 0; mi < 4; mi++) {
                int r  = wr * 64 + mi * 16 + lr;
                int kc = kk * 4 + lg;
                af[mi] = *(const short8*)&lds[r * 64 + ((kc ^ (r & 7)) << 3)];
            }
#pragma unroll
            for (int ni = 0; ni < 4; ni++) {
                int n  = wc * 64 + ni * 16 + lr;
                int kc = kk * 4 + lg;
                bfv[ni] = *(const short8*)&lds[8192 + n * 64 + ((kc ^ (n & 7)) << 3)];
            }
#pragma unroll
            for (int mi = 0; mi < 4; mi++)
#pragma unroll
                for (int ni = 0; ni < 4; ni++)
                    acc[mi][ni] = __builtin_amdgcn_mfma_f32_16x16x32_bf16(
                        af[mi], bfv[ni], acc[mi][ni], 0, 0, 0);
        }
        __syncthreads();
    }

    float bv[4];
#pragma unroll
    for (int ni = 0; ni < 4; ni++) bv[ni] = bias[tN + wc * 64 + ni * 16 + lr];
    const bool doElu = (EPI == 0) && (tN < 512);

#pragma unroll
    for (int mi = 0; mi < 4; mi++)
#pragma unroll
        for (int ni = 0; ni < 4; ni++)
#pragma unroll
            for (int j = 0; j < 4; j++) {
                float v = acc[mi][ni][j] + bv[ni];
                if (EPI == 0) { if (doElu) v = (v > 0.f) ? (v + 1.f) : expf(v); }
                if (EPI == 2) v = fmaxf(v, 0.f);
                int r = wr * 64 + mi * 16 + lg * 4 + j;
                int c = wc * 64 + ni * 16 + lr;
                lds[r * 136 + c] = f2bf(v);
            }
    __syncthreads();
#pragma unroll
    for (int i = 0; i < 8; i++) {
        int q = i * 256 + t;
        int r = q >> 4, cc = q & 15;
        short8 v8 = *(const short8*)&lds[r * 136 + cc * 8];
        *(short8*)&outp[(tM + r) * ldc + tN + cc * 8] = v8;
    }
}

// ---------------------------------------------------------------------------
// Fused GEMM + bias + residual(f32) + LayerNorm.
// BM=128, 512 thr / 8 waves; wave (wr,wc): rows wr*64+[0,64), cols
// wc*128+[0,128). BK=32 (sB 32KB, total LDS 45.5KB -> 2 blocks/CU,
// 16 waves/CU vs r7's 8; B-panel traffic unchanged by BK).
// Swizzle for 64B rows: sc=(c&3)^((row>>1)&3); lanes lr=0..15 hit 16-B slot
// 4*(r&1)+(lg^((r>>1)&3)) mod 128B -> all 8 slots exactly twice = 2-way, free.
// y = LN(A@Wt^T + bias + res); writes y to f32 `of` and bf16 `ob`.
// res may alias of (per-elem read-before-write by owning thread).
// ---------------------------------------------------------------------------
__global__ __launch_bounds__(512, 4) void gemm_ln_kernel(
    const unsigned short* __restrict__ A, int lda,
    const unsigned short* __restrict__ Bt,   // [512][K]
    const float* __restrict__ bias,          // [512]
    const float* __restrict__ res,           // [M][512] f32
    const float* __restrict__ g,
    const float* __restrict__ be,
    float* __restrict__ of,                  // [M][512] f32
    unsigned short* __restrict__ ob,         // [M][512] bf16
    int K)
{
    __shared__ unsigned short sA[128 * 32];   // 8 KiB
    __shared__ unsigned short sB[512 * 32];   // 32 KiB
    __shared__ float red[2][4][128];          // 4 KiB
    __shared__ float stats[2][128];           // 1 KiB
    const int t = threadIdx.x, w = t >> 6, l = t & 63, lr = l & 15, lg = l >> 4;
    const int wr = w >> 2, wc = w & 3;
    const long tM = (long)blockIdx.x * 128;

    f32x4 acc[4][8];
#pragma unroll
    for (int i = 0; i < 4; i++)
#pragma unroll
        for (int j = 0; j < 8; j++) acc[i][j] = f32x4{0.f, 0.f, 0.f, 0.f};

    const unsigned short* Ab = A + tM * lda;

    for (int kt = 0; kt < K; kt += 32) {
        {   // A: 128 rows x 4 chunks = 512 chunks, 1/thread
            int c = t, row = c >> 2, sc = (c & 3) ^ ((row >> 1) & 3);
            __builtin_amdgcn_global_load_lds(
                (const __attribute__((address_space(1))) void*)(Ab + (long)row * lda + kt + sc * 8),
                (__attribute__((address_space(3))) void*)(sA + w * 512),
                16, 0, 0);
        }
#pragma unroll
        for (int j = 0; j < 4; j++) {  // B: 512 rows x 4 chunks = 2048 chunks
            int c = j * 512 + t, row = c >> 2, sc = (c & 3) ^ ((row >> 1) & 3);
            __builtin_amdgcn_global_load_lds(
                (const __attribute__((address_space(1))) void*)(Bt + (long)row * K + kt + sc * 8),
                (__attribute__((address_space(3))) void*)(sB + (j * 512 + w * 64) * 8),
                16, 0, 0);
        }
        __syncthreads();
        short8 av[4], bw[8];
#pragma unroll
        for (int mi = 0; mi < 4; mi++) {
            int r = wr * 64 + mi * 16 + lr;
            av[mi] = *(const short8*)&sA[r * 32 + ((lg ^ ((r >> 1) & 3)) << 3)];
        }
#pragma unroll
        for (int ni = 0; ni < 8; ni++) {
            int n = wc * 128 + ni * 16 + lr;
            bw[ni] = *(const short8*)&sB[n * 32 + ((lg ^ ((n >> 1) & 3)) << 3)];
        }
#pragma unroll
        for (int mi = 0; mi < 4; mi++)
#pragma unroll
            for (int ni = 0; ni < 8; ni++)
                acc[mi][ni] = __builtin_amdgcn_mfma_f32_16x16x32_bf16(
                    av[mi], bw[ni], acc[mi][ni], 0, 0, 0);
        __syncthreads();
    }

    // epilogue: v = C + bias + res; LN over the 512-wide row
    float gv[8], bev[8], bb[8];
#pragma unroll
    for (int ni = 0; ni < 8; ni++) {
        int col = wc * 128 + ni * 16 + lr;
        gv[ni] = g[col]; bev[ni] = be[col]; bb[ni] = bias[col];
    }
#pragma unroll
    for (int mi = 0; mi < 4; mi++)
#pragma unroll
        for (int jj = 0; jj < 4; jj++) {
            long row = tM + wr * 64 + mi * 16 + lg * 4 + jj;
#pragma unroll
            for (int ni = 0; ni < 8; ni++) {
                int col = wc * 128 + ni * 16 + lr;
                acc[mi][ni][jj] += bb[ni] + res[row * 512 + col];
            }
        }
    float s2[4][4], ss2[4][4];
#pragma unroll
    for (int mi = 0; mi < 4; mi++)
#pragma unroll
        for (int jj = 0; jj < 4; jj++) {
            float s = 0.f, ss = 0.f;
#pragma unroll
            for (int ni = 0; ni < 8; ni++) {
                float v = acc[mi][ni][jj];
                s += v; ss += v * v;
            }
#pragma unroll
            for (int off = 1; off < 16; off <<= 1) {
                s  += __shfl_xor(s, off);
                ss += __shfl_xor(ss, off);
            }
            s2[mi][jj] = s; ss2[mi][jj] = ss;
        }
    if (lr == 0) {
#pragma unroll
        for (int mi = 0; mi < 4; mi++)
#pragma unroll
            for (int jj = 0; jj < 4; jj++) {
                int rb = wr * 64 + mi * 16 + lg * 4 + jj;
                red[0][wc][rb] = s2[mi][jj];
                red[1][wc][rb] = ss2[mi][jj];
            }
    }
    __syncthreads();
    if (t < 128) {
        float S  = red[0][0][t] + red[0][1][t] + red[0][2][t] + red[0][3][t];
        float SS = red[1][0][t] + red[1][1][t] + red[1][2][t] + red[1][3][t];
        float mean = S * (1.0f / 512.0f);
        float var  = SS * (1.0f / 512.0f) - mean * mean;
        stats[0][t] = mean;
        stats[1][t] = rsqrtf(fmaxf(var, 0.f) + 1e-5f);
    }
    __syncthreads();
#pragma unroll
    for (int mi = 0; mi < 4; mi++)
#pragma unroll
        for (int jj = 0; jj < 4; jj++) {
            int rb = wr * 64 + mi * 16 + lg * 4 + jj;
            long row = tM + rb;
            float mean = stats[0][rb], rstd = stats[1][rb];
#pragma unroll
            for (int ni = 0; ni < 8; ni++) {
                int col = wc * 128 + ni * 16 + lr;
                float y = (acc[mi][ni][jj] - mean) * rstd * gv[ni] + bev[ni];
                of[row * 512 + col] = y;
                ob[row * 512 + col] = f2bf(y);
            }
        }
}

// ---------------------------------------------------------------------------
// Attention glue. KVbuf[(s*8+b)][1024]: cols 0..511 = phiK (later ATTN),
// cols 512..1023 = V (later phiQ).
// ctx_partial also accumulates ksum_d = sum_s phiK[s][d] (part2).
// ---------------------------------------------------------------------------
__global__ __launch_bounds__(256) void ctx_partial_kernel(
    const unsigned short* __restrict__ kv, float* __restrict__ part,
    float* __restrict__ part2)
{
    const int p = blockIdx.x, ch = blockIdx.y;
    const int b = p >> 3, h = p & 7;
    __shared__ float kb[64 * 68];
    __shared__ float vbuf[64 * 68];
    const int t = threadIdx.x;
    const int dq = t >> 4, eq = t & 15;
    f32x4 acc[4];
    f32x4 ks = {0.f, 0.f, 0.f, 0.f};
#pragma unroll
    for (int i = 0; i < 4; i++) acc[i] = f32x4{0.f, 0.f, 0.f, 0.f};

    for (int sub = 0; sub < 8; sub++) {
        int sbase = ch * 512 + sub * 64;
#pragma unroll
        for (int i = 0; i < 2; i++) {
            int idx = i * 256 + t;
            int row = idx >> 3, c8 = idx & 7;
            long ga = ((long)(sbase + row) * 8 + b) * 1024 + h * 64 + c8 * 8;
            short8 kvv = *(const short8*)&kv[ga];
            short8 vv  = *(const short8*)&kv[ga + 512];
#pragma unroll
            for (int j = 0; j < 8; j++) {
                kb[row * 68 + c8 * 8 + j]   = bf2f((unsigned short)kvv[j]);
                vbuf[row * 68 + c8 * 8 + j] = bf2f((unsigned short)vv[j]);
            }
        }
        __syncthreads();
        for (int s = 0; s < 64; s++) {
            f32x4 k4 = *(const f32x4*)&kb[s * 68 + dq * 4];
            f32x4 v4 = *(const f32x4*)&vbuf[s * 68 + eq * 4];
#pragma unroll
            for (int i = 0; i < 4; i++) acc[i] += k4[i] * v4;
            ks += k4;
        }
        __syncthreads();
    }
    float* o = part + (long)(p * 8 + ch) * 4096;
#pragma unroll
    for (int i = 0; i < 4; i++)
        *(f32x4*)&o[(dq * 4 + i) * 64 + eq * 4] = acc[i];
    if (eq == 0)
        *(f32x4*)&part2[(p * 8 + ch) * 64 + dq * 4] = ks;
}

// reduce ctx partials -> ctxA[p][n=e][k=d] (bf16, transposed); finalize ksum
// into row n=64, zero rows 65..79
__global__ __launch_bounds__(256) void ctx_reduce_kernel(
    const float* __restrict__ part, const float* __restrict__ part2,
    unsigned short* __restrict__ ctxA)
{
    int o = (blockIdx.x * 256 + threadIdx.x) * 4;
    int p = o >> 12, d = (o >> 6) & 63, e0 = o & 63;
    f32x4 s = {0.f, 0.f, 0.f, 0.f};
    for (int ch = 0; ch < 8; ch++)
        s += *(const f32x4*)&part[(long)(p * 8 + ch) * 4096 + d * 64 + e0];
#pragma unroll
    for (int j = 0; j < 4; j++) ctxA[p * 5120 + (e0 + j) * 64 + d] = f2bf(s[j]);
    if (e0 == 0) {
        float ksv = 0.f;
#pragma unroll
        for (int ch = 0; ch < 8; ch++) ksv += part2[(p * 8 + ch) * 64 + d];
        ctxA[p * 5120 + 4096 + d] = f2bf(ksv);
#pragma unroll
        for (int j = 1; j < 16; j++) ctxA[p * 5120 + 4096 + j * 64 + d] = 0;
    }
}

// out = phiQ @ [ctx | ksum]; ni=4 accumulates denominator; normalize -> bf16
__global__ __launch_bounds__(256) void attn_out_kernel(
    unsigned short* __restrict__ kv,
    const unsigned short* __restrict__ ctxA)
{
    const int p = blockIdx.x;
    const int b = p >> 3, h = p & 7;
    const int t = threadIdx.x, w = t >> 6, l = t & 63, lr = l & 15, lg = l >> 4;
    const int s0 = blockIdx.y * 256 + w * 64;
    f32x4 acc[4][5];
#pragma unroll
    for (int i = 0; i < 4; i++)
#pragma unroll
        for (int j = 0; j < 5; j++) acc[i][j] = f32x4{0.f, 0.f, 0.f, 0.f};
    const unsigned short* cb = ctxA + p * 5120;
#pragma unroll
    for (int kk = 0; kk < 2; kk++) {
        short8 af[4], bfv[5];
#pragma unroll
        for (int mi = 0; mi < 4; mi++) {
            int s = s0 + mi * 16 + lr;
            af[mi] = *(const short8*)&kv[((long)s * 8 + b) * 1024 + 512 + h * 64 + kk * 32 + lg * 8];
        }
#pragma unroll
        for (int ni = 0; ni < 5; ni++)
            bfv[ni] = *(const short8*)&cb[(ni * 16 + lr) * 64 + kk * 32 + lg * 8];
#pragma unroll
        for (int mi = 0; mi < 4; mi++)
#pragma unroll
            for (int ni = 0; ni < 5; ni++)
                acc[mi][ni] = __builtin_amdgcn_mfma_f32_16x16x32_bf16(
                    af[mi], bfv[ni], acc[mi][ni], 0, 0, 0);
    }
#pragma unroll
    for (int mi = 0; mi < 4; mi++) {
#pragma unroll
        for (int j = 0; j < 4; j++) {
            float den = __shfl(acc[mi][4][j], (l & 48));
            float rc  = 1.0f / (den + 1e-6f);
            int s = s0 + mi * 16 + lg * 4 + j;
            long base = ((long)s * 8 + b) * 1024 + h * 64;
#pragma unroll
            for (int ni = 0; ni < 4; ni++)
                kv[base + ni * 16 + lr] = f2bf(acc[mi][ni][j] * rc);
        }
    }
}

// ---------------------------------------------------------------------------
// small helpers
// ---------------------------------------------------------------------------
__global__ __launch_bounds__(256) void cvtbf_kernel(
    const float* __restrict__ x, unsigned short* __restrict__ y)
{
    long i = ((long)blockIdx.x * 256 + threadIdx.x) * 8;
    f32x4 a = *(const f32x4*)&x[i];
    f32x4 c = *(const f32x4*)&x[i + 4];
    short8 pk;
#pragma unroll
    for (int j = 0; j < 4; j++) { pk[j] = (short)f2bf(a[j]); pk[4 + j] = (short)f2bf(c[j]); }
    *(short8*)&y[i] = pk;
}

__global__ __launch_bounds__(256) void bcat_kernel(
    const float* __restrict__ bk, const float* __restrict__ bv, float* __restrict__ dst)
{
    int lyr = blockIdx.x;
    int j = blockIdx.y * 256 + threadIdx.x;
    dst[lyr * 1024 + j] = (j < 512) ? bk[lyr * 512 + j] : bv[lyr * 512 + j - 512];
}

// weight transpose + convert: Wt[n][k] = (bf16) W[k][n], per-layer strides
__global__ __launch_bounds__(256) void wconv_kernel(
    const float* __restrict__ W, unsigned short* __restrict__ Wt, int K, int N,
    long lstrW, long lstrT)
{
    __shared__ float tile[64 * 65];
    const long lz = blockIdx.z;
    const float* Wl = W + lz * lstrW;
    unsigned short* Wtl = Wt + lz * lstrT;
    const int k0 = blockIdx.x * 64, n0 = blockIdx.y * 64;
    const int t = threadIdx.x;
#pragma unroll
    for (int i = 0; i < 4; i++) {
        int q = i * 256 + t;
        int r = q >> 4, c4 = q & 15;
        f32x4 v = *(const f32x4*)&Wl[(long)(k0 + r) * N + n0 + c4 * 4];
#pragma unroll
        for (int j = 0; j < 4; j++) tile[r * 65 + c4 * 4 + j] = v[j];
    }
    __syncthreads();
#pragma unroll
    for (int i = 0; i < 4; i++) {
        int q = i * 256 + t;
        int nr = q >> 4, kc = q & 15;
        ushort4v pk;
#pragma unroll
        for (int j = 0; j < 4; j++) pk[j] = f2bf(tile[(kc * 4 + j) * 65 + nr]);
        *(ushort4v*)&Wtl[(long)(n0 + nr) * K + k0 + kc * 4] = pk;
    }
}

// ---------------------------------------------------------------------------
// Host orchestration.  ws ~121 MiB:
//  [WKV 4M][WQ 2M][WO 2M][W1 4M][W2 4M][BKV 16K][R1 32M][KV 64M][KSP][CTP 8M][CTA]
// f32 residual stream F1 = d_out (in-place RMW in gemm_ln; final LN2 leaves
// the answer there). R1 = bf16 stream copy (GEMM inputs).
// KV: {K|V} -> {ATTN|phiQ} -> HBF(64M).
// ---------------------------------------------------------------------------
extern "C" void kernel_launch(void* const* d_in, const int* in_sizes, int n_in,
                              void* d_out, int out_size, void* d_ws, size_t ws_size,
                              hipStream_t stream)
{
    const float* src  = (const float*)d_in[0];
    const float* Wq   = (const float*)d_in[1];
    const float* bq   = (const float*)d_in[2];
    const float* Wk   = (const float*)d_in[3];
    const float* bk   = (const float*)d_in[4];
    const float* Wv   = (const float*)d_in[5];
    const float* bv   = (const float*)d_in[6];
    const float* Wo   = (const float*)d_in[7];
    const float* bo   = (const float*)d_in[8];
    const float* l1g  = (const float*)d_in[9];
    const float* l1b  = (const float*)d_in[10];
    const float* W1   = (const float*)d_in[11];
    const float* b1   = (const float*)d_in[12];
    const float* W2   = (const float*)d_in[13];
    const float* b2   = (const float*)d_in[14];
    const float* l2g  = (const float*)d_in[15];
    const float* l2b  = (const float*)d_in[16];

    char* ws = (char*)d_ws;
    constexpr size_t SZ_WKV = (size_t)4 * 1024 * 512 * 2;
    constexpr size_t SZ_WQ  = (size_t)4 * 512 * 512 * 2;
    constexpr size_t SZ_WO  = SZ_WQ;
    constexpr size_t SZ_W1  = (size_t)4 * 512 * 1024 * 2;
    constexpr size_t SZ_W2  = SZ_W1;
    constexpr size_t SZ_BKV = (size_t)4 * 1024 * 4;
    constexpr size_t SZ_R1  = (size_t)32768 * 512 * 2;
    constexpr size_t SZ_KV  = (size_t)32768 * 1024 * 2;
    constexpr size_t OFF_WKV = 0;
    constexpr size_t OFF_WQ  = OFF_WKV + SZ_WKV;
    constexpr size_t OFF_WO  = OFF_WQ + SZ_WQ;
    constexpr size_t OFF_W1  = OFF_WO + SZ_WO;
    constexpr size_t OFF_W2  = OFF_W1 + SZ_W1;
    constexpr size_t OFF_BKV = OFF_W2 + SZ_W2;
    constexpr size_t OFF_R1  = OFF_BKV + SZ_BKV;
    constexpr size_t OFF_KV  = OFF_R1 + SZ_R1;
    constexpr size_t OFF_KSP = OFF_KV + SZ_KV;
    constexpr size_t OFF_CTP = OFF_KSP + (size_t)16 * 4096 * 4;
    constexpr size_t OFF_CTA = OFF_CTP + (size_t)64 * 8 * 4096 * 4;

    unsigned short* WKVT = (unsigned short*)(ws + OFF_WKV);
    unsigned short* WQT  = (unsigned short*)(ws + OFF_WQ);
    unsigned short* WOT  = (unsigned short*)(ws + OFF_WO);
    unsigned short* W1T  = (unsigned short*)(ws + OFF_W1);
    unsigned short* W2T  = (unsigned short*)(ws + OFF_W2);
    float*          BKV  = (float*)(ws + OFF_BKV);
    unsigned short* R1   = (unsigned short*)(ws + OFF_R1);
    unsigned short* KV   = (unsigned short*)(ws + OFF_KV);
    float*          KSP  = (float*)(ws + OFF_KSP);
    float*          CTP  = (float*)(ws + OFF_CTP);
    unsigned short* CTA  = (unsigned short*)(ws + OFF_CTA);
    float*          F1   = (float*)d_out;    // f32 residual stream

    dim3 blk(256);
    wconv_kernel<<<dim3(8, 8, 4),  blk, 0, stream>>>(Wk, WKVT,            512, 512, 512*512, 1024*512);
    wconv_kernel<<<dim3(8, 8, 4),  blk, 0, stream>>>(Wv, WKVT + 512*512,  512, 512, 512*512, 1024*512);
    wconv_kernel<<<dim3(8, 8, 4),  blk, 0, stream>>>(Wq, WQT,             512, 512, 512*512, 512*512);
    wconv_kernel<<<dim3(8, 8, 4),  blk, 0, stream>>>(Wo, WOT,             512, 512, 512*512, 512*512);
    wconv_kernel<<<dim3(8, 16, 4), blk, 0, stream>>>(W1, W1T,             512, 1024, 512*1024, 512*1024);
    wconv_kernel<<<dim3(16, 8, 4), blk, 0, stream>>>(W2, W2T,             1024, 512, 1024*512, 1024*512);
    bcat_kernel<<<dim3(4, 4), blk, 0, stream>>>(bk, bv, BKV);
    cvtbf_kernel<<<8192, blk, 0, stream>>>(src, R1);

    for (int lyr = 0; lyr < 4; lyr++) {
        const unsigned short* wkvt = WKVT + (size_t)lyr * 1024 * 512;
        const unsigned short* wqt  = WQT  + (size_t)lyr * 512 * 512;
        const unsigned short* wot  = WOT  + (size_t)lyr * 512 * 512;
        const unsigned short* w1t  = W1T  + (size_t)lyr * 512 * 1024;
        const unsigned short* w2t  = W2T  + (size_t)lyr * 1024 * 512;

        // K|V fused GEMM (elu on cols<512), N=1024 -> nshift=3, grid 2048
        gemm_kernel<0><<<2048, blk, 0, stream>>>(R1, 512, wkvt, BKV + lyr * 1024, KV, 1024, 3, 512);

        // ctx + ksum in one pass over KV
        ctx_partial_kernel<<<dim3(64, 8), blk, 0, stream>>>(KV, CTP, KSP);
        ctx_reduce_kernel<<<256, blk, 0, stream>>>(CTP, KSP, CTA);

        // phiQ into V slot (dead), N=512 -> nshift=2, grid 1024
        gemm_kernel<0><<<1024, blk, 0, stream>>>(R1, 512, wqt, bq + lyr * 512, KV + 512, 1024, 2, 512);
        attn_out_kernel<<<dim3(64, 16), blk, 0, stream>>>(KV, CTA);

        // Wo + residual + LN1 -> F1(f32) in-place, bf16 to R1
        const float* resp = (lyr == 0) ? src : F1;
        gemm_ln_kernel<<<256, dim3(512), 0, stream>>>(KV, 1024, wot, bo + lyr * 512, resp,
                                                      l1g + lyr * 512, l1b + lyr * 512,
                                                      F1, R1, 512);
        // FFN up + relu -> HBF (KV region, dead), N=1024 -> nshift=3
        gemm_kernel<2><<<2048, blk, 0, stream>>>(R1, 512, w1t, b1 + lyr * 1024, KV, 1024, 3, 512);
        // FFN down + residual + LN2 -> F1 in-place, bf16 to R1 (next input)
        gemm_ln_kernel<<<256, dim3(512), 0, stream>>>(KV, 1024, w2t, b2 + lyr * 512, F1,
                                                      l2g + lyr * 512, l2b + lyr * 512,
                                                      F1, R1, 1024);
    }
}

// Round 9
// 1333.137 us; speedup vs baseline: 2.3766x; 2.3766x over previous
//
#include <hip/hip_runtime.h>
#include <hip/hip_bf16.h>
#include <cstdint>

typedef __attribute__((ext_vector_type(8))) short short8;
typedef __attribute__((ext_vector_type(4))) float f32x4;
typedef __attribute__((ext_vector_type(4))) unsigned short ushort4v;

#define DEV static __device__ __forceinline__

DEV float bf2f(unsigned short u) {
    union { unsigned int i; float f; } v; v.i = ((unsigned int)u) << 16; return v.f;
}
DEV unsigned short f2bf(float f) {
    union { float f; unsigned int i; } v; v.f = f;
    unsigned int x = v.i;
    unsigned int r = x + 0x7fffu + ((x >> 16) & 1u);
    return (unsigned short)(r >> 16);
}

// ---------------------------------------------------------------------------
// GEMM: C[M,N] = A[M,K](bf16, row-stride lda) @ Wt[N,K]^T + bias -> bf16 (ldc)
// 128x128 tile, 4 waves, 16x16x32 MFMA, BK=64, single-buffer LDS, XCD-aware
// 1D-grid swizzle (r7-measured best).
// EPI 0: elu+1 applied iff col<512 | EPI 2: relu
// ---------------------------------------------------------------------------
template<int EPI>
__global__ __launch_bounds__(256) void gemm_kernel(
    const unsigned short* __restrict__ A, int lda,
    const unsigned short* __restrict__ Bt,
    const float* __restrict__ bias,
    unsigned short* __restrict__ outp, int ldc,
    int nshift, int K)
{
    __shared__ unsigned short lds[128 * 136];
    const int t  = threadIdx.x;
    const int w  = t >> 6, l = t & 63;
    const int wr = w >> 1, wc = w & 1;
    const int lr = l & 15, lg = l >> 4;
    const int bid = blockIdx.x;
    const int j8  = bid & 7, s = bid >> 3;
    const int bx  = j8 * 32 + (s >> nshift);
    const int by  = s & ((1 << nshift) - 1);
    const long tM = (long)bx * 128;
    const long tN = (long)by * 128;

    f32x4 acc[4][4];
#pragma unroll
    for (int i = 0; i < 4; i++)
#pragma unroll
        for (int j = 0; j < 4; j++) acc[i][j] = f32x4{0.f, 0.f, 0.f, 0.f};

    const unsigned short* Ab = A  + tM * lda;
    const unsigned short* Bb = Bt + tN * K;

    for (int kt = 0; kt < K; kt += 64) {
#pragma unroll
        for (int j = 0; j < 4; j++) {
            int c = (w * 4 + j) * 64 + l;
            int row = c >> 3, sc = (c & 7) ^ (row & 7);
            __builtin_amdgcn_global_load_lds(
                (const __attribute__((address_space(1))) void*)(Ab + (long)row * lda + kt + sc * 8),
                (__attribute__((address_space(3))) void*)(lds + (w * 4 + j) * 512),
                16, 0, 0);
        }
#pragma unroll
        for (int j = 0; j < 4; j++) {
            int c = (w * 4 + j) * 64 + l;
            int row = c >> 3, sc = (c & 7) ^ (row & 7);
            __builtin_amdgcn_global_load_lds(
                (const __attribute__((address_space(1))) void*)(Bb + (long)row * K + kt + sc * 8),
                (__attribute__((address_space(3))) void*)(lds + 8192 + (w * 4 + j) * 512),
                16, 0, 0);
        }
        __syncthreads();
#pragma unroll
        for (int kk = 0; kk < 2; kk++) {
            short8 af[4], bfv[4];
#pragma unroll
            for (int mi = 0; mi < 4; mi++) {
                int r  = wr * 64 + mi * 16 + lr;
                int kc = kk * 4 + lg;
                af[mi] = *(const short8*)&lds[r * 64 + ((kc ^ (r & 7)) << 3)];
            }
#pragma unroll
            for (int ni = 0; ni < 4; ni++) {
                int n  = wc * 64 + ni * 16 + lr;
                int kc = kk * 4 + lg;
                bfv[ni] = *(const short8*)&lds[8192 + n * 64 + ((kc ^ (n & 7)) << 3)];
            }
#pragma unroll
            for (int mi = 0; mi < 4; mi++)
#pragma unroll
                for (int ni = 0; ni < 4; ni++)
                    acc[mi][ni] = __builtin_amdgcn_mfma_f32_16x16x32_bf16(
                        af[mi], bfv[ni], acc[mi][ni], 0, 0, 0);
        }
        __syncthreads();
    }

    float bv[4];
#pragma unroll
    for (int ni = 0; ni < 4; ni++) bv[ni] = bias[tN + wc * 64 + ni * 16 + lr];
    const bool doElu = (EPI == 0) && (tN < 512);

#pragma unroll
    for (int mi = 0; mi < 4; mi++)
#pragma unroll
        for (int ni = 0; ni < 4; ni++)
#pragma unroll
            for (int j = 0; j < 4; j++) {
                float v = acc[mi][ni][j] + bv[ni];
                if (EPI == 0) { if (doElu) v = (v > 0.f) ? (v + 1.f) : expf(v); }
                if (EPI == 2) v = fmaxf(v, 0.f);
                int r = wr * 64 + mi * 16 + lg * 4 + j;
                int c = wc * 64 + ni * 16 + lr;
                lds[r * 136 + c] = f2bf(v);
            }
    __syncthreads();
#pragma unroll
    for (int i = 0; i < 8; i++) {
        int q = i * 256 + t;
        int r = q >> 4, cc = q & 15;
        short8 v8 = *(const short8*)&lds[r * 136 + cc * 8];
        *(short8*)&outp[(tM + r) * ldc + tN + cc * 8] = v8;
    }
}

// ---------------------------------------------------------------------------
// Fused GEMM + bias + residual(f32) + LayerNorm (r7-proven body).
// BM=128, 512 thr / 8 waves; wave (wr,wc): rows wr*64+[0,64), cols
// wc*128+[0,128). BK=64, fat-gemm swizzle (0 bank conflicts).
// LDS = sA 16K + sB 64K = 80KiB EXACTLY (red/stats aliased into sA, which is
// dead after the last K-loop barrier) -> 2 blocks/CU at VGPR=128 (was 85KB ->
// 1 block/CU, occupancy 19.9%). NO min-wave bound (r8 lesson: (512,4) caused
// accumulator spill -> 1GB scratch traffic).
// y = LN(A@Wt^T + bias + res); writes y to f32 `of` and bf16 `ob`.
// res may alias of (per-elem read-before-write by owning thread).
// ---------------------------------------------------------------------------
__global__ __launch_bounds__(512) void gemm_ln_kernel(
    const unsigned short* __restrict__ A, int lda,
    const unsigned short* __restrict__ Bt,   // [512][K]
    const float* __restrict__ bias,          // [512]
    const float* __restrict__ res,           // [M][512] f32
    const float* __restrict__ g,
    const float* __restrict__ be,
    float* __restrict__ of,                  // [M][512] f32
    unsigned short* __restrict__ ob,         // [M][512] bf16
    int K)
{
    __shared__ unsigned short sA[128 * 64];   // 16 KiB; epilogue: red/stats alias
    __shared__ unsigned short sB[512 * 64];   // 64 KiB
    float* redb = (float*)sA;                 // [2][4][128] = 4 KiB
    float* statb = redb + 1024;               // [2][128] = 1 KiB
    const int t = threadIdx.x, w = t >> 6, l = t & 63, lr = l & 15, lg = l >> 4;
    const int wr = w >> 2, wc = w & 3;
    const long tM = (long)blockIdx.x * 128;

    f32x4 acc[4][8];
#pragma unroll
    for (int i = 0; i < 4; i++)
#pragma unroll
        for (int j = 0; j < 8; j++) acc[i][j] = f32x4{0.f, 0.f, 0.f, 0.f};

    const unsigned short* Ab = A + tM * lda;

    for (int kt = 0; kt < K; kt += 64) {
#pragma unroll
        for (int j = 0; j < 2; j++) {
            int c = j * 512 + t;                // 128 rows x 8 chunks
            int row = c >> 3, sc = (c & 7) ^ (row & 7);
            __builtin_amdgcn_global_load_lds(
                (const __attribute__((address_space(1))) void*)(Ab + (long)row * lda + kt + sc * 8),
                (__attribute__((address_space(3))) void*)(sA + (j * 512 + w * 64) * 8),
                16, 0, 0);
        }
#pragma unroll
        for (int j = 0; j < 8; j++) {           // 512 rows x 8 chunks
            int c = j * 512 + t;
            int row = c >> 3, sc = (c & 7) ^ (row & 7);
            __builtin_amdgcn_global_load_lds(
                (const __attribute__((address_space(1))) void*)(Bt + (long)row * K + kt + sc * 8),
                (__attribute__((address_space(3))) void*)(sB + (j * 512 + w * 64) * 8),
                16, 0, 0);
        }
        __syncthreads();
#pragma unroll
        for (int kk = 0; kk < 2; kk++) {
            short8 av[4], bw[8];
#pragma unroll
            for (int mi = 0; mi < 4; mi++) {
                int r = wr * 64 + mi * 16 + lr, kc = kk * 4 + lg;
                av[mi] = *(const short8*)&sA[r * 64 + ((kc ^ (r & 7)) << 3)];
            }
#pragma unroll
            for (int ni = 0; ni < 8; ni++) {
                int n = wc * 128 + ni * 16 + lr, kc = kk * 4 + lg;
                bw[ni] = *(const short8*)&sB[n * 64 + ((kc ^ (n & 7)) << 3)];
            }
#pragma unroll
            for (int mi = 0; mi < 4; mi++)
#pragma unroll
                for (int ni = 0; ni < 8; ni++)
                    acc[mi][ni] = __builtin_amdgcn_mfma_f32_16x16x32_bf16(
                        av[mi], bw[ni], acc[mi][ni], 0, 0, 0);
        }
        __syncthreads();
    }

    // epilogue: v = C + bias + res; LN over the 512-wide row. sA now dead ->
    // red/stats live in its space (aliased above; all waves past last barrier).
    float gv[8], bev[8], bb[8];
#pragma unroll
    for (int ni = 0; ni < 8; ni++) {
        int col = wc * 128 + ni * 16 + lr;
        gv[ni] = g[col]; bev[ni] = be[col]; bb[ni] = bias[col];
    }
#pragma unroll
    for (int mi = 0; mi < 4; mi++)
#pragma unroll
        for (int jj = 0; jj < 4; jj++) {
            long row = tM + wr * 64 + mi * 16 + lg * 4 + jj;
#pragma unroll
            for (int ni = 0; ni < 8; ni++) {
                int col = wc * 128 + ni * 16 + lr;
                acc[mi][ni][jj] += bb[ni] + res[row * 512 + col];
            }
        }
    float s2[4][4], ss2[4][4];
#pragma unroll
    for (int mi = 0; mi < 4; mi++)
#pragma unroll
        for (int jj = 0; jj < 4; jj++) {
            float s = 0.f, ss = 0.f;
#pragma unroll
            for (int ni = 0; ni < 8; ni++) {
                float v = acc[mi][ni][jj];
                s += v; ss += v * v;
            }
#pragma unroll
            for (int off = 1; off < 16; off <<= 1) {
                s  += __shfl_xor(s, off);
                ss += __shfl_xor(ss, off);
            }
            s2[mi][jj] = s; ss2[mi][jj] = ss;
        }
    __syncthreads();   // ensure all sA reads (none remain) / ordering before alias write
    if (lr == 0) {
#pragma unroll
        for (int mi = 0; mi < 4; mi++)
#pragma unroll
            for (int jj = 0; jj < 4; jj++) {
                int rb = wr * 64 + mi * 16 + lg * 4 + jj;
                redb[0 * 512 + wc * 128 + rb] = s2[mi][jj];
                redb[1 * 512 + wc * 128 + rb] = ss2[mi][jj];
            }
    }
    __syncthreads();
    if (t < 128) {
        float S  = redb[t] + redb[128 + t] + redb[256 + t] + redb[384 + t];
        float SS = redb[512 + t] + redb[640 + t] + redb[768 + t] + redb[896 + t];
        float mean = S * (1.0f / 512.0f);
        float var  = SS * (1.0f / 512.0f) - mean * mean;
        statb[t] = mean;
        statb[128 + t] = rsqrtf(fmaxf(var, 0.f) + 1e-5f);
    }
    __syncthreads();
#pragma unroll
    for (int mi = 0; mi < 4; mi++)
#pragma unroll
        for (int jj = 0; jj < 4; jj++) {
            int rb = wr * 64 + mi * 16 + lg * 4 + jj;
            long row = tM + rb;
            float mean = statb[rb], rstd = statb[128 + rb];
#pragma unroll
            for (int ni = 0; ni < 8; ni++) {
                int col = wc * 128 + ni * 16 + lr;
                float y = (acc[mi][ni][jj] - mean) * rstd * gv[ni] + bev[ni];
                of[row * 512 + col] = y;
                ob[row * 512 + col] = f2bf(y);
            }
        }
}

// ---------------------------------------------------------------------------
// Attention glue. KVbuf[(s*8+b)][1024]: cols 0..511 = phiK (later ATTN),
// cols 512..1023 = V (later phiQ).
// ctx_partial also accumulates ksum_d = sum_s phiK[s][d] (part2).
// ---------------------------------------------------------------------------
__global__ __launch_bounds__(256) void ctx_partial_kernel(
    const unsigned short* __restrict__ kv, float* __restrict__ part,
    float* __restrict__ part2)
{
    const int p = blockIdx.x, ch = blockIdx.y;
    const int b = p >> 3, h = p & 7;
    __shared__ float kb[64 * 68];
    __shared__ float vbuf[64 * 68];
    const int t = threadIdx.x;
    const int dq = t >> 4, eq = t & 15;
    f32x4 acc[4];
    f32x4 ks = {0.f, 0.f, 0.f, 0.f};
#pragma unroll
    for (int i = 0; i < 4; i++) acc[i] = f32x4{0.f, 0.f, 0.f, 0.f};

    for (int sub = 0; sub < 8; sub++) {
        int sbase = ch * 512 + sub * 64;
#pragma unroll
        for (int i = 0; i < 2; i++) {
            int idx = i * 256 + t;
            int row = idx >> 3, c8 = idx & 7;
            long ga = ((long)(sbase + row) * 8 + b) * 1024 + h * 64 + c8 * 8;
            short8 kvv = *(const short8*)&kv[ga];
            short8 vv  = *(const short8*)&kv[ga + 512];
#pragma unroll
            for (int j = 0; j < 8; j++) {
                kb[row * 68 + c8 * 8 + j]   = bf2f((unsigned short)kvv[j]);
                vbuf[row * 68 + c8 * 8 + j] = bf2f((unsigned short)vv[j]);
            }
        }
        __syncthreads();
        for (int s = 0; s < 64; s++) {
            f32x4 k4 = *(const f32x4*)&kb[s * 68 + dq * 4];
            f32x4 v4 = *(const f32x4*)&vbuf[s * 68 + eq * 4];
#pragma unroll
            for (int i = 0; i < 4; i++) acc[i] += k4[i] * v4;
            ks += k4;
        }
        __syncthreads();
    }
    float* o = part + (long)(p * 8 + ch) * 4096;
#pragma unroll
    for (int i = 0; i < 4; i++)
        *(f32x4*)&o[(dq * 4 + i) * 64 + eq * 4] = acc[i];
    if (eq == 0)
        *(f32x4*)&part2[(p * 8 + ch) * 64 + dq * 4] = ks;
}

// reduce ctx partials -> ctxA[p][n=e][k=d] (bf16, transposed); finalize ksum
// into row n=64, zero rows 65..79
__global__ __launch_bounds__(256) void ctx_reduce_kernel(
    const float* __restrict__ part, const float* __restrict__ part2,
    unsigned short* __restrict__ ctxA)
{
    int o = (blockIdx.x * 256 + threadIdx.x) * 4;
    int p = o >> 12, d = (o >> 6) & 63, e0 = o & 63;
    f32x4 s = {0.f, 0.f, 0.f, 0.f};
    for (int ch = 0; ch < 8; ch++)
        s += *(const f32x4*)&part[(long)(p * 8 + ch) * 4096 + d * 64 + e0];
#pragma unroll
    for (int j = 0; j < 4; j++) ctxA[p * 5120 + (e0 + j) * 64 + d] = f2bf(s[j]);
    if (e0 == 0) {
        float ksv = 0.f;
#pragma unroll
        for (int ch = 0; ch < 8; ch++) ksv += part2[(p * 8 + ch) * 64 + d];
        ctxA[p * 5120 + 4096 + d] = f2bf(ksv);
#pragma unroll
        for (int j = 1; j < 16; j++) ctxA[p * 5120 + 4096 + j * 64 + d] = 0;
    }
}

// out = phiQ @ [ctx | ksum]; ni=4 accumulates denominator; normalize -> bf16
__global__ __launch_bounds__(256) void attn_out_kernel(
    unsigned short* __restrict__ kv,
    const unsigned short* __restrict__ ctxA)
{
    const int p = blockIdx.x;
    const int b = p >> 3, h = p & 7;
    const int t = threadIdx.x, w = t >> 6, l = t & 63, lr = l & 15, lg = l >> 4;
    const int s0 = blockIdx.y * 256 + w * 64;
    f32x4 acc[4][5];
#pragma unroll
    for (int i = 0; i < 4; i++)
#pragma unroll
        for (int j = 0; j < 5; j++) acc[i][j] = f32x4{0.f, 0.f, 0.f, 0.f};
    const unsigned short* cb = ctxA + p * 5120;
#pragma unroll
    for (int kk = 0; kk < 2; kk++) {
        short8 af[4], bfv[5];
#pragma unroll
        for (int mi = 0; mi < 4; mi++) {
            int s = s0 + mi * 16 + lr;
            af[mi] = *(const short8*)&kv[((long)s * 8 + b) * 1024 + 512 + h * 64 + kk * 32 + lg * 8];
        }
#pragma unroll
        for (int ni = 0; ni < 5; ni++)
            bfv[ni] = *(const short8*)&cb[(ni * 16 + lr) * 64 + kk * 32 + lg * 8];
#pragma unroll
        for (int mi = 0; mi < 4; mi++)
#pragma unroll
            for (int ni = 0; ni < 5; ni++)
                acc[mi][ni] = __builtin_amdgcn_mfma_f32_16x16x32_bf16(
                    af[mi], bfv[ni], acc[mi][ni], 0, 0, 0);
    }
#pragma unroll
    for (int mi = 0; mi < 4; mi++) {
#pragma unroll
        for (int j = 0; j < 4; j++) {
            float den = __shfl(acc[mi][4][j], (l & 48));
            float rc  = 1.0f / (den + 1e-6f);
            int s = s0 + mi * 16 + lg * 4 + j;
            long base = ((long)s * 8 + b) * 1024 + h * 64;
#pragma unroll
            for (int ni = 0; ni < 4; ni++)
                kv[base + ni * 16 + lr] = f2bf(acc[mi][ni][j] * rc);
        }
    }
}

// ---------------------------------------------------------------------------
// small helpers
// ---------------------------------------------------------------------------
__global__ __launch_bounds__(256) void cvtbf_kernel(
    const float* __restrict__ x, unsigned short* __restrict__ y)
{
    long i = ((long)blockIdx.x * 256 + threadIdx.x) * 8;
    f32x4 a = *(const f32x4*)&x[i];
    f32x4 c = *(const f32x4*)&x[i + 4];
    short8 pk;
#pragma unroll
    for (int j = 0; j < 4; j++) { pk[j] = (short)f2bf(a[j]); pk[4 + j] = (short)f2bf(c[j]); }
    *(short8*)&y[i] = pk;
}

__global__ __launch_bounds__(256) void bcat_kernel(
    const float* __restrict__ bk, const float* __restrict__ bv, float* __restrict__ dst)
{
    int lyr = blockIdx.x;
    int j = blockIdx.y * 256 + threadIdx.x;
    dst[lyr * 1024 + j] = (j < 512) ? bk[lyr * 512 + j] : bv[lyr * 512 + j - 512];
}

// weight transpose + convert: Wt[n][k] = (bf16) W[k][n], per-layer strides
__global__ __launch_bounds__(256) void wconv_kernel(
    const float* __restrict__ W, unsigned short* __restrict__ Wt, int K, int N,
    long lstrW, long lstrT)
{
    __shared__ float tile[64 * 65];
    const long lz = blockIdx.z;
    const float* Wl = W + lz * lstrW;
    unsigned short* Wtl = Wt + lz * lstrT;
    const int k0 = blockIdx.x * 64, n0 = blockIdx.y * 64;
    const int t = threadIdx.x;
#pragma unroll
    for (int i = 0; i < 4; i++) {
        int q = i * 256 + t;
        int r = q >> 4, c4 = q & 15;
        f32x4 v = *(const f32x4*)&Wl[(long)(k0 + r) * N + n0 + c4 * 4];
#pragma unroll
        for (int j = 0; j < 4; j++) tile[r * 65 + c4 * 4 + j] = v[j];
    }
    __syncthreads();
#pragma unroll
    for (int i = 0; i < 4; i++) {
        int q = i * 256 + t;
        int nr = q >> 4, kc = q & 15;
        ushort4v pk;
#pragma unroll
        for (int j = 0; j < 4; j++) pk[j] = f2bf(tile[(kc * 4 + j) * 65 + nr]);
        *(ushort4v*)&Wtl[(long)(n0 + nr) * K + k0 + kc * 4] = pk;
    }
}

// ---------------------------------------------------------------------------
// Host orchestration.  ws ~121 MiB:
//  [WKV 4M][WQ 2M][WO 2M][W1 4M][W2 4M][BKV 16K][R1 32M][KV 64M][KSP][CTP 8M][CTA]
// f32 residual stream F1 = d_out (in-place RMW in gemm_ln; final LN2 leaves
// the answer there). R1 = bf16 stream copy (GEMM inputs).
// KV: {K|V} -> {ATTN|phiQ} -> HBF(64M).
// ---------------------------------------------------------------------------
extern "C" void kernel_launch(void* const* d_in, const int* in_sizes, int n_in,
                              void* d_out, int out_size, void* d_ws, size_t ws_size,
                              hipStream_t stream)
{
    const float* src  = (const float*)d_in[0];
    const float* Wq   = (const float*)d_in[1];
    const float* bq   = (const float*)d_in[2];
    const float* Wk   = (const float*)d_in[3];
    const float* bk   = (const float*)d_in[4];
    const float* Wv   = (const float*)d_in[5];
    const float* bv   = (const float*)d_in[6];
    const float* Wo   = (const float*)d_in[7];
    const float* bo   = (const float*)d_in[8];
    const float* l1g  = (const float*)d_in[9];
    const float* l1b  = (const float*)d_in[10];
    const float* W1   = (const float*)d_in[11];
    const float* b1   = (const float*)d_in[12];
    const float* W2   = (const float*)d_in[13];
    const float* b2   = (const float*)d_in[14];
    const float* l2g  = (const float*)d_in[15];
    const float* l2b  = (const float*)d_in[16];

    char* ws = (char*)d_ws;
    constexpr size_t SZ_WKV = (size_t)4 * 1024 * 512 * 2;
    constexpr size_t SZ_WQ  = (size_t)4 * 512 * 512 * 2;
    constexpr size_t SZ_WO  = SZ_WQ;
    constexpr size_t SZ_W1  = (size_t)4 * 512 * 1024 * 2;
    constexpr size_t SZ_W2  = SZ_W1;
    constexpr size_t SZ_BKV = (size_t)4 * 1024 * 4;
    constexpr size_t SZ_R1  = (size_t)32768 * 512 * 2;
    constexpr size_t SZ_KV  = (size_t)32768 * 1024 * 2;
    constexpr size_t OFF_WKV = 0;
    constexpr size_t OFF_WQ  = OFF_WKV + SZ_WKV;
    constexpr size_t OFF_WO  = OFF_WQ + SZ_WQ;
    constexpr size_t OFF_W1  = OFF_WO + SZ_WO;
    constexpr size_t OFF_W2  = OFF_W1 + SZ_W1;
    constexpr size_t OFF_BKV = OFF_W2 + SZ_W2;
    constexpr size_t OFF_R1  = OFF_BKV + SZ_BKV;
    constexpr size_t OFF_KV  = OFF_R1 + SZ_R1;
    constexpr size_t OFF_KSP = OFF_KV + SZ_KV;
    constexpr size_t OFF_CTP = OFF_KSP + (size_t)16 * 4096 * 4;
    constexpr size_t OFF_CTA = OFF_CTP + (size_t)64 * 8 * 4096 * 4;

    unsigned short* WKVT = (unsigned short*)(ws + OFF_WKV);
    unsigned short* WQT  = (unsigned short*)(ws + OFF_WQ);
    unsigned short* WOT  = (unsigned short*)(ws + OFF_WO);
    unsigned short* W1T  = (unsigned short*)(ws + OFF_W1);
    unsigned short* W2T  = (unsigned short*)(ws + OFF_W2);
    float*          BKV  = (float*)(ws + OFF_BKV);
    unsigned short* R1   = (unsigned short*)(ws + OFF_R1);
    unsigned short* KV   = (unsigned short*)(ws + OFF_KV);
    float*          KSP  = (float*)(ws + OFF_KSP);
    float*          CTP  = (float*)(ws + OFF_CTP);
    unsigned short* CTA  = (unsigned short*)(ws + OFF_CTA);
    float*          F1   = (float*)d_out;    // f32 residual stream

    dim3 blk(256);
    wconv_kernel<<<dim3(8, 8, 4),  blk, 0, stream>>>(Wk, WKVT,            512, 512, 512*512, 1024*512);
    wconv_kernel<<<dim3(8, 8, 4),  blk, 0, stream>>>(Wv, WKVT + 512*512,  512, 512, 512*512, 1024*512);
    wconv_kernel<<<dim3(8, 8, 4),  blk, 0, stream>>>(Wq, WQT,             512, 512, 512*512, 512*512);
    wconv_kernel<<<dim3(8, 8, 4),  blk, 0, stream>>>(Wo, WOT,             512, 512, 512*512, 512*512);
    wconv_kernel<<<dim3(8, 16, 4), blk, 0, stream>>>(W1, W1T,             512, 1024, 512*1024, 512*1024);
    wconv_kernel<<<dim3(16, 8, 4), blk, 0, stream>>>(W2, W2T,             1024, 512, 1024*512, 1024*512);
    bcat_kernel<<<dim3(4, 4), blk, 0, stream>>>(bk, bv, BKV);
    cvtbf_kernel<<<8192, blk, 0, stream>>>(src, R1);

    for (int lyr = 0; lyr < 4; lyr++) {
        const unsigned short* wkvt = WKVT + (size_t)lyr * 1024 * 512;
        const unsigned short* wqt  = WQT  + (size_t)lyr * 512 * 512;
        const unsigned short* wot  = WOT  + (size_t)lyr * 512 * 512;
        const unsigned short* w1t  = W1T  + (size_t)lyr * 512 * 1024;
        const unsigned short* w2t  = W2T  + (size_t)lyr * 1024 * 512;

        // K|V fused GEMM (elu on cols<512), N=1024 -> nshift=3, grid 2048
        gemm_kernel<0><<<2048, blk, 0, stream>>>(R1, 512, wkvt, BKV + lyr * 1024, KV, 1024, 3, 512);

        // ctx + ksum in one pass over KV
        ctx_partial_kernel<<<dim3(64, 8), blk, 0, stream>>>(KV, CTP, KSP);
        ctx_reduce_kernel<<<256, blk, 0, stream>>>(CTP, KSP, CTA);

        // phiQ into V slot (dead), N=512 -> nshift=2, grid 1024
        gemm_kernel<0><<<1024, blk, 0, stream>>>(R1, 512, wqt, bq + lyr * 512, KV + 512, 1024, 2, 512);
        attn_out_kernel<<<dim3(64, 16), blk, 0, stream>>>(KV, CTA);

        // Wo + residual + LN1 -> F1(f32) in-place, bf16 to R1
        const float* resp = (lyr == 0) ? src : F1;
        gemm_ln_kernel<<<256, dim3(512), 0, stream>>>(KV, 1024, wot, bo + lyr * 512, resp,
                                                      l1g + lyr * 512, l1b + lyr * 512,
                                                      F1, R1, 512);
        // FFN up + relu -> HBF (KV region, dead), N=1024 -> nshift=3
        gemm_kernel<2><<<2048, blk, 0, stream>>>(R1, 512, w1t, b1 + lyr * 1024, KV, 1024, 3, 512);
        // FFN down + residual + LN2 -> F1 in-place, bf16 to R1 (next input)
        gemm_ln_kernel<<<256, dim3(512), 0, stream>>>(KV, 1024, w2t, b2 + lyr * 512, F1,
                                                      l2g + lyr * 512, l2b + lyr * 512,
                                                      F1, R1, 1024);
    }
}

// Round 10
// 1313.865 us; speedup vs baseline: 2.4114x; 1.0147x over previous
//
#include <hip/hip_runtime.h>
#include <hip/hip_bf16.h>
#include <cstdint>

typedef __attribute__((ext_vector_type(8))) short short8;
typedef __attribute__((ext_vector_type(4))) float f32x4;
typedef __attribute__((ext_vector_type(4))) unsigned short ushort4v;

#define DEV static __device__ __forceinline__

DEV float bf2f(unsigned short u) {
    union { unsigned int i; float f; } v; v.i = ((unsigned int)u) << 16; return v.f;
}
DEV unsigned short f2bf(float f) {
    union { float f; unsigned int i; } v; v.f = f;
    unsigned int x = v.i;
    unsigned int r = x + 0x7fffu + ((x >> 16) & 1u);
    return (unsigned short)(r >> 16);
}

// ---------------------------------------------------------------------------
// GEMM: C[M,N] = A[M,K](bf16, row-stride lda) @ Wt[N,K]^T + bias -> bf16 (ldc)
// 128x128 tile, 4 waves, 16x16x32 MFMA, BK=64, single-buffer LDS, XCD-aware
// 1D-grid swizzle (r7-measured best).
// EPI 0: elu+1 applied iff col<512 | EPI 2: relu
// ---------------------------------------------------------------------------
template<int EPI>
__global__ __launch_bounds__(256) void gemm_kernel(
    const unsigned short* __restrict__ A, int lda,
    const unsigned short* __restrict__ Bt,
    const float* __restrict__ bias,
    unsigned short* __restrict__ outp, int ldc,
    int nshift, int K)
{
    __shared__ unsigned short lds[128 * 136];
    const int t  = threadIdx.x;
    const int w  = t >> 6, l = t & 63;
    const int wr = w >> 1, wc = w & 1;
    const int lr = l & 15, lg = l >> 4;
    const int bid = blockIdx.x;
    const int j8  = bid & 7, s = bid >> 3;
    const int bx  = j8 * 32 + (s >> nshift);
    const int by  = s & ((1 << nshift) - 1);
    const long tM = (long)bx * 128;
    const long tN = (long)by * 128;

    f32x4 acc[4][4];
#pragma unroll
    for (int i = 0; i < 4; i++)
#pragma unroll
        for (int j = 0; j < 4; j++) acc[i][j] = f32x4{0.f, 0.f, 0.f, 0.f};

    const unsigned short* Ab = A  + tM * lda;
    const unsigned short* Bb = Bt + tN * K;

    for (int kt = 0; kt < K; kt += 64) {
#pragma unroll
        for (int j = 0; j < 4; j++) {
            int c = (w * 4 + j) * 64 + l;
            int row = c >> 3, sc = (c & 7) ^ (row & 7);
            __builtin_amdgcn_global_load_lds(
                (const __attribute__((address_space(1))) void*)(Ab + (long)row * lda + kt + sc * 8),
                (__attribute__((address_space(3))) void*)(lds + (w * 4 + j) * 512),
                16, 0, 0);
        }
#pragma unroll
        for (int j = 0; j < 4; j++) {
            int c = (w * 4 + j) * 64 + l;
            int row = c >> 3, sc = (c & 7) ^ (row & 7);
            __builtin_amdgcn_global_load_lds(
                (const __attribute__((address_space(1))) void*)(Bb + (long)row * K + kt + sc * 8),
                (__attribute__((address_space(3))) void*)(lds + 8192 + (w * 4 + j) * 512),
                16, 0, 0);
        }
        __syncthreads();
#pragma unroll
        for (int kk = 0; kk < 2; kk++) {
            short8 af[4], bfv[4];
#pragma unroll
            for (int mi = 0; mi < 4; mi++) {
                int r  = wr * 64 + mi * 16 + lr;
                int kc = kk * 4 + lg;
                af[mi] = *(const short8*)&lds[r * 64 + ((kc ^ (r & 7)) << 3)];
            }
#pragma unroll
            for (int ni = 0; ni < 4; ni++) {
                int n  = wc * 64 + ni * 16 + lr;
                int kc = kk * 4 + lg;
                bfv[ni] = *(const short8*)&lds[8192 + n * 64 + ((kc ^ (n & 7)) << 3)];
            }
#pragma unroll
            for (int mi = 0; mi < 4; mi++)
#pragma unroll
                for (int ni = 0; ni < 4; ni++)
                    acc[mi][ni] = __builtin_amdgcn_mfma_f32_16x16x32_bf16(
                        af[mi], bfv[ni], acc[mi][ni], 0, 0, 0);
        }
        __syncthreads();
    }

    float bv[4];
#pragma unroll
    for (int ni = 0; ni < 4; ni++) bv[ni] = bias[tN + wc * 64 + ni * 16 + lr];
    const bool doElu = (EPI == 0) && (tN < 512);

#pragma unroll
    for (int mi = 0; mi < 4; mi++)
#pragma unroll
        for (int ni = 0; ni < 4; ni++)
#pragma unroll
            for (int j = 0; j < 4; j++) {
                float v = acc[mi][ni][j] + bv[ni];
                if (EPI == 0) { if (doElu) v = (v > 0.f) ? (v + 1.f) : expf(v); }
                if (EPI == 2) v = fmaxf(v, 0.f);
                int r = wr * 64 + mi * 16 + lg * 4 + j;
                int c = wc * 64 + ni * 16 + lr;
                lds[r * 136 + c] = f2bf(v);
            }
    __syncthreads();
#pragma unroll
    for (int i = 0; i < 8; i++) {
        int q = i * 256 + t;
        int r = q >> 4, cc = q & 15;
        short8 v8 = *(const short8*)&lds[r * 136 + cc * 8];
        *(short8*)&outp[(tM + r) * ldc + tN + cc * 8] = v8;
    }
}

// ---------------------------------------------------------------------------
// Fused GEMM + bias + residual(f32) + LayerNorm, 2-PHASE DOUBLE-BUFFERED.
// BM=128, 512 thr / 8 waves; wave (wr,wc): rows wr*64+[0,64), cols
// wc*128+[0,128). BK=32 (one MFMA K-depth), dbuf LDS 2x40KB = 80KiB
// (red/stats aliased into buf0 sA). Swizzle sc=(c&3)^((row>>1)&3) is
// HW-verified conflict-free (r8: SQ_LDS_BANK_CONFLICT=0).
// Loop: STAGE(buf^1, t+1); COMPUTE(buf); ONE sync/iter -> loads for t+1 fly
// during MFMA of t (T3-minimum recipe; r9's stage->drain->compute exposed
// full HBM latency each iter at 1 block/CU, 2.2 TB/s).
// NO min-wave bound (r8 lesson: forced cap -> accumulator spill).
// y = LN(A@Wt^T + bias + res); res may alias of (per-elem RMW by owner).
// ---------------------------------------------------------------------------
__global__ __launch_bounds__(512) void gemm_ln_kernel(
    const unsigned short* __restrict__ A, int lda,
    const unsigned short* __restrict__ Bt,   // [512][K]
    const float* __restrict__ bias,          // [512]
    const float* __restrict__ res,           // [M][512] f32
    const float* __restrict__ g,
    const float* __restrict__ be,
    float* __restrict__ of,                  // [M][512] f32
    unsigned short* __restrict__ ob,         // [M][512] bf16
    int K)
{
    __shared__ unsigned short sA[2][128 * 32];   // 2 x 8 KiB
    __shared__ unsigned short sB[2][512 * 32];   // 2 x 32 KiB
    float* redb  = (float*)&sA[0][0];            // [2][4][128] = 4 KiB (epilogue alias)
    float* statb = redb + 1024;                  // [2][128] = 1 KiB
    const int t = threadIdx.x, w = t >> 6, l = t & 63, lr = l & 15, lg = l >> 4;
    const int wr = w >> 2, wc = w & 3;
    const long tM = (long)blockIdx.x * 128;

    f32x4 acc[4][8];
#pragma unroll
    for (int i = 0; i < 4; i++)
#pragma unroll
        for (int j = 0; j < 8; j++) acc[i][j] = f32x4{0.f, 0.f, 0.f, 0.f};

    const unsigned short* Ab = A + tM * lda;

    auto STAGE = [&](int buf, int kt) {
        {   // A: 128 rows x 4 chunks = 512 chunks, 1/thread
            int c = t, row = c >> 2, sc = (c & 3) ^ ((row >> 1) & 3);
            __builtin_amdgcn_global_load_lds(
                (const __attribute__((address_space(1))) void*)(Ab + (long)row * lda + kt + sc * 8),
                (__attribute__((address_space(3))) void*)(&sA[buf][t * 8]),
                16, 0, 0);
        }
#pragma unroll
        for (int j = 0; j < 4; j++) {  // B: 512 rows x 4 chunks = 2048 chunks
            int c = j * 512 + t, row = c >> 2, sc = (c & 3) ^ ((row >> 1) & 3);
            __builtin_amdgcn_global_load_lds(
                (const __attribute__((address_space(1))) void*)(Bt + (long)row * K + kt + sc * 8),
                (__attribute__((address_space(3))) void*)(&sB[buf][c * 8]),
                16, 0, 0);
        }
    };

    auto COMPUTE = [&](int buf) {
        short8 av[4], bw[8];
#pragma unroll
        for (int mi = 0; mi < 4; mi++) {
            int r = wr * 64 + mi * 16 + lr;
            av[mi] = *(const short8*)&sA[buf][r * 32 + ((lg ^ ((r >> 1) & 3)) << 3)];
        }
#pragma unroll
        for (int ni = 0; ni < 8; ni++) {
            int n = wc * 128 + ni * 16 + lr;
            bw[ni] = *(const short8*)&sB[buf][n * 32 + ((lg ^ ((n >> 1) & 3)) << 3)];
        }
#pragma unroll
        for (int mi = 0; mi < 4; mi++)
#pragma unroll
            for (int ni = 0; ni < 8; ni++)
                acc[mi][ni] = __builtin_amdgcn_mfma_f32_16x16x32_bf16(
                    av[mi], bw[ni], acc[mi][ni], 0, 0, 0);
    };

    STAGE(0, 0);
    __syncthreads();
    int cur = 0;
    for (int kt = 32; kt < K; kt += 32) {
        STAGE(cur ^ 1, kt);     // next tile's loads fly during this compute
        COMPUTE(cur);
        __syncthreads();        // single barrier per iter (drains vm+lgkm)
        cur ^= 1;
    }
    COMPUTE(cur);

    // epilogue: v = C + bias + res; LN over the 512-wide row
    float gv[8], bev[8], bb[8];
#pragma unroll
    for (int ni = 0; ni < 8; ni++) {
        int col = wc * 128 + ni * 16 + lr;
        gv[ni] = g[col]; bev[ni] = be[col]; bb[ni] = bias[col];
    }
#pragma unroll
    for (int mi = 0; mi < 4; mi++)
#pragma unroll
        for (int jj = 0; jj < 4; jj++) {
            long row = tM + wr * 64 + mi * 16 + lg * 4 + jj;
#pragma unroll
            for (int ni = 0; ni < 8; ni++) {
                int col = wc * 128 + ni * 16 + lr;
                acc[mi][ni][jj] += bb[ni] + res[row * 512 + col];
            }
        }
    float s2[4][4], ss2[4][4];
#pragma unroll
    for (int mi = 0; mi < 4; mi++)
#pragma unroll
        for (int jj = 0; jj < 4; jj++) {
            float s = 0.f, ss = 0.f;
#pragma unroll
            for (int ni = 0; ni < 8; ni++) {
                float v = acc[mi][ni][jj];
                s += v; ss += v * v;
            }
#pragma unroll
            for (int off = 1; off < 16; off <<= 1) {
                s  += __shfl_xor(s, off);
                ss += __shfl_xor(ss, off);
            }
            s2[mi][jj] = s; ss2[mi][jj] = ss;
        }
    __syncthreads();   // all waves past final COMPUTE before aliasing sA[0]
    if (lr == 0) {
#pragma unroll
        for (int mi = 0; mi < 4; mi++)
#pragma unroll
            for (int jj = 0; jj < 4; jj++) {
                int rb = wr * 64 + mi * 16 + lg * 4 + jj;
                redb[0 * 512 + wc * 128 + rb] = s2[mi][jj];
                redb[1 * 512 + wc * 128 + rb] = ss2[mi][jj];
            }
    }
    __syncthreads();
    if (t < 128) {
        float S  = redb[t] + redb[128 + t] + redb[256 + t] + redb[384 + t];
        float SS = redb[512 + t] + redb[640 + t] + redb[768 + t] + redb[896 + t];
        float mean = S * (1.0f / 512.0f);
        float var  = SS * (1.0f / 512.0f) - mean * mean;
        statb[t] = mean;
        statb[128 + t] = rsqrtf(fmaxf(var, 0.f) + 1e-5f);
    }
    __syncthreads();
#pragma unroll
    for (int mi = 0; mi < 4; mi++)
#pragma unroll
        for (int jj = 0; jj < 4; jj++) {
            int rb = wr * 64 + mi * 16 + lg * 4 + jj;
            long row = tM + rb;
            float mean = statb[rb], rstd = statb[128 + rb];
#pragma unroll
            for (int ni = 0; ni < 8; ni++) {
                int col = wc * 128 + ni * 16 + lr;
                float y = (acc[mi][ni][jj] - mean) * rstd * gv[ni] + bev[ni];
                of[row * 512 + col] = y;
                ob[row * 512 + col] = f2bf(y);
            }
        }
}

// ---------------------------------------------------------------------------
// Attention glue. KVbuf[(s*8+b)][1024]: cols 0..511 = phiK (later ATTN),
// cols 512..1023 = V (later phiQ).
// ctx_partial also accumulates ksum_d = sum_s phiK[s][d] (part2).
// ---------------------------------------------------------------------------
__global__ __launch_bounds__(256) void ctx_partial_kernel(
    const unsigned short* __restrict__ kv, float* __restrict__ part,
    float* __restrict__ part2)
{
    const int p = blockIdx.x, ch = blockIdx.y;
    const int b = p >> 3, h = p & 7;
    __shared__ float kb[64 * 68];
    __shared__ float vbuf[64 * 68];
    const int t = threadIdx.x;
    const int dq = t >> 4, eq = t & 15;
    f32x4 acc[4];
    f32x4 ks = {0.f, 0.f, 0.f, 0.f};
#pragma unroll
    for (int i = 0; i < 4; i++) acc[i] = f32x4{0.f, 0.f, 0.f, 0.f};

    for (int sub = 0; sub < 8; sub++) {
        int sbase = ch * 512 + sub * 64;
#pragma unroll
        for (int i = 0; i < 2; i++) {
            int idx = i * 256 + t;
            int row = idx >> 3, c8 = idx & 7;
            long ga = ((long)(sbase + row) * 8 + b) * 1024 + h * 64 + c8 * 8;
            short8 kvv = *(const short8*)&kv[ga];
            short8 vv  = *(const short8*)&kv[ga + 512];
#pragma unroll
            for (int j = 0; j < 8; j++) {
                kb[row * 68 + c8 * 8 + j]   = bf2f((unsigned short)kvv[j]);
                vbuf[row * 68 + c8 * 8 + j] = bf2f((unsigned short)vv[j]);
            }
        }
        __syncthreads();
        for (int s = 0; s < 64; s++) {
            f32x4 k4 = *(const f32x4*)&kb[s * 68 + dq * 4];
            f32x4 v4 = *(const f32x4*)&vbuf[s * 68 + eq * 4];
#pragma unroll
            for (int i = 0; i < 4; i++) acc[i] += k4[i] * v4;
            ks += k4;
        }
        __syncthreads();
    }
    float* o = part + (long)(p * 8 + ch) * 4096;
#pragma unroll
    for (int i = 0; i < 4; i++)
        *(f32x4*)&o[(dq * 4 + i) * 64 + eq * 4] = acc[i];
    if (eq == 0)
        *(f32x4*)&part2[(p * 8 + ch) * 64 + dq * 4] = ks;
}

// reduce ctx partials -> ctxA[p][n=e][k=d] (bf16, transposed); finalize ksum
// into row n=64, zero rows 65..79
__global__ __launch_bounds__(256) void ctx_reduce_kernel(
    const float* __restrict__ part, const float* __restrict__ part2,
    unsigned short* __restrict__ ctxA)
{
    int o = (blockIdx.x * 256 + threadIdx.x) * 4;
    int p = o >> 12, d = (o >> 6) & 63, e0 = o & 63;
    f32x4 s = {0.f, 0.f, 0.f, 0.f};
    for (int ch = 0; ch < 8; ch++)
        s += *(const f32x4*)&part[(long)(p * 8 + ch) * 4096 + d * 64 + e0];
#pragma unroll
    for (int j = 0; j < 4; j++) ctxA[p * 5120 + (e0 + j) * 64 + d] = f2bf(s[j]);
    if (e0 == 0) {
        float ksv = 0.f;
#pragma unroll
        for (int ch = 0; ch < 8; ch++) ksv += part2[(p * 8 + ch) * 64 + d];
        ctxA[p * 5120 + 4096 + d] = f2bf(ksv);
#pragma unroll
        for (int j = 1; j < 16; j++) ctxA[p * 5120 + 4096 + j * 64 + d] = 0;
    }
}

// out = phiQ @ [ctx | ksum]; ni=4 accumulates denominator; normalize -> bf16
__global__ __launch_bounds__(256) void attn_out_kernel(
    unsigned short* __restrict__ kv,
    const unsigned short* __restrict__ ctxA)
{
    const int p = blockIdx.x;
    const int b = p >> 3, h = p & 7;
    const int t = threadIdx.x, w = t >> 6, l = t & 63, lr = l & 15, lg = l >> 4;
    const int s0 = blockIdx.y * 256 + w * 64;
    f32x4 acc[4][5];
#pragma unroll
    for (int i = 0; i < 4; i++)
#pragma unroll
        for (int j = 0; j < 5; j++) acc[i][j] = f32x4{0.f, 0.f, 0.f, 0.f};
    const unsigned short* cb = ctxA + p * 5120;
#pragma unroll
    for (int kk = 0; kk < 2; kk++) {
        short8 af[4], bfv[5];
#pragma unroll
        for (int mi = 0; mi < 4; mi++) {
            int s = s0 + mi * 16 + lr;
            af[mi] = *(const short8*)&kv[((long)s * 8 + b) * 1024 + 512 + h * 64 + kk * 32 + lg * 8];
        }
#pragma unroll
        for (int ni = 0; ni < 5; ni++)
            bfv[ni] = *(const short8*)&cb[(ni * 16 + lr) * 64 + kk * 32 + lg * 8];
#pragma unroll
        for (int mi = 0; mi < 4; mi++)
#pragma unroll
            for (int ni = 0; ni < 5; ni++)
                acc[mi][ni] = __builtin_amdgcn_mfma_f32_16x16x32_bf16(
                    af[mi], bfv[ni], acc[mi][ni], 0, 0, 0);
    }
#pragma unroll
    for (int mi = 0; mi < 4; mi++) {
#pragma unroll
        for (int j = 0; j < 4; j++) {
            float den = __shfl(acc[mi][4][j], (l & 48));
            float rc  = 1.0f / (den + 1e-6f);
            int s = s0 + mi * 16 + lg * 4 + j;
            long base = ((long)s * 8 + b) * 1024 + h * 64;
#pragma unroll
            for (int ni = 0; ni < 4; ni++)
                kv[base + ni * 16 + lr] = f2bf(acc[mi][ni][j] * rc);
        }
    }
}

// ---------------------------------------------------------------------------
// small helpers
// ---------------------------------------------------------------------------
__global__ __launch_bounds__(256) void cvtbf_kernel(
    const float* __restrict__ x, unsigned short* __restrict__ y)
{
    long i = ((long)blockIdx.x * 256 + threadIdx.x) * 8;
    f32x4 a = *(const f32x4*)&x[i];
    f32x4 c = *(const f32x4*)&x[i + 4];
    short8 pk;
#pragma unroll
    for (int j = 0; j < 4; j++) { pk[j] = (short)f2bf(a[j]); pk[4 + j] = (short)f2bf(c[j]); }
    *(short8*)&y[i] = pk;
}

__global__ __launch_bounds__(256) void bcat_kernel(
    const float* __restrict__ bk, const float* __restrict__ bv, float* __restrict__ dst)
{
    int lyr = blockIdx.x;
    int j = blockIdx.y * 256 + threadIdx.x;
    dst[lyr * 1024 + j] = (j < 512) ? bk[lyr * 512 + j] : bv[lyr * 512 + j - 512];
}

// weight transpose + convert: Wt[n][k] = (bf16) W[k][n], per-layer strides
__global__ __launch_bounds__(256) void wconv_kernel(
    const float* __restrict__ W, unsigned short* __restrict__ Wt, int K, int N,
    long lstrW, long lstrT)
{
    __shared__ float tile[64 * 65];
    const long lz = blockIdx.z;
    const float* Wl = W + lz * lstrW;
    unsigned short* Wtl = Wt + lz * lstrT;
    const int k0 = blockIdx.x * 64, n0 = blockIdx.y * 64;
    const int t = threadIdx.x;
#pragma unroll
    for (int i = 0; i < 4; i++) {
        int q = i * 256 + t;
        int r = q >> 4, c4 = q & 15;
        f32x4 v = *(const f32x4*)&Wl[(long)(k0 + r) * N + n0 + c4 * 4];
#pragma unroll
        for (int j = 0; j < 4; j++) tile[r * 65 + c4 * 4 + j] = v[j];
    }
    __syncthreads();
#pragma unroll
    for (int i = 0; i < 4; i++) {
        int q = i * 256 + t;
        int nr = q >> 4, kc = q & 15;
        ushort4v pk;
#pragma unroll
        for (int j = 0; j < 4; j++) pk[j] = f2bf(tile[(kc * 4 + j) * 65 + nr]);
        *(ushort4v*)&Wtl[(long)(n0 + nr) * K + k0 + kc * 4] = pk;
    }
}

// ---------------------------------------------------------------------------
// Host orchestration.  ws ~121 MiB:
//  [WKV 4M][WQ 2M][WO 2M][W1 4M][W2 4M][BKV 16K][R1 32M][KV 64M][KSP][CTP 8M][CTA]
// f32 residual stream F1 = d_out (in-place RMW in gemm_ln; final LN2 leaves
// the answer there). R1 = bf16 stream copy (GEMM inputs).
// KV: {K|V} -> {ATTN|phiQ} -> HBF(64M).
// ---------------------------------------------------------------------------
extern "C" void kernel_launch(void* const* d_in, const int* in_sizes, int n_in,
                              void* d_out, int out_size, void* d_ws, size_t ws_size,
                              hipStream_t stream)
{
    const float* src  = (const float*)d_in[0];
    const float* Wq   = (const float*)d_in[1];
    const float* bq   = (const float*)d_in[2];
    const float* Wk   = (const float*)d_in[3];
    const float* bk   = (const float*)d_in[4];
    const float* Wv   = (const float*)d_in[5];
    const float* bv   = (const float*)d_in[6];
    const float* Wo   = (const float*)d_in[7];
    const float* bo   = (const float*)d_in[8];
    const float* l1g  = (const float*)d_in[9];
    const float* l1b  = (const float*)d_in[10];
    const float* W1   = (const float*)d_in[11];
    const float* b1   = (const float*)d_in[12];
    const float* W2   = (const float*)d_in[13];
    const float* b2   = (const float*)d_in[14];
    const float* l2g  = (const float*)d_in[15];
    const float* l2b  = (const float*)d_in[16];

    char* ws = (char*)d_ws;
    constexpr size_t SZ_WKV = (size_t)4 * 1024 * 512 * 2;
    constexpr size_t SZ_WQ  = (size_t)4 * 512 * 512 * 2;
    constexpr size_t SZ_WO  = SZ_WQ;
    constexpr size_t SZ_W1  = (size_t)4 * 512 * 1024 * 2;
    constexpr size_t SZ_W2  = SZ_W1;
    constexpr size_t SZ_BKV = (size_t)4 * 1024 * 4;
    constexpr size_t SZ_R1  = (size_t)32768 * 512 * 2;
    constexpr size_t SZ_KV  = (size_t)32768 * 1024 * 2;
    constexpr size_t OFF_WKV = 0;
    constexpr size_t OFF_WQ  = OFF_WKV + SZ_WKV;
    constexpr size_t OFF_WO  = OFF_WQ + SZ_WQ;
    constexpr size_t OFF_W1  = OFF_WO + SZ_WO;
    constexpr size_t OFF_W2  = OFF_W1 + SZ_W1;
    constexpr size_t OFF_BKV = OFF_W2 + SZ_W2;
    constexpr size_t OFF_R1  = OFF_BKV + SZ_BKV;
    constexpr size_t OFF_KV  = OFF_R1 + SZ_R1;
    constexpr size_t OFF_KSP = OFF_KV + SZ_KV;
    constexpr size_t OFF_CTP = OFF_KSP + (size_t)16 * 4096 * 4;
    constexpr size_t OFF_CTA = OFF_CTP + (size_t)64 * 8 * 4096 * 4;

    unsigned short* WKVT = (unsigned short*)(ws + OFF_WKV);
    unsigned short* WQT  = (unsigned short*)(ws + OFF_WQ);
    unsigned short* WOT  = (unsigned short*)(ws + OFF_WO);
    unsigned short* W1T  = (unsigned short*)(ws + OFF_W1);
    unsigned short* W2T  = (unsigned short*)(ws + OFF_W2);
    float*          BKV  = (float*)(ws + OFF_BKV);
    unsigned short* R1   = (unsigned short*)(ws + OFF_R1);
    unsigned short* KV   = (unsigned short*)(ws + OFF_KV);
    float*          KSP  = (float*)(ws + OFF_KSP);
    float*          CTP  = (float*)(ws + OFF_CTP);
    unsigned short* CTA  = (unsigned short*)(ws + OFF_CTA);
    float*          F1   = (float*)d_out;    // f32 residual stream

    dim3 blk(256);
    wconv_kernel<<<dim3(8, 8, 4),  blk, 0, stream>>>(Wk, WKVT,            512, 512, 512*512, 1024*512);
    wconv_kernel<<<dim3(8, 8, 4),  blk, 0, stream>>>(Wv, WKVT + 512*512,  512, 512, 512*512, 1024*512);
    wconv_kernel<<<dim3(8, 8, 4),  blk, 0, stream>>>(Wq, WQT,             512, 512, 512*512, 512*512);
    wconv_kernel<<<dim3(8, 8, 4),  blk, 0, stream>>>(Wo, WOT,             512, 512, 512*512, 512*512);
    wconv_kernel<<<dim3(8, 16, 4), blk, 0, stream>>>(W1, W1T,             512, 1024, 512*1024, 512*1024);
    wconv_kernel<<<dim3(16, 8, 4), blk, 0, stream>>>(W2, W2T,             1024, 512, 1024*512, 1024*512);
    bcat_kernel<<<dim3(4, 4), blk, 0, stream>>>(bk, bv, BKV);
    cvtbf_kernel<<<8192, blk, 0, stream>>>(src, R1);

    for (int lyr = 0; lyr < 4; lyr++) {
        const unsigned short* wkvt = WKVT + (size_t)lyr * 1024 * 512;
        const unsigned short* wqt  = WQT  + (size_t)lyr * 512 * 512;
        const unsigned short* wot  = WOT  + (size_t)lyr * 512 * 512;
        const unsigned short* w1t  = W1T  + (size_t)lyr * 512 * 1024;
        const unsigned short* w2t  = W2T  + (size_t)lyr * 1024 * 512;

        // K|V fused GEMM (elu on cols<512), N=1024 -> nshift=3, grid 2048
        gemm_kernel<0><<<2048, blk, 0, stream>>>(R1, 512, wkvt, BKV + lyr * 1024, KV, 1024, 3, 512);

        // ctx + ksum in one pass over KV
        ctx_partial_kernel<<<dim3(64, 8), blk, 0, stream>>>(KV, CTP, KSP);
        ctx_reduce_kernel<<<256, blk, 0, stream>>>(CTP, KSP, CTA);

        // phiQ into V slot (dead), N=512 -> nshift=2, grid 1024
        gemm_kernel<0><<<1024, blk, 0, stream>>>(R1, 512, wqt, bq + lyr * 512, KV + 512, 1024, 2, 512);
        attn_out_kernel<<<dim3(64, 16), blk, 0, stream>>>(KV, CTA);

        // Wo + residual + LN1 -> F1(f32) in-place, bf16 to R1
        const float* resp = (lyr == 0) ? src : F1;
        gemm_ln_kernel<<<256, dim3(512), 0, stream>>>(KV, 1024, wot, bo + lyr * 512, resp,
                                                      l1g + lyr * 512, l1b + lyr * 512,
                                                      F1, R1, 512);
        // FFN up + relu -> HBF (KV region, dead), N=1024 -> nshift=3
        gemm_kernel<2><<<2048, blk, 0, stream>>>(R1, 512, w1t, b1 + lyr * 1024, KV, 1024, 3, 512);
        // FFN down + residual + LN2 -> F1 in-place, bf16 to R1 (next input)
        gemm_ln_kernel<<<256, dim3(512), 0, stream>>>(KV, 1024, w2t, b2 + lyr * 512, F1,
                                                      l2g + lyr * 512, l2b + lyr * 512,
                                                      F1, R1, 1024);
    }
}

// Round 11
// 1298.957 us; speedup vs baseline: 2.4391x; 1.0115x over previous
//
#include <hip/hip_runtime.h>
#include <hip/hip_bf16.h>
#include <cstdint>

typedef __attribute__((ext_vector_type(8))) short short8;
typedef __attribute__((ext_vector_type(4))) float f32x4;
typedef __attribute__((ext_vector_type(4))) unsigned short ushort4v;

#define DEV static __device__ __forceinline__

DEV float bf2f(unsigned short u) {
    union { unsigned int i; float f; } v; v.i = ((unsigned int)u) << 16; return v.f;
}
DEV unsigned short f2bf(float f) {
    union { float f; unsigned int i; } v; v.f = f;
    unsigned int x = v.i;
    unsigned int r = x + 0x7fffu + ((x >> 16) & 1u);
    return (unsigned short)(r >> 16);
}

// ---------------------------------------------------------------------------
// GEMM: C[M,N] = A[M,K](bf16, row-stride lda) @ Wt[N,K]^T + bias -> bf16 (ldc)
// 128x128 tile, 4 waves, 16x16x32 MFMA. 2-PHASE DOUBLE-BUFFERED, BK=32:
// dbuf LDS = 2x(A 8K + B 8K) = 32KB fits INSIDE the 34.8KB epilogue array ->
// 4 blocks/CU preserved (r3's dbuf failed because BK=64 dbuf doubled LDS).
// Swizzle (c&3)^((row>>1)&3) for 64B rows: HW-verified 0 conflicts (r10).
// XCD-aware 1D-grid swizzle (r7). EPI 0: elu+1 iff col<512 | EPI 2: relu
// ---------------------------------------------------------------------------
template<int EPI>
__global__ __launch_bounds__(256) void gemm_kernel(
    const unsigned short* __restrict__ A, int lda,
    const unsigned short* __restrict__ Bt,
    const float* __restrict__ bias,
    unsigned short* __restrict__ outp, int ldc,
    int nshift, int K)
{
    __shared__ unsigned short lds[128 * 136];  // 34.8KB; K-loop uses [0,16384)
    const int t  = threadIdx.x;
    const int w  = t >> 6, l = t & 63;
    const int wr = w >> 1, wc = w & 1;
    const int lr = l & 15, lg = l >> 4;
    const int bid = blockIdx.x;
    const int j8  = bid & 7, s = bid >> 3;
    const int bx  = j8 * 32 + (s >> nshift);
    const int by  = s & ((1 << nshift) - 1);
    const long tM = (long)bx * 128;
    const long tN = (long)by * 128;

    f32x4 acc[4][4];
#pragma unroll
    for (int i = 0; i < 4; i++)
#pragma unroll
        for (int j = 0; j < 4; j++) acc[i][j] = f32x4{0.f, 0.f, 0.f, 0.f};

    const unsigned short* Ab = A  + tM * lda;
    const unsigned short* Bb = Bt + tN * K;

    auto STAGE = [&](int buf, int kt) {
        const int base = buf * 8192;
#pragma unroll
        for (int j = 0; j < 2; j++) {   // A: 128 rows x 4 chunks = 512 chunks
            int c = j * 256 + w * 64 + l;
            int row = c >> 2, sc = (c & 3) ^ ((row >> 1) & 3);
            __builtin_amdgcn_global_load_lds(
                (const __attribute__((address_space(1))) void*)(Ab + (long)row * lda + kt + sc * 8),
                (__attribute__((address_space(3))) void*)(lds + base + (j * 256 + w * 64) * 8),
                16, 0, 0);
        }
#pragma unroll
        for (int j = 0; j < 2; j++) {   // B: 128 rows x 4 chunks
            int c = j * 256 + w * 64 + l;
            int row = c >> 2, sc = (c & 3) ^ ((row >> 1) & 3);
            __builtin_amdgcn_global_load_lds(
                (const __attribute__((address_space(1))) void*)(Bb + (long)row * K + kt + sc * 8),
                (__attribute__((address_space(3))) void*)(lds + base + 4096 + (j * 256 + w * 64) * 8),
                16, 0, 0);
        }
    };

    auto COMPUTE = [&](int buf) {
        const int base = buf * 8192;
        short8 af[4], bfv[4];
#pragma unroll
        for (int mi = 0; mi < 4; mi++) {
            int r = wr * 64 + mi * 16 + lr;
            af[mi] = *(const short8*)&lds[base + r * 32 + ((lg ^ ((r >> 1) & 3)) << 3)];
        }
#pragma unroll
        for (int ni = 0; ni < 4; ni++) {
            int n = wc * 64 + ni * 16 + lr;
            bfv[ni] = *(const short8*)&lds[base + 4096 + n * 32 + ((lg ^ ((n >> 1) & 3)) << 3)];
        }
#pragma unroll
        for (int mi = 0; mi < 4; mi++)
#pragma unroll
            for (int ni = 0; ni < 4; ni++)
                acc[mi][ni] = __builtin_amdgcn_mfma_f32_16x16x32_bf16(
                    af[mi], bfv[ni], acc[mi][ni], 0, 0, 0);
    };

    STAGE(0, 0);
    __syncthreads();
    int cur = 0;
    for (int kt = 32; kt < K; kt += 32) {
        STAGE(cur ^ 1, kt);     // next tile's loads fly during this compute
        COMPUTE(cur);
        __syncthreads();
        cur ^= 1;
    }
    COMPUTE(cur);
    __syncthreads();            // all waves done with LDS before epilogue reuse

    float bv[4];
#pragma unroll
    for (int ni = 0; ni < 4; ni++) bv[ni] = bias[tN + wc * 64 + ni * 16 + lr];
    const bool doElu = (EPI == 0) && (tN < 512);

#pragma unroll
    for (int mi = 0; mi < 4; mi++)
#pragma unroll
        for (int ni = 0; ni < 4; ni++)
#pragma unroll
            for (int j = 0; j < 4; j++) {
                float v = acc[mi][ni][j] + bv[ni];
                if (EPI == 0) { if (doElu) v = (v > 0.f) ? (v + 1.f) : expf(v); }
                if (EPI == 2) v = fmaxf(v, 0.f);
                int r = wr * 64 + mi * 16 + lg * 4 + j;
                int c = wc * 64 + ni * 16 + lr;
                lds[r * 136 + c] = f2bf(v);
            }
    __syncthreads();
#pragma unroll
    for (int i = 0; i < 8; i++) {
        int q = i * 256 + t;
        int r = q >> 4, cc = q & 15;
        short8 v8 = *(const short8*)&lds[r * 136 + cc * 8];
        *(short8*)&outp[(tM + r) * ldc + tN + cc * 8] = v8;
    }
}

// ---------------------------------------------------------------------------
// Fused GEMM + bias + residual + LayerNorm, 2-phase dbuf BK=32 (r10-proven).
// BM=128, 512 thr / 8 waves. LDS 80KiB (red/stats aliased into sA[0]).
// RESBF: residual read as bf16 (x1 intra-layer) vs f32 (cross-layer stream).
// WRITEOF: write f32 stream copy (LN2 yes; LN1 no -- its f32 copy was only
// consumed as LN2's residual, now served by the bf16 copy).
// NO min-wave bound (r8: forced cap -> accumulator spill).
// ---------------------------------------------------------------------------
template<int RESBF, int WRITEOF>
__global__ __launch_bounds__(512) void gemm_ln_kernel(
    const unsigned short* __restrict__ A, int lda,
    const unsigned short* __restrict__ Bt,   // [512][K]
    const float* __restrict__ bias,          // [512]
    const void* __restrict__ resp,           // [M][512] f32 or bf16 (RESBF)
    const float* __restrict__ g,
    const float* __restrict__ be,
    float* __restrict__ of,                  // [M][512] f32 (if WRITEOF)
    unsigned short* __restrict__ ob,         // [M][512] bf16
    int K)
{
    __shared__ unsigned short sA[2][128 * 32];   // 2 x 8 KiB
    __shared__ unsigned short sB[2][512 * 32];   // 2 x 32 KiB
    float* redb  = (float*)&sA[0][0];            // epilogue alias: 4 KiB
    float* statb = redb + 1024;                  // 1 KiB
    const int t = threadIdx.x, w = t >> 6, l = t & 63, lr = l & 15, lg = l >> 4;
    const int wr = w >> 2, wc = w & 3;
    const long tM = (long)blockIdx.x * 128;

    f32x4 acc[4][8];
#pragma unroll
    for (int i = 0; i < 4; i++)
#pragma unroll
        for (int j = 0; j < 8; j++) acc[i][j] = f32x4{0.f, 0.f, 0.f, 0.f};

    const unsigned short* Ab = A + tM * lda;

    auto STAGE = [&](int buf, int kt) {
        {   // A: 128 rows x 4 chunks = 512 chunks, 1/thread
            int c = t, row = c >> 2, sc = (c & 3) ^ ((row >> 1) & 3);
            __builtin_amdgcn_global_load_lds(
                (const __attribute__((address_space(1))) void*)(Ab + (long)row * lda + kt + sc * 8),
                (__attribute__((address_space(3))) void*)(&sA[buf][(w * 64) * 8]),
                16, 0, 0);
        }
#pragma unroll
        for (int j = 0; j < 4; j++) {  // B: 512 rows x 4 chunks = 2048 chunks
            int c = j * 512 + t, row = c >> 2, sc = (c & 3) ^ ((row >> 1) & 3);
            __builtin_amdgcn_global_load_lds(
                (const __attribute__((address_space(1))) void*)(Bt + (long)row * K + kt + sc * 8),
                (__attribute__((address_space(3))) void*)(&sB[buf][(j * 512 + w * 64) * 8]),
                16, 0, 0);
        }
    };

    auto COMPUTE = [&](int buf) {
        short8 av[4], bw[8];
#pragma unroll
        for (int mi = 0; mi < 4; mi++) {
            int r = wr * 64 + mi * 16 + lr;
            av[mi] = *(const short8*)&sA[buf][r * 32 + ((lg ^ ((r >> 1) & 3)) << 3)];
        }
#pragma unroll
        for (int ni = 0; ni < 8; ni++) {
            int n = wc * 128 + ni * 16 + lr;
            bw[ni] = *(const short8*)&sB[buf][n * 32 + ((lg ^ ((n >> 1) & 3)) << 3)];
        }
#pragma unroll
        for (int mi = 0; mi < 4; mi++)
#pragma unroll
            for (int ni = 0; ni < 8; ni++)
                acc[mi][ni] = __builtin_amdgcn_mfma_f32_16x16x32_bf16(
                    av[mi], bw[ni], acc[mi][ni], 0, 0, 0);
    };

    STAGE(0, 0);
    __syncthreads();
    int cur = 0;
    for (int kt = 32; kt < K; kt += 32) {
        STAGE(cur ^ 1, kt);
        COMPUTE(cur);
        __syncthreads();
        cur ^= 1;
    }
    COMPUTE(cur);

    // epilogue: v = C + bias + res; LN over the 512-wide row
    const float* resf = (const float*)resp;
    const unsigned short* resb = (const unsigned short*)resp;
    float gv[8], bev[8], bb[8];
#pragma unroll
    for (int ni = 0; ni < 8; ni++) {
        int col = wc * 128 + ni * 16 + lr;
        gv[ni] = g[col]; bev[ni] = be[col]; bb[ni] = bias[col];
    }
#pragma unroll
    for (int mi = 0; mi < 4; mi++)
#pragma unroll
        for (int jj = 0; jj < 4; jj++) {
            long row = tM + wr * 64 + mi * 16 + lg * 4 + jj;
#pragma unroll
            for (int ni = 0; ni < 8; ni++) {
                int col = wc * 128 + ni * 16 + lr;
                float rv = RESBF ? bf2f(resb[row * 512 + col]) : resf[row * 512 + col];
                acc[mi][ni][jj] += bb[ni] + rv;
            }
        }
    float s2[4][4], ss2[4][4];
#pragma unroll
    for (int mi = 0; mi < 4; mi++)
#pragma unroll
        for (int jj = 0; jj < 4; jj++) {
            float s = 0.f, ss = 0.f;
#pragma unroll
            for (int ni = 0; ni < 8; ni++) {
                float v = acc[mi][ni][jj];
                s += v; ss += v * v;
            }
#pragma unroll
            for (int off = 1; off < 16; off <<= 1) {
                s  += __shfl_xor(s, off);
                ss += __shfl_xor(ss, off);
            }
            s2[mi][jj] = s; ss2[mi][jj] = ss;
        }
    __syncthreads();   // all waves past final COMPUTE before aliasing sA[0]
    if (lr == 0) {
#pragma unroll
        for (int mi = 0; mi < 4; mi++)
#pragma unroll
            for (int jj = 0; jj < 4; jj++) {
                int rb = wr * 64 + mi * 16 + lg * 4 + jj;
                redb[0 * 512 + wc * 128 + rb] = s2[mi][jj];
                redb[1 * 512 + wc * 128 + rb] = ss2[mi][jj];
            }
    }
    __syncthreads();
    if (t < 128) {
        float S  = redb[t] + redb[128 + t] + redb[256 + t] + redb[384 + t];
        float SS = redb[512 + t] + redb[640 + t] + redb[768 + t] + redb[896 + t];
        float mean = S * (1.0f / 512.0f);
        float var  = SS * (1.0f / 512.0f) - mean * mean;
        statb[t] = mean;
        statb[128 + t] = rsqrtf(fmaxf(var, 0.f) + 1e-5f);
    }
    __syncthreads();
#pragma unroll
    for (int mi = 0; mi < 4; mi++)
#pragma unroll
        for (int jj = 0; jj < 4; jj++) {
            int rb = wr * 64 + mi * 16 + lg * 4 + jj;
            long row = tM + rb;
            float mean = statb[rb], rstd = statb[128 + rb];
#pragma unroll
            for (int ni = 0; ni < 8; ni++) {
                int col = wc * 128 + ni * 16 + lr;
                float y = (acc[mi][ni][jj] - mean) * rstd * gv[ni] + bev[ni];
                if (WRITEOF) of[row * 512 + col] = y;
                ob[row * 512 + col] = f2bf(y);
            }
        }
}

// ---------------------------------------------------------------------------
// Attention glue. KVbuf[(s*8+b)][1024]: cols 0..511 = phiK (later ATTN),
// cols 512..1023 = V (later phiQ).
// ctx_partial also accumulates ksum_d = sum_s phiK[s][d] (part2).
// ---------------------------------------------------------------------------
__global__ __launch_bounds__(256) void ctx_partial_kernel(
    const unsigned short* __restrict__ kv, float* __restrict__ part,
    float* __restrict__ part2)
{
    const int p = blockIdx.x, ch = blockIdx.y;
    const int b = p >> 3, h = p & 7;
    __shared__ float kb[64 * 68];
    __shared__ float vbuf[64 * 68];
    const int t = threadIdx.x;
    const int dq = t >> 4, eq = t & 15;
    f32x4 acc[4];
    f32x4 ks = {0.f, 0.f, 0.f, 0.f};
#pragma unroll
    for (int i = 0; i < 4; i++) acc[i] = f32x4{0.f, 0.f, 0.f, 0.f};

    for (int sub = 0; sub < 8; sub++) {
        int sbase = ch * 512 + sub * 64;
#pragma unroll
        for (int i = 0; i < 2; i++) {
            int idx = i * 256 + t;
            int row = idx >> 3, c8 = idx & 7;
            long ga = ((long)(sbase + row) * 8 + b) * 1024 + h * 64 + c8 * 8;
            short8 kvv = *(const short8*)&kv[ga];
            short8 vv  = *(const short8*)&kv[ga + 512];
#pragma unroll
            for (int j = 0; j < 8; j++) {
                kb[row * 68 + c8 * 8 + j]   = bf2f((unsigned short)kvv[j]);
                vbuf[row * 68 + c8 * 8 + j] = bf2f((unsigned short)vv[j]);
            }
        }
        __syncthreads();
        for (int s = 0; s < 64; s++) {
            f32x4 k4 = *(const f32x4*)&kb[s * 68 + dq * 4];
            f32x4 v4 = *(const f32x4*)&vbuf[s * 68 + eq * 4];
#pragma unroll
            for (int i = 0; i < 4; i++) acc[i] += k4[i] * v4;
            ks += k4;
        }
        __syncthreads();
    }
    float* o = part + (long)(p * 8 + ch) * 4096;
#pragma unroll
    for (int i = 0; i < 4; i++)
        *(f32x4*)&o[(dq * 4 + i) * 64 + eq * 4] = acc[i];
    if (eq == 0)
        *(f32x4*)&part2[(p * 8 + ch) * 64 + dq * 4] = ks;
}

// reduce ctx partials -> ctxA[p][n=e][k=d] (bf16, transposed); finalize ksum
// into row n=64, zero rows 65..79
__global__ __launch_bounds__(256) void ctx_reduce_kernel(
    const float* __restrict__ part, const float* __restrict__ part2,
    unsigned short* __restrict__ ctxA)
{
    int o = (blockIdx.x * 256 + threadIdx.x) * 4;
    int p = o >> 12, d = (o >> 6) & 63, e0 = o & 63;
    f32x4 s = {0.f, 0.f, 0.f, 0.f};
    for (int ch = 0; ch < 8; ch++)
        s += *(const f32x4*)&part[(long)(p * 8 + ch) * 4096 + d * 64 + e0];
#pragma unroll
    for (int j = 0; j < 4; j++) ctxA[p * 5120 + (e0 + j) * 64 + d] = f2bf(s[j]);
    if (e0 == 0) {
        float ksv = 0.f;
#pragma unroll
        for (int ch = 0; ch < 8; ch++) ksv += part2[(p * 8 + ch) * 64 + d];
        ctxA[p * 5120 + 4096 + d] = f2bf(ksv);
#pragma unroll
        for (int j = 1; j < 16; j++) ctxA[p * 5120 + 4096 + j * 64 + d] = 0;
    }
}

// out = phiQ @ [ctx | ksum]; ni=4 accumulates denominator; normalize -> bf16
__global__ __launch_bounds__(256) void attn_out_kernel(
    unsigned short* __restrict__ kv,
    const unsigned short* __restrict__ ctxA)
{
    const int p = blockIdx.x;
    const int b = p >> 3, h = p & 7;
    const int t = threadIdx.x, w = t >> 6, l = t & 63, lr = l & 15, lg = l >> 4;
    const int s0 = blockIdx.y * 256 + w * 64;
    f32x4 acc[4][5];
#pragma unroll
    for (int i = 0; i < 4; i++)
#pragma unroll
        for (int j = 0; j < 5; j++) acc[i][j] = f32x4{0.f, 0.f, 0.f, 0.f};
    const unsigned short* cb = ctxA + p * 5120;
#pragma unroll
    for (int kk = 0; kk < 2; kk++) {
        short8 af[4], bfv[5];
#pragma unroll
        for (int mi = 0; mi < 4; mi++) {
            int s = s0 + mi * 16 + lr;
            af[mi] = *(const short8*)&kv[((long)s * 8 + b) * 1024 + 512 + h * 64 + kk * 32 + lg * 8];
        }
#pragma unroll
        for (int ni = 0; ni < 5; ni++)
            bfv[ni] = *(const short8*)&cb[(ni * 16 + lr) * 64 + kk * 32 + lg * 8];
#pragma unroll
        for (int mi = 0; mi < 4; mi++)
#pragma unroll
            for (int ni = 0; ni < 5; ni++)
                acc[mi][ni] = __builtin_amdgcn_mfma_f32_16x16x32_bf16(
                    af[mi], bfv[ni], acc[mi][ni], 0, 0, 0);
    }
#pragma unroll
    for (int mi = 0; mi < 4; mi++) {
#pragma unroll
        for (int j = 0; j < 4; j++) {
            float den = __shfl(acc[mi][4][j], (l & 48));
            float rc  = 1.0f / (den + 1e-6f);
            int s = s0 + mi * 16 + lg * 4 + j;
            long base = ((long)s * 8 + b) * 1024 + h * 64;
#pragma unroll
            for (int ni = 0; ni < 4; ni++)
                kv[base + ni * 16 + lr] = f2bf(acc[mi][ni][j] * rc);
        }
    }
}

// ---------------------------------------------------------------------------
// small helpers
// ---------------------------------------------------------------------------
__global__ __launch_bounds__(256) void cvtbf_kernel(
    const float* __restrict__ x, unsigned short* __restrict__ y)
{
    long i = ((long)blockIdx.x * 256 + threadIdx.x) * 8;
    f32x4 a = *(const f32x4*)&x[i];
    f32x4 c = *(const f32x4*)&x[i + 4];
    short8 pk;
#pragma unroll
    for (int j = 0; j < 4; j++) { pk[j] = (short)f2bf(a[j]); pk[4 + j] = (short)f2bf(c[j]); }
    *(short8*)&y[i] = pk;
}

__global__ __launch_bounds__(256) void bcat_kernel(
    const float* __restrict__ bk, const float* __restrict__ bv, float* __restrict__ dst)
{
    int lyr = blockIdx.x;
    int j = blockIdx.y * 256 + threadIdx.x;
    dst[lyr * 1024 + j] = (j < 512) ? bk[lyr * 512 + j] : bv[lyr * 512 + j - 512];
}

// weight transpose + convert: Wt[n][k] = (bf16) W[k][n], per-layer strides
__global__ __launch_bounds__(256) void wconv_kernel(
    const float* __restrict__ W, unsigned short* __restrict__ Wt, int K, int N,
    long lstrW, long lstrT)
{
    __shared__ float tile[64 * 65];
    const long lz = blockIdx.z;
    const float* Wl = W + lz * lstrW;
    unsigned short* Wtl = Wt + lz * lstrT;
    const int k0 = blockIdx.x * 64, n0 = blockIdx.y * 64;
    const int t = threadIdx.x;
#pragma unroll
    for (int i = 0; i < 4; i++) {
        int q = i * 256 + t;
        int r = q >> 4, c4 = q & 15;
        f32x4 v = *(const f32x4*)&Wl[(long)(k0 + r) * N + n0 + c4 * 4];
#pragma unroll
        for (int j = 0; j < 4; j++) tile[r * 65 + c4 * 4 + j] = v[j];
    }
    __syncthreads();
#pragma unroll
    for (int i = 0; i < 4; i++) {
        int q = i * 256 + t;
        int nr = q >> 4, kc = q & 15;
        ushort4v pk;
#pragma unroll
        for (int j = 0; j < 4; j++) pk[j] = f2bf(tile[(kc * 4 + j) * 65 + nr]);
        *(ushort4v*)&Wtl[(long)(n0 + nr) * K + k0 + kc * 4] = pk;
    }
}

// ---------------------------------------------------------------------------
// Host orchestration.  ws ~121 MiB.
// F1 = d_out = f32 cross-layer residual stream (written only by LN2).
// LN1 writes ONLY bf16 (R1); LN2 reads its residual from R1 as bf16.
// KV: {K|V} -> {ATTN|phiQ} -> HBF(64M).  R1: XBF -> X1BF -> XBF(next).
// ---------------------------------------------------------------------------
extern "C" void kernel_launch(void* const* d_in, const int* in_sizes, int n_in,
                              void* d_out, int out_size, void* d_ws, size_t ws_size,
                              hipStream_t stream)
{
    const float* src  = (const float*)d_in[0];
    const float* Wq   = (const float*)d_in[1];
    const float* bq   = (const float*)d_in[2];
    const float* Wk   = (const float*)d_in[3];
    const float* bk   = (const float*)d_in[4];
    const float* Wv   = (const float*)d_in[5];
    const float* bv   = (const float*)d_in[6];
    const float* Wo   = (const float*)d_in[7];
    const float* bo   = (const float*)d_in[8];
    const float* l1g  = (const float*)d_in[9];
    const float* l1b  = (const float*)d_in[10];
    const float* W1   = (const float*)d_in[11];
    const float* b1   = (const float*)d_in[12];
    const float* W2   = (const float*)d_in[13];
    const float* b2   = (const float*)d_in[14];
    const float* l2g  = (const float*)d_in[15];
    const float* l2b  = (const float*)d_in[16];

    char* ws = (char*)d_ws;
    constexpr size_t SZ_WKV = (size_t)4 * 1024 * 512 * 2;
    constexpr size_t SZ_WQ  = (size_t)4 * 512 * 512 * 2;
    constexpr size_t SZ_WO  = SZ_WQ;
    constexpr size_t SZ_W1  = (size_t)4 * 512 * 1024 * 2;
    constexpr size_t SZ_W2  = SZ_W1;
    constexpr size_t SZ_BKV = (size_t)4 * 1024 * 4;
    constexpr size_t SZ_R1  = (size_t)32768 * 512 * 2;
    constexpr size_t SZ_KV  = (size_t)32768 * 1024 * 2;
    constexpr size_t OFF_WKV = 0;
    constexpr size_t OFF_WQ  = OFF_WKV + SZ_WKV;
    constexpr size_t OFF_WO  = OFF_WQ + SZ_WQ;
    constexpr size_t OFF_W1  = OFF_WO + SZ_WO;
    constexpr size_t OFF_W2  = OFF_W1 + SZ_W1;
    constexpr size_t OFF_BKV = OFF_W2 + SZ_W2;
    constexpr size_t OFF_R1  = OFF_BKV + SZ_BKV;
    constexpr size_t OFF_KV  = OFF_R1 + SZ_R1;
    constexpr size_t OFF_KSP = OFF_KV + SZ_KV;
    constexpr size_t OFF_CTP = OFF_KSP + (size_t)16 * 4096 * 4;
    constexpr size_t OFF_CTA = OFF_CTP + (size_t)64 * 8 * 4096 * 4;

    unsigned short* WKVT = (unsigned short*)(ws + OFF_WKV);
    unsigned short* WQT  = (unsigned short*)(ws + OFF_WQ);
    unsigned short* WOT  = (unsigned short*)(ws + OFF_WO);
    unsigned short* W1T  = (unsigned short*)(ws + OFF_W1);
    unsigned short* W2T  = (unsigned short*)(ws + OFF_W2);
    float*          BKV  = (float*)(ws + OFF_BKV);
    unsigned short* R1   = (unsigned short*)(ws + OFF_R1);
    unsigned short* KV   = (unsigned short*)(ws + OFF_KV);
    float*          KSP  = (float*)(ws + OFF_KSP);
    float*          CTP  = (float*)(ws + OFF_CTP);
    unsigned short* CTA  = (unsigned short*)(ws + OFF_CTA);
    float*          F1   = (float*)d_out;    // f32 cross-layer residual stream

    dim3 blk(256);
    wconv_kernel<<<dim3(8, 8, 4),  blk, 0, stream>>>(Wk, WKVT,            512, 512, 512*512, 1024*512);
    wconv_kernel<<<dim3(8, 8, 4),  blk, 0, stream>>>(Wv, WKVT + 512*512,  512, 512, 512*512, 1024*512);
    wconv_kernel<<<dim3(8, 8, 4),  blk, 0, stream>>>(Wq, WQT,             512, 512, 512*512, 512*512);
    wconv_kernel<<<dim3(8, 8, 4),  blk, 0, stream>>>(Wo, WOT,             512, 512, 512*512, 512*512);
    wconv_kernel<<<dim3(8, 16, 4), blk, 0, stream>>>(W1, W1T,             512, 1024, 512*1024, 512*1024);
    wconv_kernel<<<dim3(16, 8, 4), blk, 0, stream>>>(W2, W2T,             1024, 512, 1024*512, 1024*512);
    bcat_kernel<<<dim3(4, 4), blk, 0, stream>>>(bk, bv, BKV);
    cvtbf_kernel<<<8192, blk, 0, stream>>>(src, R1);

    for (int lyr = 0; lyr < 4; lyr++) {
        const unsigned short* wkvt = WKVT + (size_t)lyr * 1024 * 512;
        const unsigned short* wqt  = WQT  + (size_t)lyr * 512 * 512;
        const unsigned short* wot  = WOT  + (size_t)lyr * 512 * 512;
        const unsigned short* w1t  = W1T  + (size_t)lyr * 512 * 1024;
        const unsigned short* w2t  = W2T  + (size_t)lyr * 1024 * 512;

        // K|V fused GEMM (elu on cols<512), N=1024 -> nshift=3, grid 2048
        gemm_kernel<0><<<2048, blk, 0, stream>>>(R1, 512, wkvt, BKV + lyr * 1024, KV, 1024, 3, 512);

        // ctx + ksum in one pass over KV
        ctx_partial_kernel<<<dim3(64, 8), blk, 0, stream>>>(KV, CTP, KSP);
        ctx_reduce_kernel<<<256, blk, 0, stream>>>(CTP, KSP, CTA);

        // phiQ into V slot (dead), N=512 -> nshift=2, grid 1024
        gemm_kernel<0><<<1024, blk, 0, stream>>>(R1, 512, wqt, bq + lyr * 512, KV + 512, 1024, 2, 512);
        attn_out_kernel<<<dim3(64, 16), blk, 0, stream>>>(KV, CTA);

        // Wo + residual(f32 stream) + LN1 -> bf16 R1 ONLY (no f32 write)
        const void* resp = (lyr == 0) ? (const void*)src : (const void*)F1;
        gemm_ln_kernel<0, 0><<<256, dim3(512), 0, stream>>>(KV, 1024, wot, bo + lyr * 512, resp,
                                                            l1g + lyr * 512, l1b + lyr * 512,
                                                            F1, R1, 512);
        // FFN up + relu -> HBF (KV region, dead), N=1024 -> nshift=3
        gemm_kernel<2><<<2048, blk, 0, stream>>>(R1, 512, w1t, b1 + lyr * 1024, KV, 1024, 3, 512);
        // FFN down + residual(bf16 x1 from R1) + LN2 -> F1 f32 + R1 bf16
        gemm_ln_kernel<1, 1><<<256, dim3(512), 0, stream>>>(KV, 1024, w2t, b2 + lyr * 512, R1,
                                                            l2g + lyr * 512, l2b + lyr * 512,
                                                            F1, R1, 1024);
    }
}

// Round 12
// 1217.416 us; speedup vs baseline: 2.6025x; 1.0670x over previous
//
#include <hip/hip_runtime.h>
#include <hip/hip_bf16.h>
#include <cstdint>

typedef __attribute__((ext_vector_type(8))) short short8;
typedef __attribute__((ext_vector_type(4))) float f32x4;
typedef __attribute__((ext_vector_type(4))) unsigned short ushort4v;

#define DEV static __device__ __forceinline__

DEV float bf2f(unsigned short u) {
    union { unsigned int i; float f; } v; v.i = ((unsigned int)u) << 16; return v.f;
}
DEV unsigned short f2bf(float f) {
    union { float f; unsigned int i; } v; v.f = f;
    unsigned int x = v.i;
    unsigned int r = x + 0x7fffu + ((x >> 16) & 1u);
    return (unsigned short)(r >> 16);
}

// ---------------------------------------------------------------------------
// GEMM: C[M,N] = A[M,K](bf16, row-stride lda) @ Wt[N,K]^T + bias -> bf16 (ldc)
// 128x128 tile, 4 waves, 16x16x32 MFMA, BK=64, SINGLE-buffer LDS (r7-measured
// best: 65us; r11's BK=32 2-phase dbuf regressed ~+9us/dispatch -- at 4
// blocks/CU inter-block TLP already hides latency, and halving BK halved
// MFMA-per-barrier). XCD-aware 1D-grid swizzle.
// EPI 0: elu+1 applied iff col<512 | EPI 2: relu
// ---------------------------------------------------------------------------
template<int EPI>
__global__ __launch_bounds__(256) void gemm_kernel(
    const unsigned short* __restrict__ A, int lda,
    const unsigned short* __restrict__ Bt,
    const float* __restrict__ bias,
    unsigned short* __restrict__ outp, int ldc,
    int nshift, int K)
{
    __shared__ unsigned short lds[128 * 136];
    const int t  = threadIdx.x;
    const int w  = t >> 6, l = t & 63;
    const int wr = w >> 1, wc = w & 1;
    const int lr = l & 15, lg = l >> 4;
    const int bid = blockIdx.x;
    const int j8  = bid & 7, s = bid >> 3;
    const int bx  = j8 * 32 + (s >> nshift);
    const int by  = s & ((1 << nshift) - 1);
    const long tM = (long)bx * 128;
    const long tN = (long)by * 128;

    f32x4 acc[4][4];
#pragma unroll
    for (int i = 0; i < 4; i++)
#pragma unroll
        for (int j = 0; j < 4; j++) acc[i][j] = f32x4{0.f, 0.f, 0.f, 0.f};

    const unsigned short* Ab = A  + tM * lda;
    const unsigned short* Bb = Bt + tN * K;

    for (int kt = 0; kt < K; kt += 64) {
#pragma unroll
        for (int j = 0; j < 4; j++) {
            int c = (w * 4 + j) * 64 + l;
            int row = c >> 3, sc = (c & 7) ^ (row & 7);
            __builtin_amdgcn_global_load_lds(
                (const __attribute__((address_space(1))) void*)(Ab + (long)row * lda + kt + sc * 8),
                (__attribute__((address_space(3))) void*)(lds + (w * 4 + j) * 512),
                16, 0, 0);
        }
#pragma unroll
        for (int j = 0; j < 4; j++) {
            int c = (w * 4 + j) * 64 + l;
            int row = c >> 3, sc = (c & 7) ^ (row & 7);
            __builtin_amdgcn_global_load_lds(
                (const __attribute__((address_space(1))) void*)(Bb + (long)row * K + kt + sc * 8),
                (__attribute__((address_space(3))) void*)(lds + 8192 + (w * 4 + j) * 512),
                16, 0, 0);
        }
        __syncthreads();
#pragma unroll
        for (int kk = 0; kk < 2; kk++) {
            short8 af[4], bfv[4];
#pragma unroll
            for (int mi = 0; mi < 4; mi++) {
                int r  = wr * 64 + mi * 16 + lr;
                int kc = kk * 4 + lg;
                af[mi] = *(const short8*)&lds[r * 64 + ((kc ^ (r & 7)) << 3)];
            }
#pragma unroll
            for (int ni = 0; ni < 4; ni++) {
                int n  = wc * 64 + ni * 16 + lr;
                int kc = kk * 4 + lg;
                bfv[ni] = *(const short8*)&lds[8192 + n * 64 + ((kc ^ (n & 7)) << 3)];
            }
#pragma unroll
            for (int mi = 0; mi < 4; mi++)
#pragma unroll
                for (int ni = 0; ni < 4; ni++)
                    acc[mi][ni] = __builtin_amdgcn_mfma_f32_16x16x32_bf16(
                        af[mi], bfv[ni], acc[mi][ni], 0, 0, 0);
        }
        __syncthreads();
    }

    float bv[4];
#pragma unroll
    for (int ni = 0; ni < 4; ni++) bv[ni] = bias[tN + wc * 64 + ni * 16 + lr];
    const bool doElu = (EPI == 0) && (tN < 512);

#pragma unroll
    for (int mi = 0; mi < 4; mi++)
#pragma unroll
        for (int ni = 0; ni < 4; ni++)
#pragma unroll
            for (int j = 0; j < 4; j++) {
                float v = acc[mi][ni][j] + bv[ni];
                if (EPI == 0) { if (doElu) v = (v > 0.f) ? (v + 1.f) : expf(v); }
                if (EPI == 2) v = fmaxf(v, 0.f);
                int r = wr * 64 + mi * 16 + lg * 4 + j;
                int c = wc * 64 + ni * 16 + lr;
                lds[r * 136 + c] = f2bf(v);
            }
    __syncthreads();
#pragma unroll
    for (int i = 0; i < 8; i++) {
        int q = i * 256 + t;
        int r = q >> 4, cc = q & 15;
        short8 v8 = *(const short8*)&lds[r * 136 + cc * 8];
        *(short8*)&outp[(tM + r) * ldc + tN + cc * 8] = v8;
    }
}

// ---------------------------------------------------------------------------
// Fused GEMM + bias + residual + LayerNorm, 2-phase dbuf BK=32 (r10/r11
// proven: 74-76us @K=1024 vs 83 single-buffer -- this kernel IS 1 block/CU
// so the dbuf pays here, unlike the fat GEMM).
// RESBF: residual read bf16 (stream hop) vs f32 (src at layer 0).
// WRITEOF: write f32 copy (only the FINAL LN2 -> d_out).
// NO min-wave bound (r8: forced cap -> accumulator spill).
// ---------------------------------------------------------------------------
template<int RESBF, int WRITEOF>
__global__ __launch_bounds__(512) void gemm_ln_kernel(
    const unsigned short* __restrict__ A, int lda,
    const unsigned short* __restrict__ Bt,   // [512][K]
    const float* __restrict__ bias,          // [512]
    const void* __restrict__ resp,           // [M][512] f32 or bf16 (RESBF)
    const float* __restrict__ g,
    const float* __restrict__ be,
    float* __restrict__ of,                  // [M][512] f32 (if WRITEOF)
    unsigned short* __restrict__ ob,         // [M][512] bf16
    int K)
{
    __shared__ unsigned short sA[2][128 * 32];   // 2 x 8 KiB
    __shared__ unsigned short sB[2][512 * 32];   // 2 x 32 KiB
    float* redb  = (float*)&sA[0][0];            // epilogue alias: 4 KiB
    float* statb = redb + 1024;                  // 1 KiB
    const int t = threadIdx.x, w = t >> 6, l = t & 63, lr = l & 15, lg = l >> 4;
    const int wr = w >> 2, wc = w & 3;
    const long tM = (long)blockIdx.x * 128;

    f32x4 acc[4][8];
#pragma unroll
    for (int i = 0; i < 4; i++)
#pragma unroll
        for (int j = 0; j < 8; j++) acc[i][j] = f32x4{0.f, 0.f, 0.f, 0.f};

    const unsigned short* Ab = A + tM * lda;

    auto STAGE = [&](int buf, int kt) {
        {   // A: 128 rows x 4 chunks = 512 chunks, 1/thread
            int c = t, row = c >> 2, sc = (c & 3) ^ ((row >> 1) & 3);
            __builtin_amdgcn_global_load_lds(
                (const __attribute__((address_space(1))) void*)(Ab + (long)row * lda + kt + sc * 8),
                (__attribute__((address_space(3))) void*)(&sA[buf][(w * 64) * 8]),
                16, 0, 0);
        }
#pragma unroll
        for (int j = 0; j < 4; j++) {  // B: 512 rows x 4 chunks = 2048 chunks
            int c = j * 512 + t, row = c >> 2, sc = (c & 3) ^ ((row >> 1) & 3);
            __builtin_amdgcn_global_load_lds(
                (const __attribute__((address_space(1))) void*)(Bt + (long)row * K + kt + sc * 8),
                (__attribute__((address_space(3))) void*)(&sB[buf][(j * 512 + w * 64) * 8]),
                16, 0, 0);
        }
    };

    auto COMPUTE = [&](int buf) {
        short8 av[4], bw[8];
#pragma unroll
        for (int mi = 0; mi < 4; mi++) {
            int r = wr * 64 + mi * 16 + lr;
            av[mi] = *(const short8*)&sA[buf][r * 32 + ((lg ^ ((r >> 1) & 3)) << 3)];
        }
#pragma unroll
        for (int ni = 0; ni < 8; ni++) {
            int n = wc * 128 + ni * 16 + lr;
            bw[ni] = *(const short8*)&sB[buf][n * 32 + ((lg ^ ((n >> 1) & 3)) << 3)];
        }
#pragma unroll
        for (int mi = 0; mi < 4; mi++)
#pragma unroll
            for (int ni = 0; ni < 8; ni++)
                acc[mi][ni] = __builtin_amdgcn_mfma_f32_16x16x32_bf16(
                    av[mi], bw[ni], acc[mi][ni], 0, 0, 0);
    };

    STAGE(0, 0);
    __syncthreads();
    int cur = 0;
    for (int kt = 32; kt < K; kt += 32) {
        STAGE(cur ^ 1, kt);
        COMPUTE(cur);
        __syncthreads();
        cur ^= 1;
    }
    COMPUTE(cur);

    // epilogue: v = C + bias + res; LN over the 512-wide row
    const float* resf = (const float*)resp;
    const unsigned short* resb = (const unsigned short*)resp;
    float gv[8], bev[8], bb[8];
#pragma unroll
    for (int ni = 0; ni < 8; ni++) {
        int col = wc * 128 + ni * 16 + lr;
        gv[ni] = g[col]; bev[ni] = be[col]; bb[ni] = bias[col];
    }
#pragma unroll
    for (int mi = 0; mi < 4; mi++)
#pragma unroll
        for (int jj = 0; jj < 4; jj++) {
            long row = tM + wr * 64 + mi * 16 + lg * 4 + jj;
#pragma unroll
            for (int ni = 0; ni < 8; ni++) {
                int col = wc * 128 + ni * 16 + lr;
                float rv = RESBF ? bf2f(resb[row * 512 + col]) : resf[row * 512 + col];
                acc[mi][ni][jj] += bb[ni] + rv;
            }
        }
    float s2[4][4], ss2[4][4];
#pragma unroll
    for (int mi = 0; mi < 4; mi++)
#pragma unroll
        for (int jj = 0; jj < 4; jj++) {
            float s = 0.f, ss = 0.f;
#pragma unroll
            for (int ni = 0; ni < 8; ni++) {
                float v = acc[mi][ni][jj];
                s += v; ss += v * v;
            }
#pragma unroll
            for (int off = 1; off < 16; off <<= 1) {
                s  += __shfl_xor(s, off);
                ss += __shfl_xor(ss, off);
            }
            s2[mi][jj] = s; ss2[mi][jj] = ss;
        }
    __syncthreads();   // all waves past final COMPUTE before aliasing sA[0]
    if (lr == 0) {
#pragma unroll
        for (int mi = 0; mi < 4; mi++)
#pragma unroll
            for (int jj = 0; jj < 4; jj++) {
                int rb = wr * 64 + mi * 16 + lg * 4 + jj;
                redb[0 * 512 + wc * 128 + rb] = s2[mi][jj];
                redb[1 * 512 + wc * 128 + rb] = ss2[mi][jj];
            }
    }
    __syncthreads();
    if (t < 128) {
        float S  = redb[t] + redb[128 + t] + redb[256 + t] + redb[384 + t];
        float SS = redb[512 + t] + redb[640 + t] + redb[768 + t] + redb[896 + t];
        float mean = S * (1.0f / 512.0f);
        float var  = SS * (1.0f / 512.0f) - mean * mean;
        statb[t] = mean;
        statb[128 + t] = rsqrtf(fmaxf(var, 0.f) + 1e-5f);
    }
    __syncthreads();
#pragma unroll
    for (int mi = 0; mi < 4; mi++)
#pragma unroll
        for (int jj = 0; jj < 4; jj++) {
            int rb = wr * 64 + mi * 16 + lg * 4 + jj;
            long row = tM + rb;
            float mean = statb[rb], rstd = statb[128 + rb];
#pragma unroll
            for (int ni = 0; ni < 8; ni++) {
                int col = wc * 128 + ni * 16 + lr;
                float y = (acc[mi][ni][jj] - mean) * rstd * gv[ni] + bev[ni];
                if (WRITEOF) of[row * 512 + col] = y;
                ob[row * 512 + col] = f2bf(y);
            }
        }
}

// ---------------------------------------------------------------------------
// Attention glue. KVbuf[(s*8+b)][1024]: cols 0..511 = phiK (later ATTN),
// cols 512..1023 = V (later phiQ).
// ctx_partial also accumulates ksum_d = sum_s phiK[s][d] (part2).
// ---------------------------------------------------------------------------
__global__ __launch_bounds__(256) void ctx_partial_kernel(
    const unsigned short* __restrict__ kv, float* __restrict__ part,
    float* __restrict__ part2)
{
    const int p = blockIdx.x, ch = blockIdx.y;
    const int b = p >> 3, h = p & 7;
    __shared__ float kb[64 * 68];
    __shared__ float vbuf[64 * 68];
    const int t = threadIdx.x;
    const int dq = t >> 4, eq = t & 15;
    f32x4 acc[4];
    f32x4 ks = {0.f, 0.f, 0.f, 0.f};
#pragma unroll
    for (int i = 0; i < 4; i++) acc[i] = f32x4{0.f, 0.f, 0.f, 0.f};

    for (int sub = 0; sub < 8; sub++) {
        int sbase = ch * 512 + sub * 64;
#pragma unroll
        for (int i = 0; i < 2; i++) {
            int idx = i * 256 + t;
            int row = idx >> 3, c8 = idx & 7;
            long ga = ((long)(sbase + row) * 8 + b) * 1024 + h * 64 + c8 * 8;
            short8 kvv = *(const short8*)&kv[ga];
            short8 vv  = *(const short8*)&kv[ga + 512];
#pragma unroll
            for (int j = 0; j < 8; j++) {
                kb[row * 68 + c8 * 8 + j]   = bf2f((unsigned short)kvv[j]);
                vbuf[row * 68 + c8 * 8 + j] = bf2f((unsigned short)vv[j]);
            }
        }
        __syncthreads();
        for (int s = 0; s < 64; s++) {
            f32x4 k4 = *(const f32x4*)&kb[s * 68 + dq * 4];
            f32x4 v4 = *(const f32x4*)&vbuf[s * 68 + eq * 4];
#pragma unroll
            for (int i = 0; i < 4; i++) acc[i] += k4[i] * v4;
            ks += k4;
        }
        __syncthreads();
    }
    float* o = part + (long)(p * 8 + ch) * 4096;
#pragma unroll
    for (int i = 0; i < 4; i++)
        *(f32x4*)&o[(dq * 4 + i) * 64 + eq * 4] = acc[i];
    if (eq == 0)
        *(f32x4*)&part2[(p * 8 + ch) * 64 + dq * 4] = ks;
}

// reduce ctx partials -> ctxA[p][n=e][k=d] (bf16, transposed); finalize ksum
// into row n=64, zero rows 65..79
__global__ __launch_bounds__(256) void ctx_reduce_kernel(
    const float* __restrict__ part, const float* __restrict__ part2,
    unsigned short* __restrict__ ctxA)
{
    int o = (blockIdx.x * 256 + threadIdx.x) * 4;
    int p = o >> 12, d = (o >> 6) & 63, e0 = o & 63;
    f32x4 s = {0.f, 0.f, 0.f, 0.f};
    for (int ch = 0; ch < 8; ch++)
        s += *(const f32x4*)&part[(long)(p * 8 + ch) * 4096 + d * 64 + e0];
#pragma unroll
    for (int j = 0; j < 4; j++) ctxA[p * 5120 + (e0 + j) * 64 + d] = f2bf(s[j]);
    if (e0 == 0) {
        float ksv = 0.f;
#pragma unroll
        for (int ch = 0; ch < 8; ch++) ksv += part2[(p * 8 + ch) * 64 + d];
        ctxA[p * 5120 + 4096 + d] = f2bf(ksv);
#pragma unroll
        for (int j = 1; j < 16; j++) ctxA[p * 5120 + 4096 + j * 64 + d] = 0;
    }
}

// out = phiQ @ [ctx | ksum]; ni=4 accumulates denominator; normalize -> bf16
__global__ __launch_bounds__(256) void attn_out_kernel(
    unsigned short* __restrict__ kv,
    const unsigned short* __restrict__ ctxA)
{
    const int p = blockIdx.x;
    const int b = p >> 3, h = p & 7;
    const int t = threadIdx.x, w = t >> 6, l = t & 63, lr = l & 15, lg = l >> 4;
    const int s0 = blockIdx.y * 256 + w * 64;
    f32x4 acc[4][5];
#pragma unroll
    for (int i = 0; i < 4; i++)
#pragma unroll
        for (int j = 0; j < 5; j++) acc[i][j] = f32x4{0.f, 0.f, 0.f, 0.f};
    const unsigned short* cb = ctxA + p * 5120;
#pragma unroll
    for (int kk = 0; kk < 2; kk++) {
        short8 af[4], bfv[5];
#pragma unroll
        for (int mi = 0; mi < 4; mi++) {
            int s = s0 + mi * 16 + lr;
            af[mi] = *(const short8*)&kv[((long)s * 8 + b) * 1024 + 512 + h * 64 + kk * 32 + lg * 8];
        }
#pragma unroll
        for (int ni = 0; ni < 5; ni++)
            bfv[ni] = *(const short8*)&cb[(ni * 16 + lr) * 64 + kk * 32 + lg * 8];
#pragma unroll
        for (int mi = 0; mi < 4; mi++)
#pragma unroll
            for (int ni = 0; ni < 5; ni++)
                acc[mi][ni] = __builtin_amdgcn_mfma_f32_16x16x32_bf16(
                    af[mi], bfv[ni], acc[mi][ni], 0, 0, 0);
    }
#pragma unroll
    for (int mi = 0; mi < 4; mi++) {
#pragma unroll
        for (int j = 0; j < 4; j++) {
            float den = __shfl(acc[mi][4][j], (l & 48));
            float rc  = 1.0f / (den + 1e-6f);
            int s = s0 + mi * 16 + lg * 4 + j;
            long base = ((long)s * 8 + b) * 1024 + h * 64;
#pragma unroll
            for (int ni = 0; ni < 4; ni++)
                kv[base + ni * 16 + lr] = f2bf(acc[mi][ni][j] * rc);
        }
    }
}

// ---------------------------------------------------------------------------
// small helpers
// ---------------------------------------------------------------------------
__global__ __launch_bounds__(256) void cvtbf_kernel(
    const float* __restrict__ x, unsigned short* __restrict__ y)
{
    long i = ((long)blockIdx.x * 256 + threadIdx.x) * 8;
    f32x4 a = *(const f32x4*)&x[i];
    f32x4 c = *(const f32x4*)&x[i + 4];
    short8 pk;
#pragma unroll
    for (int j = 0; j < 4; j++) { pk[j] = (short)f2bf(a[j]); pk[4 + j] = (short)f2bf(c[j]); }
    *(short8*)&y[i] = pk;
}

__global__ __launch_bounds__(256) void bcat_kernel(
    const float* __restrict__ bk, const float* __restrict__ bv, float* __restrict__ dst)
{
    int lyr = blockIdx.x;
    int j = blockIdx.y * 256 + threadIdx.x;
    dst[lyr * 1024 + j] = (j < 512) ? bk[lyr * 512 + j] : bv[lyr * 512 + j - 512];
}

// weight transpose + convert: Wt[n][k] = (bf16) W[k][n], per-layer strides
__global__ __launch_bounds__(256) void wconv_kernel(
    const float* __restrict__ W, unsigned short* __restrict__ Wt, int K, int N,
    long lstrW, long lstrT)
{
    __shared__ float tile[64 * 65];
    const long lz = blockIdx.z;
    const float* Wl = W + lz * lstrW;
    unsigned short* Wtl = Wt + lz * lstrT;
    const int k0 = blockIdx.x * 64, n0 = blockIdx.y * 64;
    const int t = threadIdx.x;
#pragma unroll
    for (int i = 0; i < 4; i++) {
        int q = i * 256 + t;
        int r = q >> 4, c4 = q & 15;
        f32x4 v = *(const f32x4*)&Wl[(long)(k0 + r) * N + n0 + c4 * 4];
#pragma unroll
        for (int j = 0; j < 4; j++) tile[r * 65 + c4 * 4 + j] = v[j];
    }
    __syncthreads();
#pragma unroll
    for (int i = 0; i < 4; i++) {
        int q = i * 256 + t;
        int nr = q >> 4, kc = q & 15;
        ushort4v pk;
#pragma unroll
        for (int j = 0; j < 4; j++) pk[j] = f2bf(tile[(kc * 4 + j) * 65 + nr]);
        *(ushort4v*)&Wtl[(long)(n0 + nr) * K + k0 + kc * 4] = pk;
    }
}

// ---------------------------------------------------------------------------
// Host orchestration.  ws ~121 MiB.
// Stream: R1 bf16 (in-place LN RMW hops). F1 = d_out written ONCE by the
// final LN2 (f32). LN1 residual: src f32 (lyr0) / R1 bf16. LN2 residual: R1.
// Numerics = r5's bf16-stream scheme (measured absmax 0.09375 < 0.107).
// KV: {K|V} -> {ATTN|phiQ} -> HBF(64M).
// ---------------------------------------------------------------------------
extern "C" void kernel_launch(void* const* d_in, const int* in_sizes, int n_in,
                              void* d_out, int out_size, void* d_ws, size_t ws_size,
                              hipStream_t stream)
{
    const float* src  = (const float*)d_in[0];
    const float* Wq   = (const float*)d_in[1];
    const float* bq   = (const float*)d_in[2];
    const float* Wk   = (const float*)d_in[3];
    const float* bk   = (const float*)d_in[4];
    const float* Wv   = (const float*)d_in[5];
    const float* bv   = (const float*)d_in[6];
    const float* Wo   = (const float*)d_in[7];
    const float* bo   = (const float*)d_in[8];
    const float* l1g  = (const float*)d_in[9];
    const float* l1b  = (const float*)d_in[10];
    const float* W1   = (const float*)d_in[11];
    const float* b1   = (const float*)d_in[12];
    const float* W2   = (const float*)d_in[13];
    const float* b2   = (const float*)d_in[14];
    const float* l2g  = (const float*)d_in[15];
    const float* l2b  = (const float*)d_in[16];

    char* ws = (char*)d_ws;
    constexpr size_t SZ_WKV = (size_t)4 * 1024 * 512 * 2;
    constexpr size_t SZ_WQ  = (size_t)4 * 512 * 512 * 2;
    constexpr size_t SZ_WO  = SZ_WQ;
    constexpr size_t SZ_W1  = (size_t)4 * 512 * 1024 * 2;
    constexpr size_t SZ_W2  = SZ_W1;
    constexpr size_t SZ_BKV = (size_t)4 * 1024 * 4;
    constexpr size_t SZ_R1  = (size_t)32768 * 512 * 2;
    constexpr size_t SZ_KV  = (size_t)32768 * 1024 * 2;
    constexpr size_t OFF_WKV = 0;
    constexpr size_t OFF_WQ  = OFF_WKV + SZ_WKV;
    constexpr size_t OFF_WO  = OFF_WQ + SZ_WQ;
    constexpr size_t OFF_W1  = OFF_WO + SZ_WO;
    constexpr size_t OFF_W2  = OFF_W1 + SZ_W1;
    constexpr size_t OFF_BKV = OFF_W2 + SZ_W2;
    constexpr size_t OFF_R1  = OFF_BKV + SZ_BKV;
    constexpr size_t OFF_KV  = OFF_R1 + SZ_R1;
    constexpr size_t OFF_KSP = OFF_KV + SZ_KV;
    constexpr size_t OFF_CTP = OFF_KSP + (size_t)16 * 4096 * 4;
    constexpr size_t OFF_CTA = OFF_CTP + (size_t)64 * 8 * 4096 * 4;

    unsigned short* WKVT = (unsigned short*)(ws + OFF_WKV);
    unsigned short* WQT  = (unsigned short*)(ws + OFF_WQ);
    unsigned short* WOT  = (unsigned short*)(ws + OFF_WO);
    unsigned short* W1T  = (unsigned short*)(ws + OFF_W1);
    unsigned short* W2T  = (unsigned short*)(ws + OFF_W2);
    float*          BKV  = (float*)(ws + OFF_BKV);
    unsigned short* R1   = (unsigned short*)(ws + OFF_R1);
    unsigned short* KV   = (unsigned short*)(ws + OFF_KV);
    float*          KSP  = (float*)(ws + OFF_KSP);
    float*          CTP  = (float*)(ws + OFF_CTP);
    unsigned short* CTA  = (unsigned short*)(ws + OFF_CTA);
    float*          F1   = (float*)d_out;    // final f32 output (written once)

    dim3 blk(256);
    wconv_kernel<<<dim3(8, 8, 4),  blk, 0, stream>>>(Wk, WKVT,            512, 512, 512*512, 1024*512);
    wconv_kernel<<<dim3(8, 8, 4),  blk, 0, stream>>>(Wv, WKVT + 512*512,  512, 512, 512*512, 1024*512);
    wconv_kernel<<<dim3(8, 8, 4),  blk, 0, stream>>>(Wq, WQT,             512, 512, 512*512, 512*512);
    wconv_kernel<<<dim3(8, 8, 4),  blk, 0, stream>>>(Wo, WOT,             512, 512, 512*512, 512*512);
    wconv_kernel<<<dim3(8, 16, 4), blk, 0, stream>>>(W1, W1T,             512, 1024, 512*1024, 512*1024);
    wconv_kernel<<<dim3(16, 8, 4), blk, 0, stream>>>(W2, W2T,             1024, 512, 1024*512, 1024*512);
    bcat_kernel<<<dim3(4, 4), blk, 0, stream>>>(bk, bv, BKV);
    cvtbf_kernel<<<8192, blk, 0, stream>>>(src, R1);

    for (int lyr = 0; lyr < 4; lyr++) {
        const unsigned short* wkvt = WKVT + (size_t)lyr * 1024 * 512;
        const unsigned short* wqt  = WQT  + (size_t)lyr * 512 * 512;
        const unsigned short* wot  = WOT  + (size_t)lyr * 512 * 512;
        const unsigned short* w1t  = W1T  + (size_t)lyr * 512 * 1024;
        const unsigned short* w2t  = W2T  + (size_t)lyr * 1024 * 512;

        // K|V fused GEMM (elu on cols<512), N=1024 -> nshift=3, grid 2048
        gemm_kernel<0><<<2048, blk, 0, stream>>>(R1, 512, wkvt, BKV + lyr * 1024, KV, 1024, 3, 512);

        // ctx + ksum in one pass over KV
        ctx_partial_kernel<<<dim3(64, 8), blk, 0, stream>>>(KV, CTP, KSP);
        ctx_reduce_kernel<<<256, blk, 0, stream>>>(CTP, KSP, CTA);

        // phiQ into V slot (dead), N=512 -> nshift=2, grid 1024
        gemm_kernel<0><<<1024, blk, 0, stream>>>(R1, 512, wqt, bq + lyr * 512, KV + 512, 1024, 2, 512);
        attn_out_kernel<<<dim3(64, 16), blk, 0, stream>>>(KV, CTA);

        // Wo + residual + LN1 -> bf16 R1 only (in-place RMW on R1)
        if (lyr == 0)
            gemm_ln_kernel<0, 0><<<256, dim3(512), 0, stream>>>(KV, 1024, wot, bo + lyr * 512, src,
                                                                l1g + lyr * 512, l1b + lyr * 512,
                                                                F1, R1, 512);
        else
            gemm_ln_kernel<1, 0><<<256, dim3(512), 0, stream>>>(KV, 1024, wot, bo + lyr * 512, R1,
                                                                l1g + lyr * 512, l1b + lyr * 512,
                                                                F1, R1, 512);
        // FFN up + relu -> HBF (KV region, dead), N=1024 -> nshift=3
        gemm_kernel<2><<<2048, blk, 0, stream>>>(R1, 512, w1t, b1 + lyr * 1024, KV, 1024, 3, 512);
        // FFN down + residual(R1 bf16) + LN2 -> R1 bf16; final layer also f32 d_out
        if (lyr == 3)
            gemm_ln_kernel<1, 1><<<256, dim3(512), 0, stream>>>(KV, 1024, w2t, b2 + lyr * 512, R1,
                                                                l2g + lyr * 512, l2b + lyr * 512,
                                                                F1, R1, 1024);
        else
            gemm_ln_kernel<1, 0><<<256, dim3(512), 0, stream>>>(KV, 1024, w2t, b2 + lyr * 512, R1,
                                                                l2g + lyr * 512, l2b + lyr * 512,
                                                                F1, R1, 1024);
    }
}

// Round 13
// 1167.630 us; speedup vs baseline: 2.7134x; 1.0426x over previous
//
#include <hip/hip_runtime.h>
#include <hip/hip_bf16.h>
#include <cstdint>

typedef __attribute__((ext_vector_type(8))) short short8;
typedef __attribute__((ext_vector_type(4))) float f32x4;
typedef __attribute__((ext_vector_type(4))) unsigned short ushort4v;

#define DEV static __device__ __forceinline__

DEV float bf2f(unsigned short u) {
    union { unsigned int i; float f; } v; v.i = ((unsigned int)u) << 16; return v.f;
}
DEV unsigned short f2bf(float f) {
    union { float f; unsigned int i; } v; v.f = f;
    unsigned int x = v.i;
    unsigned int r = x + 0x7fffu + ((x >> 16) & 1u);
    return (unsigned short)(r >> 16);
}

// ---------------------------------------------------------------------------
// GEMM: C[M,N] = A[M,K](bf16, lda) @ Bt[N,K]^T + bias -> bf16.
// 128x128 tile, 4 waves, BK=64 single-buffer (r7-best), XCD swizzle with
// compile-time NBY (grid = 256*NBY, bx = (bid&7)*32 + s/NBY, by = s%NBY --
// bijective for any NBY<=32; div folds to shifts/magic-mul at compile time).
// EPI 0 (KVQ, NBY=12): elu+1 on cols<512 (K) and >=1024 (Q); Q cols stored
// to out2 (stride 512), K|V to out1 (ldc1). EPI 2 (W1, NBY=8): relu -> out1.
// ---------------------------------------------------------------------------
template<int EPI, int NBY>
__global__ __launch_bounds__(256) void gemm_kernel(
    const unsigned short* __restrict__ A, int lda,
    const unsigned short* __restrict__ Bt,
    const float* __restrict__ bias,
    unsigned short* __restrict__ out1, int ldc1,
    unsigned short* __restrict__ out2,
    int K)
{
    __shared__ unsigned short lds[128 * 136];
    const int t  = threadIdx.x;
    const int w  = t >> 6, l = t & 63;
    const int wr = w >> 1, wc = w & 1;
    const int lr = l & 15, lg = l >> 4;
    const int bid = blockIdx.x;
    const int j8  = bid & 7, s = bid >> 3;
    const int bx  = j8 * 32 + s / NBY;
    const int by  = s % NBY;
    const long tM = (long)bx * 128;
    const long tN = (long)by * 128;

    f32x4 acc[4][4];
#pragma unroll
    for (int i = 0; i < 4; i++)
#pragma unroll
        for (int j = 0; j < 4; j++) acc[i][j] = f32x4{0.f, 0.f, 0.f, 0.f};

    const unsigned short* Ab = A  + tM * lda;
    const unsigned short* Bb = Bt + tN * K;

    for (int kt = 0; kt < K; kt += 64) {
#pragma unroll
        for (int j = 0; j < 4; j++) {
            int c = (w * 4 + j) * 64 + l;
            int row = c >> 3, sc = (c & 7) ^ (row & 7);
            __builtin_amdgcn_global_load_lds(
                (const __attribute__((address_space(1))) void*)(Ab + (long)row * lda + kt + sc * 8),
                (__attribute__((address_space(3))) void*)(lds + (w * 4 + j) * 512),
                16, 0, 0);
        }
#pragma unroll
        for (int j = 0; j < 4; j++) {
            int c = (w * 4 + j) * 64 + l;
            int row = c >> 3, sc = (c & 7) ^ (row & 7);
            __builtin_amdgcn_global_load_lds(
                (const __attribute__((address_space(1))) void*)(Bb + (long)row * K + kt + sc * 8),
                (__attribute__((address_space(3))) void*)(lds + 8192 + (w * 4 + j) * 512),
                16, 0, 0);
        }
        __syncthreads();
#pragma unroll
        for (int kk = 0; kk < 2; kk++) {
            short8 af[4], bfv[4];
#pragma unroll
            for (int mi = 0; mi < 4; mi++) {
                int r  = wr * 64 + mi * 16 + lr;
                int kc = kk * 4 + lg;
                af[mi] = *(const short8*)&lds[r * 64 + ((kc ^ (r & 7)) << 3)];
            }
#pragma unroll
            for (int ni = 0; ni < 4; ni++) {
                int n  = wc * 64 + ni * 16 + lr;
                int kc = kk * 4 + lg;
                bfv[ni] = *(const short8*)&lds[8192 + n * 64 + ((kc ^ (n & 7)) << 3)];
            }
#pragma unroll
            for (int mi = 0; mi < 4; mi++)
#pragma unroll
                for (int ni = 0; ni < 4; ni++)
                    acc[mi][ni] = __builtin_amdgcn_mfma_f32_16x16x32_bf16(
                        af[mi], bfv[ni], acc[mi][ni], 0, 0, 0);
        }
        __syncthreads();
    }

    float bv[4];
#pragma unroll
    for (int ni = 0; ni < 4; ni++) bv[ni] = bias[tN + wc * 64 + ni * 16 + lr];
    const bool doElu = (EPI == 0) && (tN < 512 || tN >= 1024);

#pragma unroll
    for (int mi = 0; mi < 4; mi++)
#pragma unroll
        for (int ni = 0; ni < 4; ni++)
#pragma unroll
            for (int j = 0; j < 4; j++) {
                float v = acc[mi][ni][j] + bv[ni];
                if (EPI == 0) { if (doElu) v = (v > 0.f) ? (v + 1.f) : expf(v); }
                if (EPI == 2) v = fmaxf(v, 0.f);
                int r = wr * 64 + mi * 16 + lg * 4 + j;
                int c = wc * 64 + ni * 16 + lr;
                lds[r * 136 + c] = f2bf(v);
            }
    __syncthreads();
    const bool toQ = (NBY == 12) && (tN >= 1024);
    unsigned short* o = toQ ? out2 : out1;
    const long ldc   = toQ ? 512 : ldc1;
    const long cb    = toQ ? (tN - 1024) : tN;
#pragma unroll
    for (int i = 0; i < 8; i++) {
        int q = i * 256 + t;
        int r = q >> 4, cc = q & 15;
        short8 v8 = *(const short8*)&lds[r * 136 + cc * 8];
        *(short8*)&o[(tM + r) * ldc + cb + cc * 8] = v8;
    }
}

// ---------------------------------------------------------------------------
// Fused GEMM + bias + residual + LayerNorm, 2-phase dbuf BK=32 (r10-r12
// proven). RESBF: residual bf16 (stream hop) vs f32 (src, layer 0).
// WRITEOF: also write f32 (final LN2 -> d_out only).
// NO min-wave bound (r8: forced cap -> accumulator spill).
// ---------------------------------------------------------------------------
template<int RESBF, int WRITEOF>
__global__ __launch_bounds__(512) void gemm_ln_kernel(
    const unsigned short* __restrict__ A, int lda,
    const unsigned short* __restrict__ Bt,   // [512][K]
    const float* __restrict__ bias,          // [512]
    const void* __restrict__ resp,           // [M][512] f32 or bf16 (RESBF)
    const float* __restrict__ g,
    const float* __restrict__ be,
    float* __restrict__ of,                  // [M][512] f32 (if WRITEOF)
    unsigned short* __restrict__ ob,         // [M][512] bf16
    int K)
{
    __shared__ unsigned short sA[2][128 * 32];   // 2 x 8 KiB
    __shared__ unsigned short sB[2][512 * 32];   // 2 x 32 KiB
    float* redb  = (float*)&sA[0][0];            // epilogue alias: 4 KiB
    float* statb = redb + 1024;                  // 1 KiB
    const int t = threadIdx.x, w = t >> 6, l = t & 63, lr = l & 15, lg = l >> 4;
    const int wr = w >> 2, wc = w & 3;
    const long tM = (long)blockIdx.x * 128;

    f32x4 acc[4][8];
#pragma unroll
    for (int i = 0; i < 4; i++)
#pragma unroll
        for (int j = 0; j < 8; j++) acc[i][j] = f32x4{0.f, 0.f, 0.f, 0.f};

    const unsigned short* Ab = A + tM * lda;

    auto STAGE = [&](int buf, int kt) {
        {
            int c = t, row = c >> 2, sc = (c & 3) ^ ((row >> 1) & 3);
            __builtin_amdgcn_global_load_lds(
                (const __attribute__((address_space(1))) void*)(Ab + (long)row * lda + kt + sc * 8),
                (__attribute__((address_space(3))) void*)(&sA[buf][(w * 64) * 8]),
                16, 0, 0);
        }
#pragma unroll
        for (int j = 0; j < 4; j++) {
            int c = j * 512 + t, row = c >> 2, sc = (c & 3) ^ ((row >> 1) & 3);
            __builtin_amdgcn_global_load_lds(
                (const __attribute__((address_space(1))) void*)(Bt + (long)row * K + kt + sc * 8),
                (__attribute__((address_space(3))) void*)(&sB[buf][(j * 512 + w * 64) * 8]),
                16, 0, 0);
        }
    };

    auto COMPUTE = [&](int buf) {
        short8 av[4], bw[8];
#pragma unroll
        for (int mi = 0; mi < 4; mi++) {
            int r = wr * 64 + mi * 16 + lr;
            av[mi] = *(const short8*)&sA[buf][r * 32 + ((lg ^ ((r >> 1) & 3)) << 3)];
        }
#pragma unroll
        for (int ni = 0; ni < 8; ni++) {
            int n = wc * 128 + ni * 16 + lr;
            bw[ni] = *(const short8*)&sB[buf][n * 32 + ((lg ^ ((n >> 1) & 3)) << 3)];
        }
#pragma unroll
        for (int mi = 0; mi < 4; mi++)
#pragma unroll
            for (int ni = 0; ni < 8; ni++)
                acc[mi][ni] = __builtin_amdgcn_mfma_f32_16x16x32_bf16(
                    av[mi], bw[ni], acc[mi][ni], 0, 0, 0);
    };

    STAGE(0, 0);
    __syncthreads();
    int cur = 0;
    for (int kt = 32; kt < K; kt += 32) {
        STAGE(cur ^ 1, kt);
        COMPUTE(cur);
        __syncthreads();
        cur ^= 1;
    }
    COMPUTE(cur);

    const float* resf = (const float*)resp;
    const unsigned short* resb = (const unsigned short*)resp;
    float gv[8], bev[8], bb[8];
#pragma unroll
    for (int ni = 0; ni < 8; ni++) {
        int col = wc * 128 + ni * 16 + lr;
        gv[ni] = g[col]; bev[ni] = be[col]; bb[ni] = bias[col];
    }
#pragma unroll
    for (int mi = 0; mi < 4; mi++)
#pragma unroll
        for (int jj = 0; jj < 4; jj++) {
            long row = tM + wr * 64 + mi * 16 + lg * 4 + jj;
#pragma unroll
            for (int ni = 0; ni < 8; ni++) {
                int col = wc * 128 + ni * 16 + lr;
                float rv = RESBF ? bf2f(resb[row * 512 + col]) : resf[row * 512 + col];
                acc[mi][ni][jj] += bb[ni] + rv;
            }
        }
    float s2[4][4], ss2[4][4];
#pragma unroll
    for (int mi = 0; mi < 4; mi++)
#pragma unroll
        for (int jj = 0; jj < 4; jj++) {
            float s = 0.f, ss = 0.f;
#pragma unroll
            for (int ni = 0; ni < 8; ni++) {
                float v = acc[mi][ni][jj];
                s += v; ss += v * v;
            }
#pragma unroll
            for (int off = 1; off < 16; off <<= 1) {
                s  += __shfl_xor(s, off);
                ss += __shfl_xor(ss, off);
            }
            s2[mi][jj] = s; ss2[mi][jj] = ss;
        }
    __syncthreads();
    if (lr == 0) {
#pragma unroll
        for (int mi = 0; mi < 4; mi++)
#pragma unroll
            for (int jj = 0; jj < 4; jj++) {
                int rb = wr * 64 + mi * 16 + lg * 4 + jj;
                redb[0 * 512 + wc * 128 + rb] = s2[mi][jj];
                redb[1 * 512 + wc * 128 + rb] = ss2[mi][jj];
            }
    }
    __syncthreads();
    if (t < 128) {
        float S  = redb[t] + redb[128 + t] + redb[256 + t] + redb[384 + t];
        float SS = redb[512 + t] + redb[640 + t] + redb[768 + t] + redb[896 + t];
        float mean = S * (1.0f / 512.0f);
        float var  = SS * (1.0f / 512.0f) - mean * mean;
        statb[t] = mean;
        statb[128 + t] = rsqrtf(fmaxf(var, 0.f) + 1e-5f);
    }
    __syncthreads();
#pragma unroll
    for (int mi = 0; mi < 4; mi++)
#pragma unroll
        for (int jj = 0; jj < 4; jj++) {
            int rb = wr * 64 + mi * 16 + lg * 4 + jj;
            long row = tM + rb;
            float mean = statb[rb], rstd = statb[128 + rb];
#pragma unroll
            for (int ni = 0; ni < 8; ni++) {
                int col = wc * 128 + ni * 16 + lr;
                float y = (acc[mi][ni][jj] - mean) * rstd * gv[ni] + bev[ni];
                if (WRITEOF) of[row * 512 + col] = y;
                ob[row * 512 + col] = f2bf(y);
            }
        }
}

// ---------------------------------------------------------------------------
// Attention glue. KVbuf[(s*8+b)][1024]: cols 0..511 = phiK (later ATTN),
// cols 512..1023 = V. phiQ lives in QBUF (stride 512, d_out scratch).
// ctx_partial also accumulates ksum_d = sum_s phiK[s][d] (part2).
// ---------------------------------------------------------------------------
__global__ __launch_bounds__(256) void ctx_partial_kernel(
    const unsigned short* __restrict__ kv, float* __restrict__ part,
    float* __restrict__ part2)
{
    const int p = blockIdx.x, ch = blockIdx.y;
    const int b = p >> 3, h = p & 7;
    __shared__ float kb[64 * 68];
    __shared__ float vbuf[64 * 68];
    const int t = threadIdx.x;
    const int dq = t >> 4, eq = t & 15;
    f32x4 acc[4];
    f32x4 ks = {0.f, 0.f, 0.f, 0.f};
#pragma unroll
    for (int i = 0; i < 4; i++) acc[i] = f32x4{0.f, 0.f, 0.f, 0.f};

    for (int sub = 0; sub < 8; sub++) {
        int sbase = ch * 512 + sub * 64;
#pragma unroll
        for (int i = 0; i < 2; i++) {
            int idx = i * 256 + t;
            int row = idx >> 3, c8 = idx & 7;
            long ga = ((long)(sbase + row) * 8 + b) * 1024 + h * 64 + c8 * 8;
            short8 kvv = *(const short8*)&kv[ga];
            short8 vv  = *(const short8*)&kv[ga + 512];
#pragma unroll
            for (int j = 0; j < 8; j++) {
                kb[row * 68 + c8 * 8 + j]   = bf2f((unsigned short)kvv[j]);
                vbuf[row * 68 + c8 * 8 + j] = bf2f((unsigned short)vv[j]);
            }
        }
        __syncthreads();
        for (int s = 0; s < 64; s++) {
            f32x4 k4 = *(const f32x4*)&kb[s * 68 + dq * 4];
            f32x4 v4 = *(const f32x4*)&vbuf[s * 68 + eq * 4];
#pragma unroll
            for (int i = 0; i < 4; i++) acc[i] += k4[i] * v4;
            ks += k4;
        }
        __syncthreads();
    }
    float* o = part + (long)(p * 8 + ch) * 4096;
#pragma unroll
    for (int i = 0; i < 4; i++)
        *(f32x4*)&o[(dq * 4 + i) * 64 + eq * 4] = acc[i];
    if (eq == 0)
        *(f32x4*)&part2[(p * 8 + ch) * 64 + dq * 4] = ks;
}

// reduce ctx partials -> ctxA[p][n=e][k=d] (bf16, transposed); finalize ksum
// into row n=64, zero rows 65..79
__global__ __launch_bounds__(256) void ctx_reduce_kernel(
    const float* __restrict__ part, const float* __restrict__ part2,
    unsigned short* __restrict__ ctxA)
{
    int o = (blockIdx.x * 256 + threadIdx.x) * 4;
    int p = o >> 12, d = (o >> 6) & 63, e0 = o & 63;
    f32x4 s = {0.f, 0.f, 0.f, 0.f};
    for (int ch = 0; ch < 8; ch++)
        s += *(const f32x4*)&part[(long)(p * 8 + ch) * 4096 + d * 64 + e0];
#pragma unroll
    for (int j = 0; j < 4; j++) ctxA[p * 5120 + (e0 + j) * 64 + d] = f2bf(s[j]);
    if (e0 == 0) {
        float ksv = 0.f;
#pragma unroll
        for (int ch = 0; ch < 8; ch++) ksv += part2[(p * 8 + ch) * 64 + d];
        ctxA[p * 5120 + 4096 + d] = f2bf(ksv);
#pragma unroll
        for (int j = 1; j < 16; j++) ctxA[p * 5120 + 4096 + j * 64 + d] = 0;
    }
}

// out = phiQ @ [ctx | ksum]; ni=4 accumulates denominator; normalize -> bf16.
// phiQ from qbuf (stride 512); ATTN written to kv cols 0..511 (stride 1024).
__global__ __launch_bounds__(256) void attn_out_kernel(
    unsigned short* __restrict__ kv,
    const unsigned short* __restrict__ qbuf,
    const unsigned short* __restrict__ ctxA)
{
    const int p = blockIdx.x;
    const int b = p >> 3, h = p & 7;
    const int t = threadIdx.x, w = t >> 6, l = t & 63, lr = l & 15, lg = l >> 4;
    const int s0 = blockIdx.y * 256 + w * 64;
    f32x4 acc[4][5];
#pragma unroll
    for (int i = 0; i < 4; i++)
#pragma unroll
        for (int j = 0; j < 5; j++) acc[i][j] = f32x4{0.f, 0.f, 0.f, 0.f};
    const unsigned short* cb = ctxA + p * 5120;
#pragma unroll
    for (int kk = 0; kk < 2; kk++) {
        short8 af[4], bfv[5];
#pragma unroll
        for (int mi = 0; mi < 4; mi++) {
            int s = s0 + mi * 16 + lr;
            af[mi] = *(const short8*)&qbuf[((long)s * 8 + b) * 512 + h * 64 + kk * 32 + lg * 8];
        }
#pragma unroll
        for (int ni = 0; ni < 5; ni++)
            bfv[ni] = *(const short8*)&cb[(ni * 16 + lr) * 64 + kk * 32 + lg * 8];
#pragma unroll
        for (int mi = 0; mi < 4; mi++)
#pragma unroll
            for (int ni = 0; ni < 5; ni++)
                acc[mi][ni] = __builtin_amdgcn_mfma_f32_16x16x32_bf16(
                    af[mi], bfv[ni], acc[mi][ni], 0, 0, 0);
    }
#pragma unroll
    for (int mi = 0; mi < 4; mi++) {
#pragma unroll
        for (int j = 0; j < 4; j++) {
            float den = __shfl(acc[mi][4][j], (l & 48));
            float rc  = 1.0f / (den + 1e-6f);
            int s = s0 + mi * 16 + lg * 4 + j;
            long base = ((long)s * 8 + b) * 1024 + h * 64;
#pragma unroll
            for (int ni = 0; ni < 4; ni++)
                kv[base + ni * 16 + lr] = f2bf(acc[mi][ni][j] * rc);
        }
    }
}

// ---------------------------------------------------------------------------
// small helpers
// ---------------------------------------------------------------------------
__global__ __launch_bounds__(256) void cvtbf_kernel(
    const float* __restrict__ x, unsigned short* __restrict__ y)
{
    long i = ((long)blockIdx.x * 256 + threadIdx.x) * 8;
    f32x4 a = *(const f32x4*)&x[i];
    f32x4 c = *(const f32x4*)&x[i + 4];
    short8 pk;
#pragma unroll
    for (int j = 0; j < 4; j++) { pk[j] = (short)f2bf(a[j]); pk[4 + j] = (short)f2bf(c[j]); }
    *(short8*)&y[i] = pk;
}

// concat biases: dst[lyr][1536] = bk | bv | bq
__global__ __launch_bounds__(256) void bcat_kernel(
    const float* __restrict__ bk, const float* __restrict__ bv,
    const float* __restrict__ bq, float* __restrict__ dst)
{
    int lyr = blockIdx.x;
    int j = blockIdx.y * 256 + threadIdx.x;  // 0..1535
    float v;
    if (j < 512)       v = bk[lyr * 512 + j];
    else if (j < 1024) v = bv[lyr * 512 + j - 512];
    else               v = bq[lyr * 512 + j - 1024];
    dst[lyr * 1536 + j] = v;
}

// weight transpose + convert: Wt[n][k] = (bf16) W[k][n], per-layer strides
__global__ __launch_bounds__(256) void wconv_kernel(
    const float* __restrict__ W, unsigned short* __restrict__ Wt, int K, int N,
    long lstrW, long lstrT)
{
    __shared__ float tile[64 * 65];
    const long lz = blockIdx.z;
    const float* Wl = W + lz * lstrW;
    unsigned short* Wtl = Wt + lz * lstrT;
    const int k0 = blockIdx.x * 64, n0 = blockIdx.y * 64;
    const int t = threadIdx.x;
#pragma unroll
    for (int i = 0; i < 4; i++) {
        int q = i * 256 + t;
        int r = q >> 4, c4 = q & 15;
        f32x4 v = *(const f32x4*)&Wl[(long)(k0 + r) * N + n0 + c4 * 4];
#pragma unroll
        for (int j = 0; j < 4; j++) tile[r * 65 + c4 * 4 + j] = v[j];
    }
    __syncthreads();
#pragma unroll
    for (int i = 0; i < 4; i++) {
        int q = i * 256 + t;
        int nr = q >> 4, kc = q & 15;
        ushort4v pk;
#pragma unroll
        for (int j = 0; j < 4; j++) pk[j] = f2bf(tile[(kc * 4 + j) * 65 + nr]);
        *(ushort4v*)&Wtl[(long)(n0 + nr) * K + k0 + kc * 4] = pk;
    }
}

// ---------------------------------------------------------------------------
// Host orchestration.  ws ~123 MiB:
//  [WKVQ 6M][WO 2M][W1 4M][W2 4M][BKVQ 24K][R1 32M][KV 64M][KSP][CTP 8M][CTA]
// Q scratch = d_out (bf16 reinterp; only final LN2 writes d_out f32, after
// the last attn_out consumed Q). Stream: R1 bf16 in-place hops.
// ---------------------------------------------------------------------------
extern "C" void kernel_launch(void* const* d_in, const int* in_sizes, int n_in,
                              void* d_out, int out_size, void* d_ws, size_t ws_size,
                              hipStream_t stream)
{
    const float* src  = (const float*)d_in[0];
    const float* Wq   = (const float*)d_in[1];
    const float* bq   = (const float*)d_in[2];
    const float* Wk   = (const float*)d_in[3];
    const float* bk   = (const float*)d_in[4];
    const float* Wv   = (const float*)d_in[5];
    const float* bv   = (const float*)d_in[6];
    const float* Wo   = (const float*)d_in[7];
    const float* bo   = (const float*)d_in[8];
    const float* l1g  = (const float*)d_in[9];
    const float* l1b  = (const float*)d_in[10];
    const float* W1   = (const float*)d_in[11];
    const float* b1   = (const float*)d_in[12];
    const float* W2   = (const float*)d_in[13];
    const float* b2   = (const float*)d_in[14];
    const float* l2g  = (const float*)d_in[15];
    const float* l2b  = (const float*)d_in[16];

    char* ws = (char*)d_ws;
    constexpr size_t SZ_WKVQ = (size_t)4 * 1536 * 512 * 2;   // 6 MiB
    constexpr size_t SZ_WO   = (size_t)4 * 512 * 512 * 2;
    constexpr size_t SZ_W1   = (size_t)4 * 512 * 1024 * 2;
    constexpr size_t SZ_W2   = SZ_W1;
    constexpr size_t SZ_BKVQ = (size_t)4 * 1536 * 4;
    constexpr size_t SZ_R1   = (size_t)32768 * 512 * 2;
    constexpr size_t SZ_KV   = (size_t)32768 * 1024 * 2;
    constexpr size_t OFF_WKVQ = 0;
    constexpr size_t OFF_WO   = OFF_WKVQ + SZ_WKVQ;
    constexpr size_t OFF_W1   = OFF_WO + SZ_WO;
    constexpr size_t OFF_W2   = OFF_W1 + SZ_W1;
    constexpr size_t OFF_BKVQ = OFF_W2 + SZ_W2;
    constexpr size_t OFF_R1   = OFF_BKVQ + SZ_BKVQ;
    constexpr size_t OFF_KV   = OFF_R1 + SZ_R1;
    constexpr size_t OFF_KSP  = OFF_KV + SZ_KV;
    constexpr size_t OFF_CTP  = OFF_KSP + (size_t)16 * 4096 * 4;
    constexpr size_t OFF_CTA  = OFF_CTP + (size_t)64 * 8 * 4096 * 4;

    unsigned short* WKVQ = (unsigned short*)(ws + OFF_WKVQ);
    unsigned short* WOT  = (unsigned short*)(ws + OFF_WO);
    unsigned short* W1T  = (unsigned short*)(ws + OFF_W1);
    unsigned short* W2T  = (unsigned short*)(ws + OFF_W2);
    float*          BKVQ = (float*)(ws + OFF_BKVQ);
    unsigned short* R1   = (unsigned short*)(ws + OFF_R1);
    unsigned short* KV   = (unsigned short*)(ws + OFF_KV);
    float*          KSP  = (float*)(ws + OFF_KSP);
    float*          CTP  = (float*)(ws + OFF_CTP);
    unsigned short* CTA  = (unsigned short*)(ws + OFF_CTA);
    float*          F1   = (float*)d_out;                     // final f32 out
    unsigned short* QBUF = (unsigned short*)d_out;            // Q scratch (32MB)

    dim3 blk(256);
    // weights: WKVQ rows 0-511 = Wk^T, 512-1023 = Wv^T, 1024-1535 = Wq^T
    wconv_kernel<<<dim3(8, 8, 4),  blk, 0, stream>>>(Wk, WKVQ,             512, 512, 512*512, 1536*512);
    wconv_kernel<<<dim3(8, 8, 4),  blk, 0, stream>>>(Wv, WKVQ + 512*512,   512, 512, 512*512, 1536*512);
    wconv_kernel<<<dim3(8, 8, 4),  blk, 0, stream>>>(Wq, WKVQ + 1024*512,  512, 512, 512*512, 1536*512);
    wconv_kernel<<<dim3(8, 8, 4),  blk, 0, stream>>>(Wo, WOT,              512, 512, 512*512, 512*512);
    wconv_kernel<<<dim3(8, 16, 4), blk, 0, stream>>>(W1, W1T,              512, 1024, 512*1024, 512*1024);
    wconv_kernel<<<dim3(16, 8, 4), blk, 0, stream>>>(W2, W2T,              1024, 512, 1024*512, 1024*512);
    bcat_kernel<<<dim3(4, 6), blk, 0, stream>>>(bk, bv, bq, BKVQ);
    cvtbf_kernel<<<8192, blk, 0, stream>>>(src, R1);

    for (int lyr = 0; lyr < 4; lyr++) {
        const unsigned short* wkvq = WKVQ + (size_t)lyr * 1536 * 512;
        const unsigned short* wot  = WOT  + (size_t)lyr * 512 * 512;
        const unsigned short* w1t  = W1T  + (size_t)lyr * 512 * 1024;
        const unsigned short* w2t  = W2T  + (size_t)lyr * 1024 * 512;

        // K|V|Q fused GEMM (elu on K and Q cols); K|V -> KV (ldc 1024),
        // Q -> QBUF (stride 512). N=1536 -> NBY=12, grid 3072.
        gemm_kernel<0, 12><<<3072, blk, 0, stream>>>(R1, 512, wkvq, BKVQ + lyr * 1536,
                                                     KV, 1024, QBUF, 512);

        // ctx + ksum in one pass over KV
        ctx_partial_kernel<<<dim3(64, 8), blk, 0, stream>>>(KV, CTP, KSP);
        ctx_reduce_kernel<<<256, blk, 0, stream>>>(CTP, KSP, CTA);

        // attn: Q from QBUF; ATTN into KV cols 0..511 (K slot, dead)
        attn_out_kernel<<<dim3(64, 16), blk, 0, stream>>>(KV, QBUF, CTA);

        // Wo + residual + LN1 -> bf16 R1 (in-place RMW on R1)
        if (lyr == 0)
            gemm_ln_kernel<0, 0><<<256, dim3(512), 0, stream>>>(KV, 1024, wot, bo + lyr * 512, src,
                                                                l1g + lyr * 512, l1b + lyr * 512,
                                                                F1, R1, 512);
        else
            gemm_ln_kernel<1, 0><<<256, dim3(512), 0, stream>>>(KV, 1024, wot, bo + lyr * 512, R1,
                                                                l1g + lyr * 512, l1b + lyr * 512,
                                                                F1, R1, 512);
        // FFN up + relu -> HBF (KV region, dead), N=1024 -> NBY=8, grid 2048
        gemm_kernel<2, 8><<<2048, blk, 0, stream>>>(R1, 512, w1t, b1 + lyr * 1024,
                                                    KV, 1024, nullptr, 512);
        // FFN down + residual(R1 bf16) + LN2 -> R1 bf16; final also f32 d_out
        if (lyr == 3)
            gemm_ln_kernel<1, 1><<<256, dim3(512), 0, stream>>>(KV, 1024, w2t, b2 + lyr * 512, R1,
                                                                l2g + lyr * 512, l2b + lyr * 512,
                                                                F1, R1, 1024);
        else
            gemm_ln_kernel<1, 0><<<256, dim3(512), 0, stream>>>(KV, 1024, w2t, b2 + lyr * 512, R1,
                                                                l2g + lyr * 512, l2b + lyr * 512,
                                                                F1, R1, 1024);
    }
}

// Round 14
// 1122.454 us; speedup vs baseline: 2.8227x; 1.0402x over previous
//
#include <hip/hip_runtime.h>
#include <hip/hip_bf16.h>
#include <cstdint>

typedef __attribute__((ext_vector_type(8))) short short8;
typedef __attribute__((ext_vector_type(4))) float f32x4;
typedef __attribute__((ext_vector_type(4))) unsigned short ushort4v;

#define DEV static __device__ __forceinline__

DEV float bf2f(unsigned short u) {
    union { unsigned int i; float f; } v; v.i = ((unsigned int)u) << 16; return v.f;
}
DEV unsigned short f2bf(float f) {
    union { float f; unsigned int i; } v; v.f = f;
    unsigned int x = v.i;
    unsigned int r = x + 0x7fffu + ((x >> 16) & 1u);
    return (unsigned short)(r >> 16);
}

// ---------------------------------------------------------------------------
// GEMM: C[M,N] = A[M,K] @ Bt[N,K]^T + bias -> bf16. 128x128 tile, 4 waves,
// BK=64 single-buffer (r7-best). LDA/KT compile-time + full K-unroll:
// per-lane global pointers hoisted out of the loop, kt folds into the
// instruction imm offset -> staging address VALU ~0 (r13: VALUBusy 55% from
// per-iter address math). XCD swizzle, compile-time NBY.
// EPI 0 (KVQ): elu+1 on cols<512|>=1024; Q -> out2. EPI 2 (W1): relu.
// ---------------------------------------------------------------------------
template<int EPI, int NBY, int LDA, int KT>
__global__ __launch_bounds__(256) void gemm_kernel(
    const unsigned short* __restrict__ A,
    const unsigned short* __restrict__ Bt,
    const float* __restrict__ bias,
    unsigned short* __restrict__ out1, int ldc1,
    unsigned short* __restrict__ out2)
{
    __shared__ unsigned short lds[128 * 136];
    const int t  = threadIdx.x;
    const int w  = t >> 6, l = t & 63;
    const int wr = w >> 1, wc = w & 1;
    const int lr = l & 15, lg = l >> 4;
    const int bid = blockIdx.x;
    const int j8  = bid & 7, s = bid >> 3;
    const int bx  = j8 * 32 + s / NBY;
    const int by  = s % NBY;
    const long tM = (long)bx * 128;
    const long tN = (long)by * 128;

    f32x4 acc[4][4];
#pragma unroll
    for (int i = 0; i < 4; i++)
#pragma unroll
        for (int j = 0; j < 4; j++) acc[i][j] = f32x4{0.f, 0.f, 0.f, 0.f};

    // hoisted per-lane staging pointers (loop-invariant; kt folds into imm)
    const unsigned short* ga[4];
    const unsigned short* gb[4];
    unsigned int ldsa[4], ldsb[4];
#pragma unroll
    for (int j = 0; j < 4; j++) {
        int c = (w * 4 + j) * 64 + l;
        int row = c >> 3, sc = (c & 7) ^ (row & 7);
        ga[j] = A + (tM + row) * LDA + sc * 8;
        gb[j] = Bt + (tN + row) * (long)KT + sc * 8;
        ldsa[j] = (w * 4 + j) * 512;
        ldsb[j] = 8192 + (w * 4 + j) * 512;
    }

#pragma unroll
    for (int kt = 0; kt < KT; kt += 64) {
#pragma unroll
        for (int j = 0; j < 4; j++)
            __builtin_amdgcn_global_load_lds(
                (const __attribute__((address_space(1))) void*)(ga[j] + kt),
                (__attribute__((address_space(3))) void*)(lds + ldsa[j]), 16, 0, 0);
#pragma unroll
        for (int j = 0; j < 4; j++)
            __builtin_amdgcn_global_load_lds(
                (const __attribute__((address_space(1))) void*)(gb[j] + kt),
                (__attribute__((address_space(3))) void*)(lds + ldsb[j]), 16, 0, 0);
        __syncthreads();
#pragma unroll
        for (int kk = 0; kk < 2; kk++) {
            short8 af[4], bfv[4];
#pragma unroll
            for (int mi = 0; mi < 4; mi++) {
                int r  = wr * 64 + mi * 16 + lr;
                int kc = kk * 4 + lg;
                af[mi] = *(const short8*)&lds[r * 64 + ((kc ^ (r & 7)) << 3)];
            }
#pragma unroll
            for (int ni = 0; ni < 4; ni++) {
                int n  = wc * 64 + ni * 16 + lr;
                int kc = kk * 4 + lg;
                bfv[ni] = *(const short8*)&lds[8192 + n * 64 + ((kc ^ (n & 7)) << 3)];
            }
#pragma unroll
            for (int mi = 0; mi < 4; mi++)
#pragma unroll
                for (int ni = 0; ni < 4; ni++)
                    acc[mi][ni] = __builtin_amdgcn_mfma_f32_16x16x32_bf16(
                        af[mi], bfv[ni], acc[mi][ni], 0, 0, 0);
        }
        __syncthreads();
    }

    float bv[4];
#pragma unroll
    for (int ni = 0; ni < 4; ni++) bv[ni] = bias[tN + wc * 64 + ni * 16 + lr];
    const bool doElu = (EPI == 0) && (tN < 512 || tN >= 1024);

#pragma unroll
    for (int mi = 0; mi < 4; mi++)
#pragma unroll
        for (int ni = 0; ni < 4; ni++)
#pragma unroll
            for (int j = 0; j < 4; j++) {
                float v = acc[mi][ni][j] + bv[ni];
                if (EPI == 0) { if (doElu) v = (v > 0.f) ? (v + 1.f) : expf(v); }
                if (EPI == 2) v = fmaxf(v, 0.f);
                int r = wr * 64 + mi * 16 + lg * 4 + j;
                int c = wc * 64 + ni * 16 + lr;
                lds[r * 136 + c] = f2bf(v);
            }
    __syncthreads();
    const bool toQ = (NBY == 12) && (tN >= 1024);
    unsigned short* o = toQ ? out2 : out1;
    const long ldc   = toQ ? 512 : ldc1;
    const long cb    = toQ ? (tN - 1024) : tN;
#pragma unroll
    for (int i = 0; i < 8; i++) {
        int q = i * 256 + t;
        int r = q >> 4, cc = q & 15;
        short8 v8 = *(const short8*)&lds[r * 136 + cc * 8];
        *(short8*)&o[(tM + r) * ldc + cb + cc * 8] = v8;
    }
}

// ---------------------------------------------------------------------------
// Fused GEMM + bias + residual + LayerNorm, 2-phase dbuf BK=32 (r10-r13
// proven), KT compile-time + full unroll + hoisted staging pointers.
// RESBF: residual bf16 vs f32 (src, layer 0). WRITEOF: final LN2 -> d_out.
// NO min-wave bound (r8: forced cap -> accumulator spill).
// ---------------------------------------------------------------------------
template<int RESBF, int WRITEOF, int KT>
__global__ __launch_bounds__(512) void gemm_ln_kernel(
    const unsigned short* __restrict__ A, int lda,
    const unsigned short* __restrict__ Bt,   // [512][KT]
    const float* __restrict__ bias,          // [512]
    const void* __restrict__ resp,           // [M][512] f32 or bf16 (RESBF)
    const float* __restrict__ g,
    const float* __restrict__ be,
    float* __restrict__ of,                  // [M][512] f32 (if WRITEOF)
    unsigned short* __restrict__ ob,         // [M][512] bf16
    int unused)
{
    __shared__ unsigned short sA[2][128 * 32];   // 2 x 8 KiB
    __shared__ unsigned short sB[2][512 * 32];   // 2 x 32 KiB
    float* redb  = (float*)&sA[0][0];            // epilogue alias: 4 KiB
    float* statb = redb + 1024;                  // 1 KiB
    const int t = threadIdx.x, w = t >> 6, l = t & 63, lr = l & 15, lg = l >> 4;
    const int wr = w >> 2, wc = w & 3;
    const long tM = (long)blockIdx.x * 128;

    f32x4 acc[4][8];
#pragma unroll
    for (int i = 0; i < 4; i++)
#pragma unroll
        for (int j = 0; j < 8; j++) acc[i][j] = f32x4{0.f, 0.f, 0.f, 0.f};

    // hoisted staging pointers
    const unsigned short* gA;
    const unsigned short* gB[4];
    unsigned int la, lb[4];
    {
        int c = t, row = c >> 2, sc = (c & 3) ^ ((row >> 1) & 3);
        gA = A + (tM + row) * (long)lda + sc * 8;
        la = (w * 64) * 8;
    }
#pragma unroll
    for (int j = 0; j < 4; j++) {
        int c = j * 512 + t, row = c >> 2, sc = (c & 3) ^ ((row >> 1) & 3);
        gB[j] = Bt + (long)row * KT + sc * 8;
        lb[j] = (j * 512 + w * 64) * 8;
    }

    auto STAGE = [&](int buf, int kt) {
        __builtin_amdgcn_global_load_lds(
            (const __attribute__((address_space(1))) void*)(gA + kt),
            (__attribute__((address_space(3))) void*)(&sA[buf][la]), 16, 0, 0);
#pragma unroll
        for (int j = 0; j < 4; j++)
            __builtin_amdgcn_global_load_lds(
                (const __attribute__((address_space(1))) void*)(gB[j] + kt),
                (__attribute__((address_space(3))) void*)(&sB[buf][lb[j]]), 16, 0, 0);
    };

    auto COMPUTE = [&](int buf) {
        short8 av[4], bw[8];
#pragma unroll
        for (int mi = 0; mi < 4; mi++) {
            int r = wr * 64 + mi * 16 + lr;
            av[mi] = *(const short8*)&sA[buf][r * 32 + ((lg ^ ((r >> 1) & 3)) << 3)];
        }
#pragma unroll
        for (int ni = 0; ni < 8; ni++) {
            int n = wc * 128 + ni * 16 + lr;
            bw[ni] = *(const short8*)&sB[buf][n * 32 + ((lg ^ ((n >> 1) & 3)) << 3)];
        }
#pragma unroll
        for (int mi = 0; mi < 4; mi++)
#pragma unroll
            for (int ni = 0; ni < 8; ni++)
                acc[mi][ni] = __builtin_amdgcn_mfma_f32_16x16x32_bf16(
                    av[mi], bw[ni], acc[mi][ni], 0, 0, 0);
    };

    STAGE(0, 0);
    __syncthreads();
#pragma unroll
    for (int kt = 32; kt < KT; kt += 32) {
        const int cur = ((kt >> 5) & 1) ^ 1;   // 0,1,0,1... compile-time per iter
        STAGE(cur ^ 1, kt);
        COMPUTE(cur);
        __syncthreads();
    }
    COMPUTE(((KT >> 5) & 1) ^ 1);

    const float* resf = (const float*)resp;
    const unsigned short* resb = (const unsigned short*)resp;
    float gv[8], bev[8], bb[8];
#pragma unroll
    for (int ni = 0; ni < 8; ni++) {
        int col = wc * 128 + ni * 16 + lr;
        gv[ni] = g[col]; bev[ni] = be[col]; bb[ni] = bias[col];
    }
#pragma unroll
    for (int mi = 0; mi < 4; mi++)
#pragma unroll
        for (int jj = 0; jj < 4; jj++) {
            long row = tM + wr * 64 + mi * 16 + lg * 4 + jj;
#pragma unroll
            for (int ni = 0; ni < 8; ni++) {
                int col = wc * 128 + ni * 16 + lr;
                float rv = RESBF ? bf2f(resb[row * 512 + col]) : resf[row * 512 + col];
                acc[mi][ni][jj] += bb[ni] + rv;
            }
        }
    float s2[4][4], ss2[4][4];
#pragma unroll
    for (int mi = 0; mi < 4; mi++)
#pragma unroll
        for (int jj = 0; jj < 4; jj++) {
            float s = 0.f, ss = 0.f;
#pragma unroll
            for (int ni = 0; ni < 8; ni++) {
                float v = acc[mi][ni][jj];
                s += v; ss += v * v;
            }
#pragma unroll
            for (int off = 1; off < 16; off <<= 1) {
                s  += __shfl_xor(s, off);
                ss += __shfl_xor(ss, off);
            }
            s2[mi][jj] = s; ss2[mi][jj] = ss;
        }
    __syncthreads();
    if (lr == 0) {
#pragma unroll
        for (int mi = 0; mi < 4; mi++)
#pragma unroll
            for (int jj = 0; jj < 4; jj++) {
                int rb = wr * 64 + mi * 16 + lg * 4 + jj;
                redb[0 * 512 + wc * 128 + rb] = s2[mi][jj];
                redb[1 * 512 + wc * 128 + rb] = ss2[mi][jj];
            }
    }
    __syncthreads();
    if (t < 128) {
        float S  = redb[t] + redb[128 + t] + redb[256 + t] + redb[384 + t];
        float SS = redb[512 + t] + redb[640 + t] + redb[768 + t] + redb[896 + t];
        float mean = S * (1.0f / 512.0f);
        float var  = SS * (1.0f / 512.0f) - mean * mean;
        statb[t] = mean;
        statb[128 + t] = rsqrtf(fmaxf(var, 0.f) + 1e-5f);
    }
    __syncthreads();
#pragma unroll
    for (int mi = 0; mi < 4; mi++)
#pragma unroll
        for (int jj = 0; jj < 4; jj++) {
            int rb = wr * 64 + mi * 16 + lg * 4 + jj;
            long row = tM + rb;
            float mean = statb[rb], rstd = statb[128 + rb];
#pragma unroll
            for (int ni = 0; ni < 8; ni++) {
                int col = wc * 128 + ni * 16 + lr;
                float y = (acc[mi][ni][jj] - mean) * rstd * gv[ni] + bev[ni];
                if (WRITEOF) of[row * 512 + col] = y;
                ob[row * 512 + col] = f2bf(y);
            }
        }
}

// ---------------------------------------------------------------------------
// Attention glue. KVbuf[(s*8+b)][1024]: cols 0..511 = phiK (later ATTN),
// cols 512..1023 = V. phiQ lives in QBUF (stride 512, d_out scratch).
// ctx_partial also accumulates ksum_d = sum_s phiK[s][d] (part2).
// ---------------------------------------------------------------------------
__global__ __launch_bounds__(256) void ctx_partial_kernel(
    const unsigned short* __restrict__ kv, float* __restrict__ part,
    float* __restrict__ part2)
{
    const int p = blockIdx.x, ch = blockIdx.y;
    const int b = p >> 3, h = p & 7;
    __shared__ float kb[64 * 68];
    __shared__ float vbuf[64 * 68];
    const int t = threadIdx.x;
    const int dq = t >> 4, eq = t & 15;
    f32x4 acc[4];
    f32x4 ks = {0.f, 0.f, 0.f, 0.f};
#pragma unroll
    for (int i = 0; i < 4; i++) acc[i] = f32x4{0.f, 0.f, 0.f, 0.f};

    for (int sub = 0; sub < 8; sub++) {
        int sbase = ch * 512 + sub * 64;
#pragma unroll
        for (int i = 0; i < 2; i++) {
            int idx = i * 256 + t;
            int row = idx >> 3, c8 = idx & 7;
            long ga = ((long)(sbase + row) * 8 + b) * 1024 + h * 64 + c8 * 8;
            short8 kvv = *(const short8*)&kv[ga];
            short8 vv  = *(const short8*)&kv[ga + 512];
#pragma unroll
            for (int j = 0; j < 8; j++) {
                kb[row * 68 + c8 * 8 + j]   = bf2f((unsigned short)kvv[j]);
                vbuf[row * 68 + c8 * 8 + j] = bf2f((unsigned short)vv[j]);
            }
        }
        __syncthreads();
        for (int s = 0; s < 64; s++) {
            f32x4 k4 = *(const f32x4*)&kb[s * 68 + dq * 4];
            f32x4 v4 = *(const f32x4*)&vbuf[s * 68 + eq * 4];
#pragma unroll
            for (int i = 0; i < 4; i++) acc[i] += k4[i] * v4;
            ks += k4;
        }
        __syncthreads();
    }
    float* o = part + (long)(p * 8 + ch) * 4096;
#pragma unroll
    for (int i = 0; i < 4; i++)
        *(f32x4*)&o[(dq * 4 + i) * 64 + eq * 4] = acc[i];
    if (eq == 0)
        *(f32x4*)&part2[(p * 8 + ch) * 64 + dq * 4] = ks;
}

// reduce ctx partials -> ctxA[p][n=e][k=d] (bf16, transposed); finalize ksum
// into row n=64, zero rows 65..79
__global__ __launch_bounds__(256) void ctx_reduce_kernel(
    const float* __restrict__ part, const float* __restrict__ part2,
    unsigned short* __restrict__ ctxA)
{
    int o = (blockIdx.x * 256 + threadIdx.x) * 4;
    int p = o >> 12, d = (o >> 6) & 63, e0 = o & 63;
    f32x4 s = {0.f, 0.f, 0.f, 0.f};
    for (int ch = 0; ch < 8; ch++)
        s += *(const f32x4*)&part[(long)(p * 8 + ch) * 4096 + d * 64 + e0];
#pragma unroll
    for (int j = 0; j < 4; j++) ctxA[p * 5120 + (e0 + j) * 64 + d] = f2bf(s[j]);
    if (e0 == 0) {
        float ksv = 0.f;
#pragma unroll
        for (int ch = 0; ch < 8; ch++) ksv += part2[(p * 8 + ch) * 64 + d];
        ctxA[p * 5120 + 4096 + d] = f2bf(ksv);
#pragma unroll
        for (int j = 1; j < 16; j++) ctxA[p * 5120 + 4096 + j * 64 + d] = 0;
    }
}

// out = phiQ @ [ctx | ksum]; ni=4 accumulates denominator; normalize -> bf16.
__global__ __launch_bounds__(256) void attn_out_kernel(
    unsigned short* __restrict__ kv,
    const unsigned short* __restrict__ qbuf,
    const unsigned short* __restrict__ ctxA)
{
    const int p = blockIdx.x;
    const int b = p >> 3, h = p & 7;
    const int t = threadIdx.x, w = t >> 6, l = t & 63, lr = l & 15, lg = l >> 4;
    const int s0 = blockIdx.y * 256 + w * 64;
    f32x4 acc[4][5];
#pragma unroll
    for (int i = 0; i < 4; i++)
#pragma unroll
        for (int j = 0; j < 5; j++) acc[i][j] = f32x4{0.f, 0.f, 0.f, 0.f};
    const unsigned short* cb = ctxA + p * 5120;
#pragma unroll
    for (int kk = 0; kk < 2; kk++) {
        short8 af[4], bfv[5];
#pragma unroll
        for (int mi = 0; mi < 4; mi++) {
            int s = s0 + mi * 16 + lr;
            af[mi] = *(const short8*)&qbuf[((long)s * 8 + b) * 512 + h * 64 + kk * 32 + lg * 8];
        }
#pragma unroll
        for (int ni = 0; ni < 5; ni++)
            bfv[ni] = *(const short8*)&cb[(ni * 16 + lr) * 64 + kk * 32 + lg * 8];
#pragma unroll
        for (int mi = 0; mi < 4; mi++)
#pragma unroll
            for (int ni = 0; ni < 5; ni++)
                acc[mi][ni] = __builtin_amdgcn_mfma_f32_16x16x32_bf16(
                    af[mi], bfv[ni], acc[mi][ni], 0, 0, 0);
    }
#pragma unroll
    for (int mi = 0; mi < 4; mi++) {
#pragma unroll
        for (int j = 0; j < 4; j++) {
            float den = __shfl(acc[mi][4][j], (l & 48));
            float rc  = 1.0f / (den + 1e-6f);
            int s = s0 + mi * 16 + lg * 4 + j;
            long base = ((long)s * 8 + b) * 1024 + h * 64;
#pragma unroll
            for (int ni = 0; ni < 4; ni++)
                kv[base + ni * 16 + lr] = f2bf(acc[mi][ni][j] * rc);
        }
    }
}

// ---------------------------------------------------------------------------
// small helpers
// ---------------------------------------------------------------------------
__global__ __launch_bounds__(256) void cvtbf_kernel(
    const float* __restrict__ x, unsigned short* __restrict__ y)
{
    long i = ((long)blockIdx.x * 256 + threadIdx.x) * 8;
    f32x4 a = *(const f32x4*)&x[i];
    f32x4 c = *(const f32x4*)&x[i + 4];
    short8 pk;
#pragma unroll
    for (int j = 0; j < 4; j++) { pk[j] = (short)f2bf(a[j]); pk[4 + j] = (short)f2bf(c[j]); }
    *(short8*)&y[i] = pk;
}

// concat biases: dst[lyr][1536] = bk | bv | bq
__global__ __launch_bounds__(256) void bcat_kernel(
    const float* __restrict__ bk, const float* __restrict__ bv,
    const float* __restrict__ bq, float* __restrict__ dst)
{
    int lyr = blockIdx.x;
    int j = blockIdx.y * 256 + threadIdx.x;  // 0..1535
    float v;
    if (j < 512)       v = bk[lyr * 512 + j];
    else if (j < 1024) v = bv[lyr * 512 + j - 512];
    else               v = bq[lyr * 512 + j - 1024];
    dst[lyr * 1536 + j] = v;
}

// weight transpose + convert: Wt[n][k] = (bf16) W[k][n], per-layer strides
__global__ __launch_bounds__(256) void wconv_kernel(
    const float* __restrict__ W, unsigned short* __restrict__ Wt, int K, int N,
    long lstrW, long lstrT)
{
    __shared__ float tile[64 * 65];
    const long lz = blockIdx.z;
    const float* Wl = W + lz * lstrW;
    unsigned short* Wtl = Wt + lz * lstrT;
    const int k0 = blockIdx.x * 64, n0 = blockIdx.y * 64;
    const int t = threadIdx.x;
#pragma unroll
    for (int i = 0; i < 4; i++) {
        int q = i * 256 + t;
        int r = q >> 4, c4 = q & 15;
        f32x4 v = *(const f32x4*)&Wl[(long)(k0 + r) * N + n0 + c4 * 4];
#pragma unroll
        for (int j = 0; j < 4; j++) tile[r * 65 + c4 * 4 + j] = v[j];
    }
    __syncthreads();
#pragma unroll
    for (int i = 0; i < 4; i++) {
        int q = i * 256 + t;
        int nr = q >> 4, kc = q & 15;
        ushort4v pk;
#pragma unroll
        for (int j = 0; j < 4; j++) pk[j] = f2bf(tile[(kc * 4 + j) * 65 + nr]);
        *(ushort4v*)&Wtl[(long)(n0 + nr) * K + k0 + kc * 4] = pk;
    }
}

// ---------------------------------------------------------------------------
// Host orchestration.  ws ~123 MiB:
//  [WKVQ 6M][WO 2M][W1 4M][W2 4M][BKVQ 24K][R1 32M][KV 64M][KSP][CTP 8M][CTA]
// Q scratch = d_out (bf16 reinterp; only final LN2 writes d_out f32, after
// the last attn_out consumed Q). Stream: R1 bf16 in-place hops.
// ---------------------------------------------------------------------------
extern "C" void kernel_launch(void* const* d_in, const int* in_sizes, int n_in,
                              void* d_out, int out_size, void* d_ws, size_t ws_size,
                              hipStream_t stream)
{
    const float* src  = (const float*)d_in[0];
    const float* Wq   = (const float*)d_in[1];
    const float* bq   = (const float*)d_in[2];
    const float* Wk   = (const float*)d_in[3];
    const float* bk   = (const float*)d_in[4];
    const float* Wv   = (const float*)d_in[5];
    const float* bv   = (const float*)d_in[6];
    const float* Wo   = (const float*)d_in[7];
    const float* bo   = (const float*)d_in[8];
    const float* l1g  = (const float*)d_in[9];
    const float* l1b  = (const float*)d_in[10];
    const float* W1   = (const float*)d_in[11];
    const float* b1   = (const float*)d_in[12];
    const float* W2   = (const float*)d_in[13];
    const float* b2   = (const float*)d_in[14];
    const float* l2g  = (const float*)d_in[15];
    const float* l2b  = (const float*)d_in[16];

    char* ws = (char*)d_ws;
    constexpr size_t SZ_WKVQ = (size_t)4 * 1536 * 512 * 2;   // 6 MiB
    constexpr size_t SZ_WO   = (size_t)4 * 512 * 512 * 2;
    constexpr size_t SZ_W1   = (size_t)4 * 512 * 1024 * 2;
    constexpr size_t SZ_W2   = SZ_W1;
    constexpr size_t SZ_BKVQ = (size_t)4 * 1536 * 4;
    constexpr size_t SZ_R1   = (size_t)32768 * 512 * 2;
    constexpr size_t SZ_KV   = (size_t)32768 * 1024 * 2;
    constexpr size_t OFF_WKVQ = 0;
    constexpr size_t OFF_WO   = OFF_WKVQ + SZ_WKVQ;
    constexpr size_t OFF_W1   = OFF_WO + SZ_WO;
    constexpr size_t OFF_W2   = OFF_W1 + SZ_W1;
    constexpr size_t OFF_BKVQ = OFF_W2 + SZ_W2;
    constexpr size_t OFF_R1   = OFF_BKVQ + SZ_BKVQ;
    constexpr size_t OFF_KV   = OFF_R1 + SZ_R1;
    constexpr size_t OFF_KSP  = OFF_KV + SZ_KV;
    constexpr size_t OFF_CTP  = OFF_KSP + (size_t)16 * 4096 * 4;
    constexpr size_t OFF_CTA  = OFF_CTP + (size_t)64 * 8 * 4096 * 4;

    unsigned short* WKVQ = (unsigned short*)(ws + OFF_WKVQ);
    unsigned short* WOT  = (unsigned short*)(ws + OFF_WO);
    unsigned short* W1T  = (unsigned short*)(ws + OFF_W1);
    unsigned short* W2T  = (unsigned short*)(ws + OFF_W2);
    float*          BKVQ = (float*)(ws + OFF_BKVQ);
    unsigned short* R1   = (unsigned short*)(ws + OFF_R1);
    unsigned short* KV   = (unsigned short*)(ws + OFF_KV);
    float*          KSP  = (float*)(ws + OFF_KSP);
    float*          CTP  = (float*)(ws + OFF_CTP);
    unsigned short* CTA  = (unsigned short*)(ws + OFF_CTA);
    float*          F1   = (float*)d_out;                     // final f32 out
    unsigned short* QBUF = (unsigned short*)d_out;            // Q scratch

    dim3 blk(256);
    wconv_kernel<<<dim3(8, 8, 4),  blk, 0, stream>>>(Wk, WKVQ,             512, 512, 512*512, 1536*512);
    wconv_kernel<<<dim3(8, 8, 4),  blk, 0, stream>>>(Wv, WKVQ + 512*512,   512, 512, 512*512, 1536*512);
    wconv_kernel<<<dim3(8, 8, 4),  blk, 0, stream>>>(Wq, WKVQ + 1024*512,  512, 512, 512*512, 1536*512);
    wconv_kernel<<<dim3(8, 8, 4),  blk, 0, stream>>>(Wo, WOT,              512, 512, 512*512, 512*512);
    wconv_kernel<<<dim3(8, 16, 4), blk, 0, stream>>>(W1, W1T,              512, 1024, 512*1024, 512*1024);
    wconv_kernel<<<dim3(16, 8, 4), blk, 0, stream>>>(W2, W2T,              1024, 512, 1024*512, 1024*512);
    bcat_kernel<<<dim3(4, 6), blk, 0, stream>>>(bk, bv, bq, BKVQ);
    cvtbf_kernel<<<8192, blk, 0, stream>>>(src, R1);

    for (int lyr = 0; lyr < 4; lyr++) {
        const unsigned short* wkvq = WKVQ + (size_t)lyr * 1536 * 512;
        const unsigned short* wot  = WOT  + (size_t)lyr * 512 * 512;
        const unsigned short* w1t  = W1T  + (size_t)lyr * 512 * 1024;
        const unsigned short* w2t  = W2T  + (size_t)lyr * 1024 * 512;

        // K|V|Q fused GEMM; K|V -> KV (ldc 1024), Q -> QBUF (stride 512)
        gemm_kernel<0, 12, 512, 512><<<3072, blk, 0, stream>>>(R1, wkvq, BKVQ + lyr * 1536,
                                                               KV, 1024, QBUF);

        // ctx + ksum in one pass over KV
        ctx_partial_kernel<<<dim3(64, 8), blk, 0, stream>>>(KV, CTP, KSP);
        ctx_reduce_kernel<<<256, blk, 0, stream>>>(CTP, KSP, CTA);

        // attn: Q from QBUF; ATTN into KV cols 0..511 (K slot, dead)
        attn_out_kernel<<<dim3(64, 16), blk, 0, stream>>>(KV, QBUF, CTA);

        // Wo + residual + LN1 -> bf16 R1 (in-place RMW on R1)
        if (lyr == 0)
            gemm_ln_kernel<0, 0, 512><<<256, dim3(512), 0, stream>>>(KV, 1024, wot, bo + lyr * 512, src,
                                                                     l1g + lyr * 512, l1b + lyr * 512,
                                                                     F1, R1, 0);
        else
            gemm_ln_kernel<1, 0, 512><<<256, dim3(512), 0, stream>>>(KV, 1024, wot, bo + lyr * 512, R1,
                                                                     l1g + lyr * 512, l1b + lyr * 512,
                                                                     F1, R1, 0);
        // FFN up + relu -> HBF (KV region, dead)
        gemm_kernel<2, 8, 512, 512><<<2048, blk, 0, stream>>>(R1, w1t, b1 + lyr * 1024,
                                                              KV, 1024, nullptr);
        // FFN down + residual(R1 bf16) + LN2 -> R1 bf16; final also f32 d_out
        if (lyr == 3)
            gemm_ln_kernel<1, 1, 1024><<<256, dim3(512), 0, stream>>>(KV, 1024, w2t, b2 + lyr * 512, R1,
                                                                      l2g + lyr * 512, l2b + lyr * 512,
                                                                      F1, R1, 0);
        else
            gemm_ln_kernel<1, 0, 1024><<<256, dim3(512), 0, stream>>>(KV, 1024, w2t, b2 + lyr * 512, R1,
                                                                      l2g + lyr * 512, l2b + lyr * 512,
                                                                      F1, R1, 0);
    }
}